// Round 2
// baseline (5402.742 us; speedup 1.0000x reference)
//
#include <hip/hip_runtime.h>
#include <math.h>

// Shapes fixed by setup_inputs: B=4, T=8192 -> N=32768 tokens, D=256, H=256, S=4096.
#define NTOK 32768
#define SMEM 4096

typedef unsigned short u16;
typedef __attribute__((ext_vector_type(8))) short bf16x8_t;
typedef __attribute__((ext_vector_type(4))) float f32x4_t;

#define MFMA16(A, B, C) __builtin_amdgcn_mfma_f32_16x16x32_bf16(A, B, C, 0, 0, 0)

__device__ __forceinline__ float gelu_f(float x) {
  return 0.5f * x * (1.0f + erff(x * 0.7071067811865475f));
}
// round-to-nearest-even f32 -> bf16 (as u16 bits)
__device__ __forceinline__ u16 f2bf(float x) {
  unsigned u = __float_as_uint(x);
  return (u16)((u + 0x7FFFu + ((u >> 16) & 1u)) >> 16);
}
__device__ __forceinline__ float bf2f(u16 h) {
  return __uint_as_float(((unsigned)h) << 16);
}

// ---------------------------------------------------------------------------
// Prep 1: elementwise split K_mem -> khi/klo (bf16 hi + residual lo)
// ---------------------------------------------------------------------------
__global__ __launch_bounds__(256) void split_k(const float* __restrict__ K,
                                               u16* __restrict__ khi,
                                               u16* __restrict__ klo) {
  const int i8 = (blockIdx.x * 256 + threadIdx.x) * 8;  // grid sized exactly
  union { u16 u[8]; float4 f; } H, L;
#pragma unroll
  for (int j = 0; j < 8; j++) {
    const float v = K[i8 + j];
    const u16 h = f2bf(v);
    H.u[j] = h;
    L.u[j] = f2bf(v - bf2f(h));
  }
  *(float4*)(khi + i8) = H.f;
  *(float4*)(klo + i8) = L.f;
}

// ---------------------------------------------------------------------------
// Prep 2: V_mem[4096][256] -> vthi/vtlo transposed [256][4096] bf16 hi/lo
// Block tile: 256 slots x 32 dims. LDS Vs[dim][slot].
// ---------------------------------------------------------------------------
__global__ __launch_bounds__(256) void vt_split(const float* __restrict__ V,
                                                u16* __restrict__ vthi,
                                                u16* __restrict__ vtlo) {
  __shared__ float Vs[32][260];
  const int t = threadIdx.x;
  const int s0 = (blockIdx.x & 15) * 256;  // slot tile
  const int d0 = (blockIdx.x >> 4) * 32;   // dim tile
#pragma unroll
  for (int m = 0; m < 8; m++) {
    const int r = (t >> 3) + 32 * m;  // slot-local row
    const float4 v =
        *(const float4*)(V + (size_t)(s0 + r) * 256 + d0 + (t & 7) * 4);
    Vs[(t & 7) * 4 + 0][r] = v.x;
    Vs[(t & 7) * 4 + 1][r] = v.y;
    Vs[(t & 7) * 4 + 2][r] = v.z;
    Vs[(t & 7) * 4 + 3][r] = v.w;
  }
  __syncthreads();
  const int dl = t >> 3;          // dim-local 0..31
  const int sl0 = (t & 7) * 32;   // slot-local base
  union { u16 u[8]; float4 f; } H[4], L[4];
#pragma unroll
  for (int i = 0; i < 8; i++) {
    const float4 v = *(const float4*)&Vs[dl][sl0 + i * 4];
    const float vv[4] = {v.x, v.y, v.z, v.w};
#pragma unroll
    for (int j = 0; j < 4; j++) {
      const u16 h = f2bf(vv[j]);
      H[i >> 1].u[(i & 1) * 4 + j] = h;
      L[i >> 1].u[(i & 1) * 4 + j] = f2bf(vv[j] - bf2f(h));
    }
  }
  const size_t ob = (size_t)(d0 + dl) * 4096 + s0 + sl0;
#pragma unroll
  for (int i = 0; i < 4; i++) {
    *(float4*)(vthi + ob + i * 8) = H[i].f;
    *(float4*)(vtlo + ob + i * 8) = L[i].f;
  }
}

// ---------------------------------------------------------------------------
// GEMM BN=256, BM=32, KSTEP=32, 256 threads.
// EPI==0: out = A@W + b                                (x_proj, fp32)
// EPI==1: bf16split(gelu(LN(A@W+b)) * 0.0625) -> bh,bl (query/16, no fp32 out)
// EPI==2: out = LN(LN(A@W+b) + ident)                  (final out, fp32)
// ---------------------------------------------------------------------------
template <int KDIM, int EPI>
__global__ __launch_bounds__(256) void gemm256(
    const float* __restrict__ A1, const float* __restrict__ A2,
    const float* __restrict__ W, const float* __restrict__ bias,
    const float* __restrict__ g0, const float* __restrict__ be0,
    const float* __restrict__ g1, const float* __restrict__ be1,
    const float* __restrict__ ident, float* __restrict__ out,
    u16* __restrict__ bh, u16* __restrict__ bl) {
  __shared__ float As[32][36];
  __shared__ float Bs[32][256];
  const int t = threadIdx.x;
  const int tx = t & 63;
  const int ty = t >> 6;
  const int row0 = blockIdx.x * 32;
  const int c0 = tx * 4;

  float acc[8][4];
#pragma unroll
  for (int r = 0; r < 8; r++)
#pragma unroll
    for (int j = 0; j < 4; j++) acc[r][j] = 0.f;

  const int ar = t >> 3;
  const int akc = (t & 7) * 4;

  for (int k0 = 0; k0 < KDIM; k0 += 32) {
    float4 av;
    if (KDIM == 512) {
      const int kg = k0 + akc;
      const float* src = (kg < 256) ? A1 : A2;
      av = *(const float4*)(src + (size_t)(row0 + ar) * 256 + (kg & 255));
    } else {
      av = *(const float4*)(A1 + (size_t)(row0 + ar) * 256 + k0 + akc);
    }
    As[akc + 0][ar] = av.x;
    As[akc + 1][ar] = av.y;
    As[akc + 2][ar] = av.z;
    As[akc + 3][ar] = av.w;
#pragma unroll
    for (int j = 0; j < 8; j++) {
      *(float4*)&Bs[ar][akc + j * 32] =
          *(const float4*)(W + (size_t)(k0 + ar) * 256 + akc + j * 32);
    }
    __syncthreads();
#pragma unroll
    for (int kk = 0; kk < 32; kk++) {
      const float4 bv = *(const float4*)&Bs[kk][c0];
      const float4 a0 = *(const float4*)&As[kk][ty * 8];
      const float4 a1 = *(const float4*)&As[kk][ty * 8 + 4];
      const float a8[8] = {a0.x, a0.y, a0.z, a0.w, a1.x, a1.y, a1.z, a1.w};
      const float b4[4] = {bv.x, bv.y, bv.z, bv.w};
#pragma unroll
      for (int r = 0; r < 8; r++)
#pragma unroll
        for (int j = 0; j < 4; j++) acc[r][j] = fmaf(a8[r], b4[j], acc[r][j]);
    }
    __syncthreads();
  }

  float bb[4];
#pragma unroll
  for (int j = 0; j < 4; j++) bb[j] = bias[c0 + j];
#pragma unroll
  for (int r = 0; r < 8; r++)
#pragma unroll
    for (int j = 0; j < 4; j++) acc[r][j] += bb[j];

  if (EPI == 0) {
#pragma unroll
    for (int r = 0; r < 8; r++) {
      float4 v = make_float4(acc[r][0], acc[r][1], acc[r][2], acc[r][3]);
      *(float4*)(out + (size_t)(row0 + ty * 8 + r) * 256 + c0) = v;
    }
    return;
  }

  float gg[4], ee[4];
#pragma unroll
  for (int j = 0; j < 4; j++) {
    gg[j] = g0[c0 + j];
    ee[j] = be0[c0 + j];
  }

#pragma unroll
  for (int r = 0; r < 8; r++) {
    float s1 = acc[r][0] + acc[r][1] + acc[r][2] + acc[r][3];
    float s2 = acc[r][0] * acc[r][0] + acc[r][1] * acc[r][1] +
               acc[r][2] * acc[r][2] + acc[r][3] * acc[r][3];
#pragma unroll
    for (int mk = 1; mk < 64; mk <<= 1) {
      s1 += __shfl_xor(s1, mk, 64);
      s2 += __shfl_xor(s2, mk, 64);
    }
    const float mu = s1 * (1.0f / 256.0f);
    const float rstd = rsqrtf(s2 * (1.0f / 256.0f) - mu * mu + 1e-5f);
    if (EPI == 1) {
      float q[4];
#pragma unroll
      for (int j = 0; j < 4; j++)
        q[j] = gelu_f((acc[r][j] - mu) * rstd * gg[j] + ee[j]) * 0.0625f;
      ushort4 hv, lv;
      u16 h;
      h = f2bf(q[0]); hv.x = h; lv.x = f2bf(q[0] - bf2f(h));
      h = f2bf(q[1]); hv.y = h; lv.y = f2bf(q[1] - bf2f(h));
      h = f2bf(q[2]); hv.z = h; lv.z = f2bf(q[2] - bf2f(h));
      h = f2bf(q[3]); hv.w = h; lv.w = f2bf(q[3] - bf2f(h));
      const size_t o = (size_t)(row0 + ty * 8 + r) * 256 + c0;
      *(ushort4*)(bh + o) = hv;
      *(ushort4*)(bl + o) = lv;
    } else {
      const float4 idv =
          *(const float4*)(ident + (size_t)(row0 + ty * 8 + r) * 256 + c0);
      acc[r][0] = (acc[r][0] - mu) * rstd * gg[0] + ee[0] + idv.x;
      acc[r][1] = (acc[r][1] - mu) * rstd * gg[1] + ee[1] + idv.y;
      acc[r][2] = (acc[r][2] - mu) * rstd * gg[2] + ee[2] + idv.z;
      acc[r][3] = (acc[r][3] - mu) * rstd * gg[3] + ee[3] + idv.w;
    }
  }

  if (EPI == 2) {
    float g1v[4], e1v[4];
#pragma unroll
    for (int j = 0; j < 4; j++) {
      g1v[j] = g1[c0 + j];
      e1v[j] = be1[c0 + j];
    }
#pragma unroll
    for (int r = 0; r < 8; r++) {
      float s1 = acc[r][0] + acc[r][1] + acc[r][2] + acc[r][3];
      float s2 = acc[r][0] * acc[r][0] + acc[r][1] * acc[r][1] +
                 acc[r][2] * acc[r][2] + acc[r][3] * acc[r][3];
#pragma unroll
      for (int mk = 1; mk < 64; mk <<= 1) {
        s1 += __shfl_xor(s1, mk, 64);
        s2 += __shfl_xor(s2, mk, 64);
      }
      const float mu = s1 * (1.0f / 256.0f);
      const float rstd = rsqrtf(s2 * (1.0f / 256.0f) - mu * mu + 1e-5f);
      float4 v;
      v.x = (acc[r][0] - mu) * rstd * g1v[0] + e1v[0];
      v.y = (acc[r][1] - mu) * rstd * g1v[1] + e1v[1];
      v.z = (acc[r][2] - mu) * rstd * g1v[2] + e1v[2];
      v.w = (acc[r][3] - mu) * rstd * g1v[3] + e1v[3];
      *(float4*)(out + (size_t)(row0 + ty * 8 + r) * 256 + c0) = v;
    }
  }
}

// ---------------------------------------------------------------------------
// kv GEMM: concat[N,512] @ W_kv[512,768] + b -> LN(768) -> gelu ->
// key_new (fp32 + bf16 hi/lo), value_new (fp32), lr.
// ---------------------------------------------------------------------------
__global__ __launch_bounds__(256) void gemm_kv(
    const float* __restrict__ A1, const float* __restrict__ A2,
    const float* __restrict__ W, const float* __restrict__ bias,
    const float* __restrict__ gln, const float* __restrict__ bln,
    float* __restrict__ key_new, u16* __restrict__ knhi, u16* __restrict__ knlo,
    float* __restrict__ value_new, float* __restrict__ lr_out) {
  __shared__ float As[16][20];
  __shared__ float Bs[16][768];
  const int t = threadIdx.x;
  const int tx = t & 63;
  const int ty = t >> 6;
  const int row0 = blockIdx.x * 16;
  const int c0 = tx * 4;

  float acc[4][3][4];
#pragma unroll
  for (int r = 0; r < 4; r++)
#pragma unroll
    for (int g = 0; g < 3; g++)
#pragma unroll
      for (int j = 0; j < 4; j++) acc[r][g][j] = 0.f;

  for (int k0 = 0; k0 < 512; k0 += 16) {
    if (t < 64) {
      const int r = t & 15;
      const int kc = (t >> 4) * 4;
      const int kg = k0 + kc;
      const float* src = (kg < 256) ? A1 : A2;
      const float4 av =
          *(const float4*)(src + (size_t)(row0 + r) * 256 + (kg & 255));
      As[kc + 0][r] = av.x;
      As[kc + 1][r] = av.y;
      As[kc + 2][r] = av.z;
      As[kc + 3][r] = av.w;
    }
    {
      const int kk = t >> 4;
      const int bc = (t & 15) * 4;
#pragma unroll
      for (int j = 0; j < 12; j++)
        *(float4*)&Bs[kk][bc + j * 64] =
            *(const float4*)(W + (size_t)(k0 + kk) * 768 + bc + j * 64);
    }
    __syncthreads();
#pragma unroll
    for (int kk = 0; kk < 16; kk++) {
      const float4 a = *(const float4*)&As[kk][ty * 4];
      const float a4[4] = {a.x, a.y, a.z, a.w};
#pragma unroll
      for (int g = 0; g < 3; g++) {
        const float4 b = *(const float4*)&Bs[kk][g * 256 + c0];
#pragma unroll
        for (int r = 0; r < 4; r++) {
          acc[r][g][0] = fmaf(a4[r], b.x, acc[r][g][0]);
          acc[r][g][1] = fmaf(a4[r], b.y, acc[r][g][1]);
          acc[r][g][2] = fmaf(a4[r], b.z, acc[r][g][2]);
          acc[r][g][3] = fmaf(a4[r], b.w, acc[r][g][3]);
        }
      }
    }
    __syncthreads();
  }

  float bv[3][4], gw[3][4], ew[3][4];
#pragma unroll
  for (int g = 0; g < 3; g++)
#pragma unroll
    for (int j = 0; j < 4; j++) {
      bv[g][j] = bias[g * 256 + c0 + j];
      gw[g][j] = gln[g * 256 + c0 + j];
      ew[g][j] = bln[g * 256 + c0 + j];
    }

#pragma unroll
  for (int r = 0; r < 4; r++) {
    float s1 = 0.f, s2 = 0.f;
#pragma unroll
    for (int g = 0; g < 3; g++)
#pragma unroll
      for (int j = 0; j < 4; j++) {
        acc[r][g][j] += bv[g][j];
        s1 += acc[r][g][j];
        s2 += acc[r][g][j] * acc[r][g][j];
      }
#pragma unroll
    for (int mk = 1; mk < 64; mk <<= 1) {
      s1 += __shfl_xor(s1, mk, 64);
      s2 += __shfl_xor(s2, mk, 64);
    }
    const float mu = s1 * (1.0f / 768.0f);
    const float rstd = rsqrtf(s2 * (1.0f / 768.0f) - mu * mu + 1e-5f);
    const size_t orow = (size_t)(row0 + ty * 4 + r) * 256 + c0;
    float kq[4];
    float4 vv;
#pragma unroll
    for (int j = 0; j < 4; j++)
      kq[j] = gelu_f((acc[r][0][j] - mu) * rstd * gw[0][j] + ew[0][j]);
    vv.x = gelu_f((acc[r][1][0] - mu) * rstd * gw[1][0] + ew[1][0]);
    vv.y = gelu_f((acc[r][1][1] - mu) * rstd * gw[1][1] + ew[1][1]);
    vv.z = gelu_f((acc[r][1][2] - mu) * rstd * gw[1][2] + ew[1][2]);
    vv.w = gelu_f((acc[r][1][3] - mu) * rstd * gw[1][3] + ew[1][3]);
    *(float4*)(key_new + orow) = make_float4(kq[0], kq[1], kq[2], kq[3]);
    *(float4*)(value_new + orow) = vv;
    ushort4 hv, lv;
    u16 h;
    h = f2bf(kq[0]); hv.x = h; lv.x = f2bf(kq[0] - bf2f(h));
    h = f2bf(kq[1]); hv.y = h; lv.y = f2bf(kq[1] - bf2f(h));
    h = f2bf(kq[2]); hv.z = h; lv.z = f2bf(kq[2] - bf2f(h));
    h = f2bf(kq[3]); hv.w = h; lv.w = f2bf(kq[3] - bf2f(h));
    *(ushort4*)(knhi + orow) = hv;
    *(ushort4*)(knlo + orow) = lv;
    float ls = 0.f;
#pragma unroll
    for (int j = 0; j < 4; j++) {
      const float lvv = gelu_f((acc[r][2][j] - mu) * rstd * gw[2][j] + ew[2][j]);
      ls += 1.0f / (1.0f + __expf(-lvv));
    }
#pragma unroll
    for (int mk = 1; mk < 64; mk <<= 1) ls += __shfl_xor(ls, mk, 64);
    if (tx == 0) lr_out[row0 + ty * 4 + r] = ls * (1.0f / 256.0f);
  }
}

// ---------------------------------------------------------------------------
// Flash read via 3-product split-bf16 MFMA.
// Block: 128 threads = 2 waves, 64 tokens (32/wave). Grid 512.
// K staged [kstep][slot][32], V^T staged [dim][slot] (both conflict-free b128).
// Softmax: D-layout row reductions over 16 lanes; l via ones-MFMA (token layout).
// ---------------------------------------------------------------------------
__global__ __launch_bounds__(128, 2) void flash_mfma(
    const u16* __restrict__ qhi, const u16* __restrict__ qlo,
    const u16* __restrict__ khi, const u16* __restrict__ klo,
    const u16* __restrict__ vthi, const u16* __restrict__ vtlo,
    float* __restrict__ memout, float* __restrict__ surprise_out) {
  __shared__ u16 kv[2][8192];           // timeshared: K2 then VT, hi/lo
  __shared__ u16 pbuf[2][2][32][32];    // [wave][prec][tok][slot]
  __shared__ float scf[2][32];
  const int t = threadIdx.x;
  const int w = t >> 6;
  const int l = t & 63;
  const int s = l & 15;
  const int g = l >> 4;
  const int row0 = blockIdx.x * 64 + w * 32;

  f32x4_t o_acc[2][16];
  f32x4_t l_acc[2];
  float m_st[2][4];
#pragma unroll
  for (int mt = 0; mt < 2; mt++) {
#pragma unroll
    for (int nt = 0; nt < 16; nt++)
#pragma unroll
      for (int j = 0; j < 4; j++) o_acc[mt][nt][j] = 0.f;
#pragma unroll
    for (int j = 0; j < 4; j++) l_acc[mt][j] = 0.f;
#pragma unroll
    for (int q = 0; q < 4; q++) m_st[mt][q] = -INFINITY;
  }
  bf16x8_t ones;
#pragma unroll
  for (int j = 0; j < 8; j++) ones[j] = (short)0x3F80;

  const int kslot = t >> 2;  // 0..31
  const int ku = t & 3;

  for (int c0 = 0; c0 < SMEM; c0 += 32) {
    __syncthreads();
    // ---- stage K chunk: kv[prec][ks*1024 + slot*32 + kk] ----
#pragma unroll
    for (int i = 0; i < 8; i++) {
      const size_t go = (size_t)(c0 + kslot) * 256 + ku * 8 + i * 32;
      const int lo = i * 1024 + kslot * 32 + ku * 8;
      *(float4*)&kv[0][lo] = *(const float4*)(khi + go);
      *(float4*)&kv[1][lo] = *(const float4*)(klo + go);
    }
    __syncthreads();
    // ---- scores: S = Q @ K^T (3-product) ----
    f32x4_t sacc[2][2];
#pragma unroll
    for (int mt = 0; mt < 2; mt++)
#pragma unroll
      for (int nt = 0; nt < 2; nt++)
#pragma unroll
        for (int j = 0; j < 4; j++) sacc[mt][nt][j] = 0.f;

#pragma unroll
    for (int ks = 0; ks < 8; ks++) {
      bf16x8_t qh[2], ql[2];
#pragma unroll
      for (int mt = 0; mt < 2; mt++) {
        const size_t qo = (size_t)(row0 + mt * 16 + s) * 256 + ks * 32 + g * 8;
        qh[mt] = *(const bf16x8_t*)(qhi + qo);
        ql[mt] = *(const bf16x8_t*)(qlo + qo);
      }
#pragma unroll
      for (int nt = 0; nt < 2; nt++) {
        const int ko = ks * 1024 + (nt * 16 + s) * 32 + g * 8;
        const bf16x8_t kh = *(const bf16x8_t*)&kv[0][ko];
        const bf16x8_t kl = *(const bf16x8_t*)&kv[1][ko];
#pragma unroll
        for (int mt = 0; mt < 2; mt++) {
          sacc[mt][nt] = MFMA16(qh[mt], kh, sacc[mt][nt]);
          sacc[mt][nt] = MFMA16(ql[mt], kh, sacc[mt][nt]);
          sacc[mt][nt] = MFMA16(qh[mt], kl, sacc[mt][nt]);
        }
      }
    }
    // ---- online softmax (rows: tok = mt*16 + g*4 + q) ----
    float cmax[2][4];
    bool needb = false;
#pragma unroll
    for (int mt = 0; mt < 2; mt++)
#pragma unroll
      for (int q = 0; q < 4; q++) {
        float v = fmaxf(sacc[mt][0][q], sacc[mt][1][q]);
#pragma unroll
        for (int mk = 1; mk < 16; mk <<= 1) v = fmaxf(v, __shfl_xor(v, mk, 64));
        cmax[mt][q] = v;
        needb |= (v > m_st[mt][q]);
      }
    const bool need = (__ballot(needb) != 0ull);  // wave-uniform
#pragma unroll
    for (int mt = 0; mt < 2; mt++)
#pragma unroll
      for (int q = 0; q < 4; q++) {
        const float mold = m_st[mt][q];
        const float mnew = need ? fmaxf(mold, cmax[mt][q]) : mold;
        const float e0 = __expf(sacc[mt][0][q] - mnew);
        const float e1 = __expf(sacc[mt][1][q] - mnew);
        const int tok = mt * 16 + g * 4 + q;
        u16 h;
        h = f2bf(e0);
        pbuf[w][0][tok][s] = h;
        pbuf[w][1][tok][s] = f2bf(e0 - bf2f(h));
        h = f2bf(e1);
        pbuf[w][0][tok][16 + s] = h;
        pbuf[w][1][tok][16 + s] = f2bf(e1 - bf2f(h));
        if (need) {
          if (s == 0) scf[w][tok] = __expf(mold - mnew);
          m_st[mt][q] = mnew;
        }
      }
    __syncthreads();
    // ---- stage V^T chunk: kv[prec][dim*32 + sl] ----
#pragma unroll
    for (int i = 0; i < 8; i++) {
      const int gg = t + 128 * i;  // unit id: dim = gg>>2, su = gg&3
      const size_t go = (size_t)(gg >> 2) * 4096 + c0 + (gg & 3) * 8;
      *(float4*)&kv[0][gg * 8] = *(const float4*)(vthi + go);
      *(float4*)&kv[1][gg * 8] = *(const float4*)(vtlo + go);
    }
    __syncthreads();
    // ---- rescale (exact defer: only when max moved) ----
    if (need) {
      float scv[2];
      scv[0] = scf[w][s];
      scv[1] = scf[w][16 + s];
#pragma unroll
      for (int mt = 0; mt < 2; mt++) {
#pragma unroll
        for (int j = 0; j < 4; j++) l_acc[mt][j] *= scv[mt];
#pragma unroll
        for (int nt = 0; nt < 16; nt++)
#pragma unroll
          for (int j = 0; j < 4; j++) o_acc[mt][nt][j] *= scv[mt];
      }
    }
    // ---- P fragments + l update via ones-MFMA ----
    bf16x8_t ph[2], pl[2];
#pragma unroll
    for (int mt = 0; mt < 2; mt++) {
      ph[mt] = *(const bf16x8_t*)&pbuf[w][0][mt * 16 + s][g * 8];
      pl[mt] = *(const bf16x8_t*)&pbuf[w][1][mt * 16 + s][g * 8];
      l_acc[mt] = MFMA16(ones, ph[mt], l_acc[mt]);
      l_acc[mt] = MFMA16(ones, pl[mt], l_acc[mt]);
    }
    // ---- PV: O^T = V^T @ P^T (3-product) ----
#pragma unroll
    for (int nt = 0; nt < 16; nt++) {
      const int vo = (nt * 16 + s) * 32 + g * 8;
      const bf16x8_t vh = *(const bf16x8_t*)&kv[0][vo];
      const bf16x8_t vl = *(const bf16x8_t*)&kv[1][vo];
#pragma unroll
      for (int mt = 0; mt < 2; mt++) {
        o_acc[mt][nt] = MFMA16(vh, ph[mt], o_acc[mt][nt]);
        o_acc[mt][nt] = MFMA16(vl, ph[mt], o_acc[mt][nt]);
        o_acc[mt][nt] = MFMA16(vh, pl[mt], o_acc[mt][nt]);
      }
    }
  }
  // ---- epilogue: normalize + store ----
#pragma unroll
  for (int mt = 0; mt < 2; mt++) {
    const float li = 1.0f / l_acc[mt][0];
    if (g == 0) surprise_out[row0 + mt * 16 + s] = 1.0f - li;
    const size_t rb = (size_t)(row0 + mt * 16 + s) * 256;
#pragma unroll
    for (int nt = 0; nt < 16; nt++) {
      float4 v = make_float4(o_acc[mt][nt][0] * li, o_acc[mt][nt][1] * li,
                             o_acc[mt][nt][2] * li, o_acc[mt][nt][3] * li);
      *(float4*)(memout + rb + nt * 16 + g * 4) = v;
    }
  }
}

// ---------------------------------------------------------------------------
// wsim = key_new @ K_mem^T via 3-product MFMA; per-lane top-2 tracking;
// cross-lane merge at end -> cand1/cand2 (refined exactly afterwards).
// ---------------------------------------------------------------------------
__device__ __forceinline__ void top2_upd(float a, int ia, float& v1, int& i1,
                                         float& v2, int& i2) {
  if (a > v1 || (a == v1 && ia < i1)) {
    v2 = v1; i2 = i1; v1 = a; i1 = ia;
  } else if (a > v2 || (a == v2 && ia < i2)) {
    v2 = a; i2 = ia;
  }
}

__global__ __launch_bounds__(128, 2) void wsim_mfma(
    const u16* __restrict__ knhi, const u16* __restrict__ knlo,
    const u16* __restrict__ khi, const u16* __restrict__ klo,
    int* __restrict__ cand1, int* __restrict__ cand2) {
  __shared__ u16 kk2[2][8192];
  const int t = threadIdx.x;
  const int w = t >> 6;
  const int l = t & 63;
  const int s = l & 15;
  const int g = l >> 4;
  const int row0 = blockIdx.x * 64 + w * 32;

  bf16x8_t ah[2][8], al[2][8];
#pragma unroll
  for (int mt = 0; mt < 2; mt++)
#pragma unroll
    for (int ks = 0; ks < 8; ks++) {
      const size_t qo = (size_t)(row0 + mt * 16 + s) * 256 + ks * 32 + g * 8;
      ah[mt][ks] = *(const bf16x8_t*)(knhi + qo);
      al[mt][ks] = *(const bf16x8_t*)(knlo + qo);
    }
  float v1[2][4], v2[2][4];
  int i1[2][4], i2[2][4];
#pragma unroll
  for (int mt = 0; mt < 2; mt++)
#pragma unroll
    for (int q = 0; q < 4; q++) {
      v1[mt][q] = -INFINITY; v2[mt][q] = -INFINITY;
      i1[mt][q] = 0; i2[mt][q] = 0;
    }

  const int kslot = t >> 2;
  const int ku = t & 3;
  for (int c0 = 0; c0 < SMEM; c0 += 32) {
    __syncthreads();
#pragma unroll
    for (int i = 0; i < 8; i++) {
      const size_t go = (size_t)(c0 + kslot) * 256 + ku * 8 + i * 32;
      const int lo = i * 1024 + kslot * 32 + ku * 8;
      *(float4*)&kk2[0][lo] = *(const float4*)(khi + go);
      *(float4*)&kk2[1][lo] = *(const float4*)(klo + go);
    }
    __syncthreads();
    f32x4_t sacc[2][2];
#pragma unroll
    for (int mt = 0; mt < 2; mt++)
#pragma unroll
      for (int nt = 0; nt < 2; nt++)
#pragma unroll
        for (int j = 0; j < 4; j++) sacc[mt][nt][j] = 0.f;
#pragma unroll
    for (int ks = 0; ks < 8; ks++) {
#pragma unroll
      for (int nt = 0; nt < 2; nt++) {
        const int ko = ks * 1024 + (nt * 16 + s) * 32 + g * 8;
        const bf16x8_t kh = *(const bf16x8_t*)&kk2[0][ko];
        const bf16x8_t kl = *(const bf16x8_t*)&kk2[1][ko];
#pragma unroll
        for (int mt = 0; mt < 2; mt++) {
          sacc[mt][nt] = MFMA16(ah[mt][ks], kh, sacc[mt][nt]);
          sacc[mt][nt] = MFMA16(al[mt][ks], kh, sacc[mt][nt]);
          sacc[mt][nt] = MFMA16(ah[mt][ks], kl, sacc[mt][nt]);
        }
      }
    }
#pragma unroll
    for (int mt = 0; mt < 2; mt++)
#pragma unroll
      for (int q = 0; q < 4; q++) {
        top2_upd(sacc[mt][0][q], c0 + s, v1[mt][q], i1[mt][q], v2[mt][q],
                 i2[mt][q]);
        top2_upd(sacc[mt][1][q], c0 + 16 + s, v1[mt][q], i1[mt][q], v2[mt][q],
                 i2[mt][q]);
      }
  }
  // cross-lane merge over the 16 slot-lanes
#pragma unroll
  for (int mt = 0; mt < 2; mt++)
#pragma unroll
    for (int q = 0; q < 4; q++) {
#pragma unroll
      for (int mk = 1; mk < 16; mk <<= 1) {
        const float w1 = __shfl_xor(v1[mt][q], mk, 64);
        const int j1 = __shfl_xor(i1[mt][q], mk, 64);
        const float w2 = __shfl_xor(v2[mt][q], mk, 64);
        const int j2 = __shfl_xor(i2[mt][q], mk, 64);
        const bool take = (w1 > v1[mt][q]) || (w1 == v1[mt][q] && j1 < i1[mt][q]);
        const float ca = take ? v1[mt][q] : w1;
        const int ja = take ? i1[mt][q] : j1;
        const float cb = take ? w2 : v2[mt][q];
        const int jb = take ? j2 : i2[mt][q];
        v1[mt][q] = take ? w1 : v1[mt][q];
        i1[mt][q] = take ? j1 : i1[mt][q];
        const bool t2 = (cb > ca) || (cb == ca && jb < ja);
        v2[mt][q] = t2 ? cb : ca;
        i2[mt][q] = t2 ? jb : ja;
      }
      if (s == 0) {
        cand1[row0 + mt * 16 + g * 4 + q] = i1[mt][q];
        cand2[row0 + mt * 16 + g * 4 + q] = i2[mt][q];
      }
    }
}

// exact fp32 re-check of the two candidates -> final argmax index
__global__ __launch_bounds__(256) void refine_argmax(
    const float* __restrict__ kn, const float* __restrict__ Km,
    const int* __restrict__ cand1, const int* __restrict__ cand2,
    int* __restrict__ idx) {
  const int t = threadIdx.x;
  const int w = t >> 6;
  const int l = t & 63;
  const int tok = blockIdx.x * 4 + w;
  const int c1 = cand1[tok], c2 = cand2[tok];
  const float4 a = *(const float4*)(kn + (size_t)tok * 256 + l * 4);
  const float4 b1 = *(const float4*)(Km + (size_t)c1 * 256 + l * 4);
  const float4 b2 = *(const float4*)(Km + (size_t)c2 * 256 + l * 4);
  float d1 = a.x * b1.x + a.y * b1.y + a.z * b1.z + a.w * b1.w;
  float d2 = a.x * b2.x + a.y * b2.y + a.z * b2.z + a.w * b2.w;
#pragma unroll
  for (int mk = 1; mk < 64; mk <<= 1) {
    d1 += __shfl_xor(d1, mk, 64);
    d2 += __shfl_xor(d2, mk, 64);
  }
  if (l == 0) idx[tok] = (d2 > d1 || (d2 == d1 && c2 < c1)) ? c2 : c1;
}

// ---------------------------------------------------------------------------
__global__ void zero_kernel(float* __restrict__ p, int n) {
  int i = blockIdx.x * blockDim.x + threadIdx.x;
  const int stride = gridDim.x * blockDim.x;
  for (; i < n; i += stride) p[i] = 0.f;
}

__global__ __launch_bounds__(256) void scatter_write(
    const float* __restrict__ keyn, const float* __restrict__ valn,
    const float* __restrict__ surprise, const int* __restrict__ idx,
    float* __restrict__ gk, float* __restrict__ gv, float* __restrict__ gcnt) {
  const int t = threadIdx.x;
  const int tok = blockIdx.x * 32 + (t >> 3);
  const int h0 = (t & 7) * 32;
  const float gate = surprise[tok];
  const int s = idx[tok];
  const float* kf = keyn + (size_t)tok * 256 + h0;
  const float* vf = valn + (size_t)tok * 256 + h0;
  float* gks = gk + (size_t)s * 256 + h0;
  float* gvs = gv + (size_t)s * 256 + h0;
#pragma unroll
  for (int j = 0; j < 32; j += 4) {
    const float4 kvv = *(const float4*)(kf + j);
    const float4 vvv = *(const float4*)(vf + j);
    atomicAdd(gks + j + 0, gate * kvv.x);
    atomicAdd(gks + j + 1, gate * kvv.y);
    atomicAdd(gks + j + 2, gate * kvv.z);
    atomicAdd(gks + j + 3, gate * kvv.w);
    atomicAdd(gvs + j + 0, gate * vvv.x);
    atomicAdd(gvs + j + 1, gate * vvv.y);
    atomicAdd(gvs + j + 2, gate * vvv.z);
    atomicAdd(gvs + j + 3, gate * vvv.w);
  }
  if ((t & 7) == 0) atomicAdd(gcnt + s, gate);
}

__global__ void mem_update(const float* __restrict__ Km,
                           const float* __restrict__ Vm,
                           const float* __restrict__ gk,
                           const float* __restrict__ gv,
                           const float* __restrict__ gcnt,
                           float* __restrict__ Ko, float* __restrict__ Vo) {
  const int i = blockIdx.x * 256 + threadIdx.x;
  if (i < SMEM * 256) {
    const float c = gcnt[i >> 8];
    Ko[i] = Km[i] + 0.1f * (gk[i] - c * Km[i]);
    Vo[i] = Vm[i] + 0.1f * (gv[i] - c * Vm[i]);
  }
}

// ---------------------------------------------------------------------------
extern "C" void kernel_launch(void* const* d_in, const int* in_sizes, int n_in,
                              void* d_out, int out_size, void* d_ws,
                              size_t ws_size, hipStream_t stream) {
  const float* x = (const float*)d_in[0];
  const float* W_in = (const float*)d_in[1];
  const float* b_in = (const float*)d_in[2];
  const float* W_q = (const float*)d_in[3];
  const float* b_q = (const float*)d_in[4];
  const float* g_q = (const float*)d_in[5];
  const float* be_q = (const float*)d_in[6];
  const float* K_mem = (const float*)d_in[7];
  const float* V_mem = (const float*)d_in[8];
  const float* W_kv = (const float*)d_in[9];
  const float* b_kv = (const float*)d_in[10];
  const float* g_kv = (const float*)d_in[11];
  const float* be_kv = (const float*)d_in[12];
  const float* W_o = (const float*)d_in[13];
  const float* b_o = (const float*)d_in[14];
  const float* g_o = (const float*)d_in[15];
  const float* be_o = (const float*)d_in[16];
  const float* g_1 = (const float*)d_in[17];
  const float* be_1 = (const float*)d_in[18];

  // d_out: [out(N*256) | K_new(S*256) | V_new(S*256) | surprise(N) | lr(N)]
  float* out_main = (float*)d_out;
  float* out_K = out_main + (size_t)NTOK * 256;
  float* out_V = out_K + (size_t)SMEM * 256;
  float* out_sur = out_V + (size_t)SMEM * 256;
  float* out_lr = out_sur + NTOK;

  // workspace layout (float offsets)
  float* ws = (float*)d_ws;
  float* x_proj = ws + (size_t)0;         // 8388608
  float* memout = ws + (size_t)8388608;   // 8388608
  float* keynew = ws + (size_t)16777216;  // 8388608
  float* valnew = ws + (size_t)25165824;  // 8388608
  u16* qhi = (u16*)(ws + (size_t)33554432);
  u16* qlo = (u16*)(ws + (size_t)37748736);
  u16* knhi = (u16*)(ws + (size_t)41943040);
  u16* knlo = (u16*)(ws + (size_t)46137344);
  u16* khi = (u16*)(ws + (size_t)50331648);
  u16* klo = (u16*)(ws + (size_t)50855936);
  u16* vthi = (u16*)(ws + (size_t)51380224);
  u16* vtlo = (u16*)(ws + (size_t)51904512);
  float* gk = ws + (size_t)52428800;      // 1048576
  float* gv = ws + (size_t)53477376;      // 1048576
  float* gcnt = ws + (size_t)54525952;    // 4096
  int* cand1 = (int*)(ws + (size_t)54530048);
  int* cand2 = (int*)(ws + (size_t)54562816);
  int* idx = (int*)(ws + (size_t)54595584);

  const dim3 b256(256), b128(128);
  // prep: bf16 splits of K_mem and transposed V_mem
  split_k<<<512, b256, 0, stream>>>(K_mem, khi, klo);
  vt_split<<<128, b256, 0, stream>>>(V_mem, vthi, vtlo);
  // 1. x_proj = x@W_in + b_in
  gemm256<256, 0><<<NTOK / 32, b256, 0, stream>>>(
      x, nullptr, W_in, b_in, nullptr, nullptr, nullptr, nullptr, nullptr,
      x_proj, nullptr, nullptr);
  // 2. query/16 -> bf16 hi/lo
  gemm256<256, 1><<<NTOK / 32, b256, 0, stream>>>(
      x_proj, nullptr, W_q, b_q, g_q, be_q, nullptr, nullptr, nullptr, nullptr,
      qhi, qlo);
  // 3. flash attention read -> memout + surprise
  flash_mfma<<<NTOK / 64, b128, 0, stream>>>(qhi, qlo, khi, klo, vthi, vtlo,
                                             memout, out_sur);
  // 4. kv GEMM -> key_new (fp32 + bf16), value_new, lr
  gemm_kv<<<NTOK / 16, b256, 0, stream>>>(x_proj, memout, W_kv, b_kv, g_kv,
                                          be_kv, keynew, knhi, knlo, valnew,
                                          out_lr);
  // 5. wsim top-2 candidates
  wsim_mfma<<<NTOK / 64, b128, 0, stream>>>(knhi, knlo, khi, klo, cand1, cand2);
  // 6. exact fp32 refine -> idx
  refine_argmax<<<NTOK / 4, b256, 0, stream>>>(keynew, K_mem, cand1, cand2,
                                               idx);
  // 7. zero accumulators
  zero_kernel<<<2048, b256, 0, stream>>>(gk, 2 * SMEM * 256 + SMEM);
  // 8. surprise-gated scatter
  scatter_write<<<NTOK / 32, b256, 0, stream>>>(keynew, valnew, out_sur, idx,
                                                gk, gv, gcnt);
  // 9. K_new/V_new
  mem_update<<<SMEM * 256 / 256, b256, 0, stream>>>(K_mem, V_mem, gk, gv, gcnt,
                                                    out_K, out_V);
  // 10. out = LN(LN(concat@W_o + b_o) + x_proj)
  gemm256<512, 2><<<NTOK / 32, b256, 0, stream>>>(
      x_proj, memout, W_o, b_o, g_o, be_o, g_1, be_1, x_proj, out_main,
      nullptr, nullptr);
}

// Round 4
// 3839.145 us; speedup vs baseline: 1.4073x; 1.4073x over previous
//
#include <hip/hip_runtime.h>
#include <math.h>

// Shapes fixed by setup_inputs: B=4, T=8192 -> N=32768 tokens, D=256, H=256, S=4096.
#define NTOK 32768
#define SMEM 4096

typedef unsigned short u16;
typedef __attribute__((ext_vector_type(8))) short bf16x8_t;
typedef __attribute__((ext_vector_type(4))) float f32x4_t;

#define MFMA16(A, B, C) __builtin_amdgcn_mfma_f32_16x16x32_bf16(A, B, C, 0, 0, 0)

__device__ __forceinline__ float gelu_f(float x) {
  return 0.5f * x * (1.0f + erff(x * 0.7071067811865475f));
}
// round-to-nearest-even f32 -> bf16 (as u16 bits)
__device__ __forceinline__ u16 f2bf(float x) {
  unsigned u = __float_as_uint(x);
  return (u16)((u + 0x7FFFu + ((u >> 16) & 1u)) >> 16);
}
__device__ __forceinline__ float bf2f(u16 h) {
  return __uint_as_float(((unsigned)h) << 16);
}

// ---------------------------------------------------------------------------
// Prep 1: elementwise split K_mem -> khi/klo (bf16 hi + residual lo)
// ---------------------------------------------------------------------------
__global__ __launch_bounds__(256) void split_k(const float* __restrict__ K,
                                               u16* __restrict__ khi,
                                               u16* __restrict__ klo) {
  const int i8 = (blockIdx.x * 256 + threadIdx.x) * 8;  // grid sized exactly
  union { u16 u[8]; float4 f; } H, L;
#pragma unroll
  for (int j = 0; j < 8; j++) {
    const float v = K[i8 + j];
    const u16 h = f2bf(v);
    H.u[j] = h;
    L.u[j] = f2bf(v - bf2f(h));
  }
  *(float4*)(khi + i8) = H.f;
  *(float4*)(klo + i8) = L.f;
}

// ---------------------------------------------------------------------------
// Prep 2: V_mem[4096][256] -> vthi/vtlo transposed [256][4096] bf16 hi/lo
// ---------------------------------------------------------------------------
__global__ __launch_bounds__(256) void vt_split(const float* __restrict__ V,
                                                u16* __restrict__ vthi,
                                                u16* __restrict__ vtlo) {
  __shared__ float Vs[32][260];
  const int t = threadIdx.x;
  const int s0 = (blockIdx.x & 15) * 256;  // slot tile
  const int d0 = (blockIdx.x >> 4) * 32;   // dim tile
#pragma unroll
  for (int m = 0; m < 8; m++) {
    const int r = (t >> 3) + 32 * m;  // slot-local row
    const float4 v =
        *(const float4*)(V + (size_t)(s0 + r) * 256 + d0 + (t & 7) * 4);
    Vs[(t & 7) * 4 + 0][r] = v.x;
    Vs[(t & 7) * 4 + 1][r] = v.y;
    Vs[(t & 7) * 4 + 2][r] = v.z;
    Vs[(t & 7) * 4 + 3][r] = v.w;
  }
  __syncthreads();
  const int dl = t >> 3;          // dim-local 0..31
  const int sl0 = (t & 7) * 32;   // slot-local base
  union { u16 u[8]; float4 f; } H[4], L[4];
#pragma unroll
  for (int i = 0; i < 8; i++) {
    const float4 v = *(const float4*)&Vs[dl][sl0 + i * 4];
    const float vv[4] = {v.x, v.y, v.z, v.w};
#pragma unroll
    for (int j = 0; j < 4; j++) {
      const u16 h = f2bf(vv[j]);
      H[i >> 1].u[(i & 1) * 4 + j] = h;
      L[i >> 1].u[(i & 1) * 4 + j] = f2bf(vv[j] - bf2f(h));
    }
  }
  const size_t ob = (size_t)(d0 + dl) * 4096 + s0 + sl0;
#pragma unroll
  for (int i = 0; i < 4; i++) {
    *(float4*)(vthi + ob + i * 8) = H[i].f;
    *(float4*)(vtlo + ob + i * 8) = L[i].f;
  }
}

// ---------------------------------------------------------------------------
// GEMM BN=256, BM=32, KSTEP=32, 256 threads.
// EPI==0: out = A@W + b                                (x_proj, fp32)
// EPI==1: bf16split(gelu(LN(A@W+b)) * 0.0625) -> bh,bl (query/16)
// EPI==2: out = LN(LN(A@W+b) + ident)                  (final out, fp32)
// ---------------------------------------------------------------------------
template <int KDIM, int EPI>
__global__ __launch_bounds__(256) void gemm256(
    const float* __restrict__ A1, const float* __restrict__ A2,
    const float* __restrict__ W, const float* __restrict__ bias,
    const float* __restrict__ g0, const float* __restrict__ be0,
    const float* __restrict__ g1, const float* __restrict__ be1,
    const float* __restrict__ ident, float* __restrict__ out,
    u16* __restrict__ bh, u16* __restrict__ bl) {
  __shared__ float As[32][36];
  __shared__ float Bs[32][256];
  const int t = threadIdx.x;
  const int tx = t & 63;
  const int ty = t >> 6;
  const int row0 = blockIdx.x * 32;
  const int c0 = tx * 4;

  float acc[8][4];
#pragma unroll
  for (int r = 0; r < 8; r++)
#pragma unroll
    for (int j = 0; j < 4; j++) acc[r][j] = 0.f;

  const int ar = t >> 3;
  const int akc = (t & 7) * 4;

  for (int k0 = 0; k0 < KDIM; k0 += 32) {
    float4 av;
    if (KDIM == 512) {
      const int kg = k0 + akc;
      const float* src = (kg < 256) ? A1 : A2;
      av = *(const float4*)(src + (size_t)(row0 + ar) * 256 + (kg & 255));
    } else {
      av = *(const float4*)(A1 + (size_t)(row0 + ar) * 256 + k0 + akc);
    }
    As[akc + 0][ar] = av.x;
    As[akc + 1][ar] = av.y;
    As[akc + 2][ar] = av.z;
    As[akc + 3][ar] = av.w;
#pragma unroll
    for (int j = 0; j < 8; j++) {
      *(float4*)&Bs[ar][akc + j * 32] =
          *(const float4*)(W + (size_t)(k0 + ar) * 256 + akc + j * 32);
    }
    __syncthreads();
#pragma unroll
    for (int kk = 0; kk < 32; kk++) {
      const float4 bv = *(const float4*)&Bs[kk][c0];
      const float4 a0 = *(const float4*)&As[kk][ty * 8];
      const float4 a1 = *(const float4*)&As[kk][ty * 8 + 4];
      const float a8[8] = {a0.x, a0.y, a0.z, a0.w, a1.x, a1.y, a1.z, a1.w};
      const float b4[4] = {bv.x, bv.y, bv.z, bv.w};
#pragma unroll
      for (int r = 0; r < 8; r++)
#pragma unroll
        for (int j = 0; j < 4; j++) acc[r][j] = fmaf(a8[r], b4[j], acc[r][j]);
    }
    __syncthreads();
  }

  float bb[4];
#pragma unroll
  for (int j = 0; j < 4; j++) bb[j] = bias[c0 + j];
#pragma unroll
  for (int r = 0; r < 8; r++)
#pragma unroll
    for (int j = 0; j < 4; j++) acc[r][j] += bb[j];

  if (EPI == 0) {
#pragma unroll
    for (int r = 0; r < 8; r++) {
      float4 v = make_float4(acc[r][0], acc[r][1], acc[r][2], acc[r][3]);
      *(float4*)(out + (size_t)(row0 + ty * 8 + r) * 256 + c0) = v;
    }
    return;
  }

  float gg[4], ee[4];
#pragma unroll
  for (int j = 0; j < 4; j++) {
    gg[j] = g0[c0 + j];
    ee[j] = be0[c0 + j];
  }

#pragma unroll
  for (int r = 0; r < 8; r++) {
    float s1 = acc[r][0] + acc[r][1] + acc[r][2] + acc[r][3];
    float s2 = acc[r][0] * acc[r][0] + acc[r][1] * acc[r][1] +
               acc[r][2] * acc[r][2] + acc[r][3] * acc[r][3];
#pragma unroll
    for (int mk = 1; mk < 64; mk <<= 1) {
      s1 += __shfl_xor(s1, mk, 64);
      s2 += __shfl_xor(s2, mk, 64);
    }
    const float mu = s1 * (1.0f / 256.0f);
    const float rstd = rsqrtf(s2 * (1.0f / 256.0f) - mu * mu + 1e-5f);
    if (EPI == 1) {
      float q[4];
#pragma unroll
      for (int j = 0; j < 4; j++)
        q[j] = gelu_f((acc[r][j] - mu) * rstd * gg[j] + ee[j]) * 0.0625f;
      ushort4 hv, lv;
      u16 h;
      h = f2bf(q[0]); hv.x = h; lv.x = f2bf(q[0] - bf2f(h));
      h = f2bf(q[1]); hv.y = h; lv.y = f2bf(q[1] - bf2f(h));
      h = f2bf(q[2]); hv.z = h; lv.z = f2bf(q[2] - bf2f(h));
      h = f2bf(q[3]); hv.w = h; lv.w = f2bf(q[3] - bf2f(h));
      const size_t o = (size_t)(row0 + ty * 8 + r) * 256 + c0;
      *(ushort4*)(bh + o) = hv;
      *(ushort4*)(bl + o) = lv;
    } else {
      const float4 idv =
          *(const float4*)(ident + (size_t)(row0 + ty * 8 + r) * 256 + c0);
      acc[r][0] = (acc[r][0] - mu) * rstd * gg[0] + ee[0] + idv.x;
      acc[r][1] = (acc[r][1] - mu) * rstd * gg[1] + ee[1] + idv.y;
      acc[r][2] = (acc[r][2] - mu) * rstd * gg[2] + ee[2] + idv.z;
      acc[r][3] = (acc[r][3] - mu) * rstd * gg[3] + ee[3] + idv.w;
    }
  }

  if (EPI == 2) {
    float g1v[4], e1v[4];
#pragma unroll
    for (int j = 0; j < 4; j++) {
      g1v[j] = g1[c0 + j];
      e1v[j] = be1[c0 + j];
    }
#pragma unroll
    for (int r = 0; r < 8; r++) {
      float s1 = acc[r][0] + acc[r][1] + acc[r][2] + acc[r][3];
      float s2 = acc[r][0] * acc[r][0] + acc[r][1] * acc[r][1] +
                 acc[r][2] * acc[r][2] + acc[r][3] * acc[r][3];
#pragma unroll
      for (int mk = 1; mk < 64; mk <<= 1) {
        s1 += __shfl_xor(s1, mk, 64);
        s2 += __shfl_xor(s2, mk, 64);
      }
      const float mu = s1 * (1.0f / 256.0f);
      const float rstd = rsqrtf(s2 * (1.0f / 256.0f) - mu * mu + 1e-5f);
      float4 v;
      v.x = (acc[r][0] - mu) * rstd * g1v[0] + e1v[0];
      v.y = (acc[r][1] - mu) * rstd * g1v[1] + e1v[1];
      v.z = (acc[r][2] - mu) * rstd * g1v[2] + e1v[2];
      v.w = (acc[r][3] - mu) * rstd * g1v[3] + e1v[3];
      *(float4*)(out + (size_t)(row0 + ty * 8 + r) * 256 + c0) = v;
    }
  }
}

// ---------------------------------------------------------------------------
// kv GEMM: concat[N,512] @ W_kv[512,768] + b -> LN(768) -> gelu ->
// key_new (fp32 + bf16 hi/lo), value_new (fp32), lr.
// ---------------------------------------------------------------------------
__global__ __launch_bounds__(256) void gemm_kv(
    const float* __restrict__ A1, const float* __restrict__ A2,
    const float* __restrict__ W, const float* __restrict__ bias,
    const float* __restrict__ gln, const float* __restrict__ bln,
    float* __restrict__ key_new, u16* __restrict__ knhi, u16* __restrict__ knlo,
    float* __restrict__ value_new, float* __restrict__ lr_out) {
  __shared__ float As[16][20];
  __shared__ float Bs[16][768];
  const int t = threadIdx.x;
  const int tx = t & 63;
  const int ty = t >> 6;
  const int row0 = blockIdx.x * 16;
  const int c0 = tx * 4;

  float acc[4][3][4];
#pragma unroll
  for (int r = 0; r < 4; r++)
#pragma unroll
    for (int g = 0; g < 3; g++)
#pragma unroll
      for (int j = 0; j < 4; j++) acc[r][g][j] = 0.f;

  for (int k0 = 0; k0 < 512; k0 += 16) {
    if (t < 64) {
      const int r = t & 15;
      const int kc = (t >> 4) * 4;
      const int kg = k0 + kc;
      const float* src = (kg < 256) ? A1 : A2;
      const float4 av =
          *(const float4*)(src + (size_t)(row0 + r) * 256 + (kg & 255));
      As[kc + 0][r] = av.x;
      As[kc + 1][r] = av.y;
      As[kc + 2][r] = av.z;
      As[kc + 3][r] = av.w;
    }
    {
      const int kk = t >> 4;
      const int bc = (t & 15) * 4;
#pragma unroll
      for (int j = 0; j < 12; j++)
        *(float4*)&Bs[kk][bc + j * 64] =
            *(const float4*)(W + (size_t)(k0 + kk) * 768 + bc + j * 64);
    }
    __syncthreads();
#pragma unroll
    for (int kk = 0; kk < 16; kk++) {
      const float4 a = *(const float4*)&As[kk][ty * 4];
      const float a4[4] = {a.x, a.y, a.z, a.w};
#pragma unroll
      for (int g = 0; g < 3; g++) {
        const float4 b = *(const float4*)&Bs[kk][g * 256 + c0];
#pragma unroll
        for (int r = 0; r < 4; r++) {
          acc[r][g][0] = fmaf(a4[r], b.x, acc[r][g][0]);
          acc[r][g][1] = fmaf(a4[r], b.y, acc[r][g][1]);
          acc[r][g][2] = fmaf(a4[r], b.z, acc[r][g][2]);
          acc[r][g][3] = fmaf(a4[r], b.w, acc[r][g][3]);
        }
      }
    }
    __syncthreads();
  }

  float bv[3][4], gw[3][4], ew[3][4];
#pragma unroll
  for (int g = 0; g < 3; g++)
#pragma unroll
    for (int j = 0; j < 4; j++) {
      bv[g][j] = bias[g * 256 + c0 + j];
      gw[g][j] = gln[g * 256 + c0 + j];
      ew[g][j] = bln[g * 256 + c0 + j];
    }

#pragma unroll
  for (int r = 0; r < 4; r++) {
    float s1 = 0.f, s2 = 0.f;
#pragma unroll
    for (int g = 0; g < 3; g++)
#pragma unroll
      for (int j = 0; j < 4; j++) {
        acc[r][g][j] += bv[g][j];
        s1 += acc[r][g][j];
        s2 += acc[r][g][j] * acc[r][g][j];
      }
#pragma unroll
    for (int mk = 1; mk < 64; mk <<= 1) {
      s1 += __shfl_xor(s1, mk, 64);
      s2 += __shfl_xor(s2, mk, 64);
    }
    const float mu = s1 * (1.0f / 768.0f);
    const float rstd = rsqrtf(s2 * (1.0f / 768.0f) - mu * mu + 1e-5f);
    const size_t orow = (size_t)(row0 + ty * 4 + r) * 256 + c0;
    float kq[4];
    float4 vv;
#pragma unroll
    for (int j = 0; j < 4; j++)
      kq[j] = gelu_f((acc[r][0][j] - mu) * rstd * gw[0][j] + ew[0][j]);
    vv.x = gelu_f((acc[r][1][0] - mu) * rstd * gw[1][0] + ew[1][0]);
    vv.y = gelu_f((acc[r][1][1] - mu) * rstd * gw[1][1] + ew[1][1]);
    vv.z = gelu_f((acc[r][1][2] - mu) * rstd * gw[1][2] + ew[1][2]);
    vv.w = gelu_f((acc[r][1][3] - mu) * rstd * gw[1][3] + ew[1][3]);
    *(float4*)(key_new + orow) = make_float4(kq[0], kq[1], kq[2], kq[3]);
    *(float4*)(value_new + orow) = vv;
    ushort4 hv, lv;
    u16 h;
    h = f2bf(kq[0]); hv.x = h; lv.x = f2bf(kq[0] - bf2f(h));
    h = f2bf(kq[1]); hv.y = h; lv.y = f2bf(kq[1] - bf2f(h));
    h = f2bf(kq[2]); hv.z = h; lv.z = f2bf(kq[2] - bf2f(h));
    h = f2bf(kq[3]); hv.w = h; lv.w = f2bf(kq[3] - bf2f(h));
    *(ushort4*)(knhi + orow) = hv;
    *(ushort4*)(knlo + orow) = lv;
    float ls = 0.f;
#pragma unroll
    for (int j = 0; j < 4; j++) {
      const float lvv = gelu_f((acc[r][2][j] - mu) * rstd * gw[2][j] + ew[2][j]);
      ls += 1.0f / (1.0f + __expf(-lvv));
    }
#pragma unroll
    for (int mk = 1; mk < 64; mk <<= 1) ls += __shfl_xor(ls, mk, 64);
    if (tx == 0) lr_out[row0 + ty * 4 + r] = ls * (1.0f / 256.0f);
  }
}

// ---------------------------------------------------------------------------
// Flash read via 3-product split-bf16 MFMA. 128 thr = 2 waves, 32 tok/wave.
// ---------------------------------------------------------------------------
__global__ __launch_bounds__(128, 2) void flash_mfma(
    const u16* __restrict__ qhi, const u16* __restrict__ qlo,
    const u16* __restrict__ khi, const u16* __restrict__ klo,
    const u16* __restrict__ vthi, const u16* __restrict__ vtlo,
    float* __restrict__ memout, float* __restrict__ surprise_out) {
  __shared__ u16 kv[2][8192];           // timeshared: K2 then VT, hi/lo
  __shared__ u16 pbuf[2][2][32][32];    // [wave][prec][tok][slot]
  __shared__ float scf[2][32];
  const int t = threadIdx.x;
  const int w = t >> 6;
  const int l = t & 63;
  const int s = l & 15;
  const int g = l >> 4;
  const int row0 = blockIdx.x * 64 + w * 32;

  f32x4_t o_acc[2][16];
  f32x4_t l_acc[2];
  float m_st[2][4];
#pragma unroll
  for (int mt = 0; mt < 2; mt++) {
#pragma unroll
    for (int nt = 0; nt < 16; nt++)
#pragma unroll
      for (int j = 0; j < 4; j++) o_acc[mt][nt][j] = 0.f;
#pragma unroll
    for (int j = 0; j < 4; j++) l_acc[mt][j] = 0.f;
#pragma unroll
    for (int q = 0; q < 4; q++) m_st[mt][q] = -INFINITY;
  }
  bf16x8_t ones;
#pragma unroll
  for (int j = 0; j < 8; j++) ones[j] = (short)0x3F80;

  const int kslot = t >> 2;  // 0..31
  const int ku = t & 3;

  for (int c0 = 0; c0 < SMEM; c0 += 32) {
    __syncthreads();
    // ---- stage K chunk: kv[prec][ks*1024 + slot*32 + kk] ----
#pragma unroll
    for (int i = 0; i < 8; i++) {
      const size_t go = (size_t)(c0 + kslot) * 256 + ku * 8 + i * 32;
      const int lo = i * 1024 + kslot * 32 + ku * 8;
      *(float4*)&kv[0][lo] = *(const float4*)(khi + go);
      *(float4*)&kv[1][lo] = *(const float4*)(klo + go);
    }
    __syncthreads();
    // ---- scores: S = Q @ K^T (3-product) ----
    f32x4_t sacc[2][2];
#pragma unroll
    for (int mt = 0; mt < 2; mt++)
#pragma unroll
      for (int nt = 0; nt < 2; nt++)
#pragma unroll
        for (int j = 0; j < 4; j++) sacc[mt][nt][j] = 0.f;

#pragma unroll
    for (int ks = 0; ks < 8; ks++) {
      bf16x8_t qh[2], ql[2];
#pragma unroll
      for (int mt = 0; mt < 2; mt++) {
        const size_t qo = (size_t)(row0 + mt * 16 + s) * 256 + ks * 32 + g * 8;
        qh[mt] = *(const bf16x8_t*)(qhi + qo);
        ql[mt] = *(const bf16x8_t*)(qlo + qo);
      }
#pragma unroll
      for (int nt = 0; nt < 2; nt++) {
        const int ko = ks * 1024 + (nt * 16 + s) * 32 + g * 8;
        const bf16x8_t kh = *(const bf16x8_t*)&kv[0][ko];
        const bf16x8_t kl = *(const bf16x8_t*)&kv[1][ko];
#pragma unroll
        for (int mt = 0; mt < 2; mt++) {
          sacc[mt][nt] = MFMA16(qh[mt], kh, sacc[mt][nt]);
          sacc[mt][nt] = MFMA16(ql[mt], kh, sacc[mt][nt]);
          sacc[mt][nt] = MFMA16(qh[mt], kl, sacc[mt][nt]);
        }
      }
    }
    // ---- online softmax (rows: tok = mt*16 + g*4 + q) ----
    float cmax[2][4];
    bool needb = false;
#pragma unroll
    for (int mt = 0; mt < 2; mt++)
#pragma unroll
      for (int q = 0; q < 4; q++) {
        float v = fmaxf(sacc[mt][0][q], sacc[mt][1][q]);
#pragma unroll
        for (int mk = 1; mk < 16; mk <<= 1) v = fmaxf(v, __shfl_xor(v, mk, 64));
        cmax[mt][q] = v;
        needb |= (v > m_st[mt][q]);
      }
    const bool need = (__ballot(needb) != 0ull);  // wave-uniform
#pragma unroll
    for (int mt = 0; mt < 2; mt++)
#pragma unroll
      for (int q = 0; q < 4; q++) {
        const float mold = m_st[mt][q];
        const float mnew = need ? fmaxf(mold, cmax[mt][q]) : mold;
        const float e0 = __expf(sacc[mt][0][q] - mnew);
        const float e1 = __expf(sacc[mt][1][q] - mnew);
        const int tok = mt * 16 + g * 4 + q;
        u16 h;
        h = f2bf(e0);
        pbuf[w][0][tok][s] = h;
        pbuf[w][1][tok][s] = f2bf(e0 - bf2f(h));
        h = f2bf(e1);
        pbuf[w][0][tok][16 + s] = h;
        pbuf[w][1][tok][16 + s] = f2bf(e1 - bf2f(h));
        if (need) {
          if (s == 0) scf[w][tok] = __expf(mold - mnew);
          m_st[mt][q] = mnew;
        }
      }
    __syncthreads();
    // ---- stage V^T chunk: kv[prec][dim*32 + sl] ----
#pragma unroll
    for (int i = 0; i < 8; i++) {
      const int gg = t + 128 * i;  // unit id: dim = gg>>2, su = gg&3
      const size_t go = (size_t)(gg >> 2) * 4096 + c0 + (gg & 3) * 8;
      *(float4*)&kv[0][gg * 8] = *(const float4*)(vthi + go);
      *(float4*)&kv[1][gg * 8] = *(const float4*)(vtlo + go);
    }
    __syncthreads();
    // ---- rescale (exact defer: only when max moved) ----
    if (need) {
      float scv[2];
      scv[0] = scf[w][s];
      scv[1] = scf[w][16 + s];
#pragma unroll
      for (int mt = 0; mt < 2; mt++) {
#pragma unroll
        for (int j = 0; j < 4; j++) l_acc[mt][j] *= scv[mt];
#pragma unroll
        for (int nt = 0; nt < 16; nt++)
#pragma unroll
          for (int j = 0; j < 4; j++) o_acc[mt][nt][j] *= scv[mt];
      }
    }
    // ---- P fragments + l update via ones-MFMA ----
    bf16x8_t ph[2], pl[2];
#pragma unroll
    for (int mt = 0; mt < 2; mt++) {
      ph[mt] = *(const bf16x8_t*)&pbuf[w][0][mt * 16 + s][g * 8];
      pl[mt] = *(const bf16x8_t*)&pbuf[w][1][mt * 16 + s][g * 8];
      l_acc[mt] = MFMA16(ones, ph[mt], l_acc[mt]);
      l_acc[mt] = MFMA16(ones, pl[mt], l_acc[mt]);
    }
    // ---- PV: O^T = V^T @ P^T (3-product) ----
#pragma unroll
    for (int nt = 0; nt < 16; nt++) {
      const int vo = (nt * 16 + s) * 32 + g * 8;
      const bf16x8_t vh = *(const bf16x8_t*)&kv[0][vo];
      const bf16x8_t vl = *(const bf16x8_t*)&kv[1][vo];
#pragma unroll
      for (int mt = 0; mt < 2; mt++) {
        o_acc[mt][nt] = MFMA16(vh, ph[mt], o_acc[mt][nt]);
        o_acc[mt][nt] = MFMA16(vl, ph[mt], o_acc[mt][nt]);
        o_acc[mt][nt] = MFMA16(vh, pl[mt], o_acc[mt][nt]);
      }
    }
  }
  // ---- epilogue: normalize + store ----
#pragma unroll
  for (int mt = 0; mt < 2; mt++) {
    const float li = 1.0f / l_acc[mt][0];
    if (g == 0) surprise_out[row0 + mt * 16 + s] = 1.0f - li;
    const size_t rb = (size_t)(row0 + mt * 16 + s) * 256;
#pragma unroll
    for (int nt = 0; nt < 16; nt++) {
      float4 v = make_float4(o_acc[mt][nt][0] * li, o_acc[mt][nt][1] * li,
                             o_acc[mt][nt][2] * li, o_acc[mt][nt][3] * li);
      *(float4*)(memout + rb + nt * 16 + g * 4) = v;
    }
  }
}

// ---------------------------------------------------------------------------
// wsim = key_new @ K_mem^T via 3-product MFMA; per-lane top-2 tracking.
// ---------------------------------------------------------------------------
__device__ __forceinline__ void top2_upd(float a, int ia, float& v1, int& i1,
                                         float& v2, int& i2) {
  if (a > v1 || (a == v1 && ia < i1)) {
    v2 = v1; i2 = i1; v1 = a; i1 = ia;
  } else if (a > v2 || (a == v2 && ia < i2)) {
    v2 = a; i2 = ia;
  }
}

__global__ __launch_bounds__(128, 2) void wsim_mfma(
    const u16* __restrict__ knhi, const u16* __restrict__ knlo,
    const u16* __restrict__ khi, const u16* __restrict__ klo,
    int* __restrict__ cand1, int* __restrict__ cand2) {
  __shared__ u16 kk2[2][8192];
  const int t = threadIdx.x;
  const int w = t >> 6;
  const int l = t & 63;
  const int s = l & 15;
  const int g = l >> 4;
  const int row0 = blockIdx.x * 64 + w * 32;

  bf16x8_t ah[2][8], al[2][8];
#pragma unroll
  for (int mt = 0; mt < 2; mt++)
#pragma unroll
    for (int ks = 0; ks < 8; ks++) {
      const size_t qo = (size_t)(row0 + mt * 16 + s) * 256 + ks * 32 + g * 8;
      ah[mt][ks] = *(const bf16x8_t*)(knhi + qo);
      al[mt][ks] = *(const bf16x8_t*)(knlo + qo);
    }
  float v1[2][4], v2[2][4];
  int i1[2][4], i2[2][4];
#pragma unroll
  for (int mt = 0; mt < 2; mt++)
#pragma unroll
    for (int q = 0; q < 4; q++) {
      v1[mt][q] = -INFINITY; v2[mt][q] = -INFINITY;
      i1[mt][q] = 0; i2[mt][q] = 0;
    }

  const int kslot = t >> 2;
  const int ku = t & 3;
  for (int c0 = 0; c0 < SMEM; c0 += 32) {
    __syncthreads();
#pragma unroll
    for (int i = 0; i < 8; i++) {
      const size_t go = (size_t)(c0 + kslot) * 256 + ku * 8 + i * 32;
      const int lo = i * 1024 + kslot * 32 + ku * 8;
      *(float4*)&kk2[0][lo] = *(const float4*)(khi + go);
      *(float4*)&kk2[1][lo] = *(const float4*)(klo + go);
    }
    __syncthreads();
    f32x4_t sacc[2][2];
#pragma unroll
    for (int mt = 0; mt < 2; mt++)
#pragma unroll
      for (int nt = 0; nt < 2; nt++)
#pragma unroll
        for (int j = 0; j < 4; j++) sacc[mt][nt][j] = 0.f;
#pragma unroll
    for (int ks = 0; ks < 8; ks++) {
#pragma unroll
      for (int nt = 0; nt < 2; nt++) {
        const int ko = ks * 1024 + (nt * 16 + s) * 32 + g * 8;
        const bf16x8_t kh = *(const bf16x8_t*)&kk2[0][ko];
        const bf16x8_t kl = *(const bf16x8_t*)&kk2[1][ko];
#pragma unroll
        for (int mt = 0; mt < 2; mt++) {
          sacc[mt][nt] = MFMA16(ah[mt][ks], kh, sacc[mt][nt]);
          sacc[mt][nt] = MFMA16(al[mt][ks], kh, sacc[mt][nt]);
          sacc[mt][nt] = MFMA16(ah[mt][ks], kl, sacc[mt][nt]);
        }
      }
    }
#pragma unroll
    for (int mt = 0; mt < 2; mt++)
#pragma unroll
      for (int q = 0; q < 4; q++) {
        top2_upd(sacc[mt][0][q], c0 + s, v1[mt][q], i1[mt][q], v2[mt][q],
                 i2[mt][q]);
        top2_upd(sacc[mt][1][q], c0 + 16 + s, v1[mt][q], i1[mt][q], v2[mt][q],
                 i2[mt][q]);
      }
  }
  // cross-lane merge over the 16 slot-lanes
#pragma unroll
  for (int mt = 0; mt < 2; mt++)
#pragma unroll
    for (int q = 0; q < 4; q++) {
#pragma unroll
      for (int mk = 1; mk < 16; mk <<= 1) {
        const float w1 = __shfl_xor(v1[mt][q], mk, 64);
        const int j1 = __shfl_xor(i1[mt][q], mk, 64);
        const float w2 = __shfl_xor(v2[mt][q], mk, 64);
        const int j2 = __shfl_xor(i2[mt][q], mk, 64);
        const bool take = (w1 > v1[mt][q]) || (w1 == v1[mt][q] && j1 < i1[mt][q]);
        const float ca = take ? v1[mt][q] : w1;
        const int ja = take ? i1[mt][q] : j1;
        const float cb = take ? w2 : v2[mt][q];
        const int jb = take ? j2 : i2[mt][q];
        v1[mt][q] = take ? w1 : v1[mt][q];
        i1[mt][q] = take ? j1 : i1[mt][q];
        const bool t2 = (cb > ca) || (cb == ca && jb < ja);
        v2[mt][q] = t2 ? cb : ca;
        i2[mt][q] = t2 ? jb : ja;
      }
      if (s == 0) {
        cand1[row0 + mt * 16 + g * 4 + q] = i1[mt][q];
        cand2[row0 + mt * 16 + g * 4 + q] = i2[mt][q];
      }
    }
}

// exact fp32 re-check of the two candidates -> final argmax index
__global__ __launch_bounds__(256) void refine_argmax(
    const float* __restrict__ kn, const float* __restrict__ Km,
    const int* __restrict__ cand1, const int* __restrict__ cand2,
    int* __restrict__ idx) {
  const int t = threadIdx.x;
  const int w = t >> 6;
  const int l = t & 63;
  const int tok = blockIdx.x * 4 + w;
  const int c1 = cand1[tok], c2 = cand2[tok];
  const float4 a = *(const float4*)(kn + (size_t)tok * 256 + l * 4);
  const float4 b1 = *(const float4*)(Km + (size_t)c1 * 256 + l * 4);
  const float4 b2 = *(const float4*)(Km + (size_t)c2 * 256 + l * 4);
  float d1 = a.x * b1.x + a.y * b1.y + a.z * b1.z + a.w * b1.w;
  float d2 = a.x * b2.x + a.y * b2.y + a.z * b2.z + a.w * b2.w;
#pragma unroll
  for (int mk = 1; mk < 64; mk <<= 1) {
    d1 += __shfl_xor(d1, mk, 64);
    d2 += __shfl_xor(d2, mk, 64);
  }
  if (l == 0) idx[tok] = (d2 > d1 || (d2 == d1 && c2 < c1)) ? c2 : c1;
}

// ---------------------------------------------------------------------------
// Binned write path: histogram -> scan -> fill token lists -> per-slot gather
// fused with the memory update (replaces 16.8M global atomics).
// ---------------------------------------------------------------------------
__global__ void zero_kernel(float* __restrict__ p, int n) {
  int i = blockIdx.x * blockDim.x + threadIdx.x;
  const int stride = gridDim.x * blockDim.x;
  for (; i < n; i += stride) p[i] = 0.f;
}

__global__ __launch_bounds__(256) void hist_kernel(const int* __restrict__ idx,
                                                   int* __restrict__ cnt) {
  const int i = blockIdx.x * 256 + threadIdx.x;
  atomicAdd(&cnt[idx[i]], 1);
}

__global__ __launch_bounds__(1024) void scan4096(const int* __restrict__ cnt,
                                                 int* __restrict__ start,
                                                 int* __restrict__ cursor) {
  __shared__ int sums[1024];
  const int t = threadIdx.x;
  const int4 c = *(const int4*)(cnt + t * 4);
  const int local = c.x + c.y + c.z + c.w;
  sums[t] = local;
  __syncthreads();
  int acc = local;
  for (int off = 1; off < 1024; off <<= 1) {
    const int v = (t >= off) ? sums[t - off] : 0;
    __syncthreads();
    acc += v;
    sums[t] = acc;
    __syncthreads();
  }
  const int base = acc - local;  // exclusive prefix of this thread's 4
  int4 st;
  st.x = base;
  st.y = base + c.x;
  st.z = st.y + c.y;
  st.w = st.z + c.z;
  *(int4*)(start + t * 4) = st;
  *(int4*)(cursor + t * 4) = st;
  if (t == 1023) start[4096] = acc;
}

__global__ __launch_bounds__(256) void fill_kernel(const int* __restrict__ idx,
                                                   int* __restrict__ cursor,
                                                   int* __restrict__ tok_list) {
  const int i = blockIdx.x * 256 + threadIdx.x;
  const int pos = atomicAdd(&cursor[idx[i]], 1);
  tok_list[pos] = i;
}

// One 256-thread block per slot; 4 waves split the slot's token list
// round-robin (hot-slot tail /4); each wave covers all 256 dims (64 lanes x
// float4). LDS reduce, then fused K_new/V_new update.
__global__ __launch_bounds__(256) void gather_update(
    const float* __restrict__ keyn, const float* __restrict__ valn,
    const float* __restrict__ surprise, const int* __restrict__ start,
    const int* __restrict__ tok_list, const float* __restrict__ Km,
    const float* __restrict__ Vm, float* __restrict__ Ko,
    float* __restrict__ Vo) {
  __shared__ float4 gkp[4][64];
  __shared__ float4 gvp[4][64];
  __shared__ float gcp[4];
  const int t = threadIdx.x;
  const int w = t >> 6;
  const int l = t & 63;
  const int s = blockIdx.x;
  const int d0 = l * 4;
  const int b = start[s];
  const int e = start[s + 1];
  float4 gk = make_float4(0.f, 0.f, 0.f, 0.f);
  float4 gv = make_float4(0.f, 0.f, 0.f, 0.f);
  float gc = 0.f;
  for (int i = b + w; i < e; i += 4) {
    const int tok = tok_list[i];
    const float gate = surprise[tok];
    const float4 kq = *(const float4*)(keyn + (size_t)tok * 256 + d0);
    const float4 vq = *(const float4*)(valn + (size_t)tok * 256 + d0);
    gk.x = fmaf(gate, kq.x, gk.x);
    gk.y = fmaf(gate, kq.y, gk.y);
    gk.z = fmaf(gate, kq.z, gk.z);
    gk.w = fmaf(gate, kq.w, gk.w);
    gv.x = fmaf(gate, vq.x, gv.x);
    gv.y = fmaf(gate, vq.y, gv.y);
    gv.z = fmaf(gate, vq.z, gv.z);
    gv.w = fmaf(gate, vq.w, gv.w);
    gc += gate;
  }
  gkp[w][l] = gk;
  gvp[w][l] = gv;
  if (l == 0) gcp[w] = gc;
  __syncthreads();
  if (w == 0) {
#pragma unroll
    for (int ww = 1; ww < 4; ww++) {
      const float4 a = gkp[ww][l];
      gk.x += a.x; gk.y += a.y; gk.z += a.z; gk.w += a.w;
      const float4 bq = gvp[ww][l];
      gv.x += bq.x; gv.y += bq.y; gv.z += bq.z; gv.w += bq.w;
    }
    const float gct = gcp[0] + gcp[1] + gcp[2] + gcp[3];
    const float4 km = *(const float4*)(Km + (size_t)s * 256 + d0);
    const float4 vm = *(const float4*)(Vm + (size_t)s * 256 + d0);
    float4 ko, vo;
    ko.x = km.x + 0.1f * (gk.x - gct * km.x);
    ko.y = km.y + 0.1f * (gk.y - gct * km.y);
    ko.z = km.z + 0.1f * (gk.z - gct * km.z);
    ko.w = km.w + 0.1f * (gk.w - gct * km.w);
    vo.x = vm.x + 0.1f * (gv.x - gct * vm.x);
    vo.y = vm.y + 0.1f * (gv.y - gct * vm.y);
    vo.z = vm.z + 0.1f * (gv.z - gct * vm.z);
    vo.w = vm.w + 0.1f * (gv.w - gct * vm.w);
    *(float4*)(Ko + (size_t)s * 256 + d0) = ko;
    *(float4*)(Vo + (size_t)s * 256 + d0) = vo;
  }
}

// ---------------------------------------------------------------------------
extern "C" void kernel_launch(void* const* d_in, const int* in_sizes, int n_in,
                              void* d_out, int out_size, void* d_ws,
                              size_t ws_size, hipStream_t stream) {
  const float* x = (const float*)d_in[0];
  const float* W_in = (const float*)d_in[1];
  const float* b_in = (const float*)d_in[2];
  const float* W_q = (const float*)d_in[3];
  const float* b_q = (const float*)d_in[4];
  const float* g_q = (const float*)d_in[5];
  const float* be_q = (const float*)d_in[6];
  const float* K_mem = (const float*)d_in[7];
  const float* V_mem = (const float*)d_in[8];
  const float* W_kv = (const float*)d_in[9];
  const float* b_kv = (const float*)d_in[10];
  const float* g_kv = (const float*)d_in[11];
  const float* be_kv = (const float*)d_in[12];
  const float* W_o = (const float*)d_in[13];
  const float* b_o = (const float*)d_in[14];
  const float* g_o = (const float*)d_in[15];
  const float* be_o = (const float*)d_in[16];
  const float* g_1 = (const float*)d_in[17];
  const float* be_1 = (const float*)d_in[18];

  // d_out: [out(N*256) | K_new(S*256) | V_new(S*256) | surprise(N) | lr(N)]
  float* out_main = (float*)d_out;
  float* out_K = out_main + (size_t)NTOK * 256;
  float* out_V = out_K + (size_t)SMEM * 256;
  float* out_sur = out_V + (size_t)SMEM * 256;
  float* out_lr = out_sur + NTOK;

  // workspace layout (float offsets)
  float* ws = (float*)d_ws;
  float* x_proj = ws + (size_t)0;         // 8388608
  float* memout = ws + (size_t)8388608;   // 8388608
  float* keynew = ws + (size_t)16777216;  // 8388608
  float* valnew = ws + (size_t)25165824;  // 8388608
  u16* qhi = (u16*)(ws + (size_t)33554432);
  u16* qlo = (u16*)(ws + (size_t)37748736);
  u16* knhi = (u16*)(ws + (size_t)41943040);
  u16* knlo = (u16*)(ws + (size_t)46137344);
  u16* khi = (u16*)(ws + (size_t)50331648);
  u16* klo = (u16*)(ws + (size_t)50855936);
  u16* vthi = (u16*)(ws + (size_t)51380224);
  u16* vtlo = (u16*)(ws + (size_t)51904512);
  int* cnt = (int*)(ws + (size_t)52428800);        // 4096
  int* cursor = (int*)(ws + (size_t)52432896);     // 4096
  int* slot_start = (int*)(ws + (size_t)52436992); // 4097
  int* tok_list = (int*)(ws + (size_t)52445184);   // 32768
  int* cand1 = (int*)(ws + (size_t)54530048);
  int* cand2 = (int*)(ws + (size_t)54562816);
  int* idx = (int*)(ws + (size_t)54595584);

  const dim3 b256(256), b128(128);
  // prep: bf16 splits of K_mem and transposed V_mem
  split_k<<<512, b256, 0, stream>>>(K_mem, khi, klo);
  vt_split<<<128, b256, 0, stream>>>(V_mem, vthi, vtlo);
  // 1. x_proj = x@W_in + b_in
  gemm256<256, 0><<<NTOK / 32, b256, 0, stream>>>(
      x, nullptr, W_in, b_in, nullptr, nullptr, nullptr, nullptr, nullptr,
      x_proj, nullptr, nullptr);
  // 2. query/16 -> bf16 hi/lo
  gemm256<256, 1><<<NTOK / 32, b256, 0, stream>>>(
      x_proj, nullptr, W_q, b_q, g_q, be_q, nullptr, nullptr, nullptr, nullptr,
      qhi, qlo);
  // 3. flash attention read -> memout + surprise
  flash_mfma<<<NTOK / 64, b128, 0, stream>>>(qhi, qlo, khi, klo, vthi, vtlo,
                                             memout, out_sur);
  // 4. kv GEMM -> key_new (fp32 + bf16), value_new, lr
  gemm_kv<<<NTOK / 16, b256, 0, stream>>>(x_proj, memout, W_kv, b_kv, g_kv,
                                          be_kv, keynew, knhi, knlo, valnew,
                                          out_lr);
  // 5. wsim top-2 candidates
  wsim_mfma<<<NTOK / 64, b128, 0, stream>>>(knhi, knlo, khi, klo, cand1, cand2);
  // 6. exact fp32 refine -> idx
  refine_argmax<<<NTOK / 4, b256, 0, stream>>>(keynew, K_mem, cand1, cand2,
                                               idx);
  // 7. binned write path (no big atomics)
  zero_kernel<<<16, b256, 0, stream>>>((float*)cnt, SMEM);
  hist_kernel<<<NTOK / 256, b256, 0, stream>>>(idx, cnt);
  scan4096<<<1, 1024, 0, stream>>>(cnt, slot_start, cursor);
  fill_kernel<<<NTOK / 256, b256, 0, stream>>>(idx, cursor, tok_list);
  gather_update<<<SMEM, b256, 0, stream>>>(keynew, valnew, out_sur,
                                           slot_start, tok_list, K_mem,
                                           V_mem, out_K, out_V);
  // 8. out = LN(LN(concat@W_o + b_o) + x_proj)
  gemm256<512, 2><<<NTOK / 32, b256, 0, stream>>>(
      x_proj, memout, W_o, b_o, g_o, be_o, g_1, be_1, x_proj, out_main,
      nullptr, nullptr);
}

// Round 6
// 3369.350 us; speedup vs baseline: 1.6035x; 1.1394x over previous
//
#include <hip/hip_runtime.h>
#include <math.h>

// Shapes fixed by setup_inputs: B=4, T=8192 -> N=32768 tokens, D=256, H=256, S=4096.
#define NTOK 32768
#define SMEM 4096
#define NC 128  // 32-slot chunks

typedef unsigned short u16;
typedef __attribute__((ext_vector_type(8))) short bf16x8_t;
typedef __attribute__((ext_vector_type(4))) float f32x4_t;

#define MFMA16(A, B, C) __builtin_amdgcn_mfma_f32_16x16x32_bf16(A, B, C, 0, 0, 0)

__device__ __forceinline__ float gelu_f(float x) {
  return 0.5f * x * (1.0f + erff(x * 0.7071067811865475f));
}
__device__ __forceinline__ u16 f2bf(float x) {
  unsigned u = __float_as_uint(x);
  return (u16)((u + 0x7FFFu + ((u >> 16) & 1u)) >> 16);
}
__device__ __forceinline__ float bf2f(u16 h) {
  return __uint_as_float(((unsigned)h) << 16);
}
// async 16B/lane global->LDS; lds ptr must be wave-uniform (HW adds lane*16B)
__device__ __forceinline__ void glds16(const u16* g, u16* l) {
  __builtin_amdgcn_global_load_lds(
      (const __attribute__((address_space(1))) unsigned int*)(g),
      (__attribute__((address_space(3))) unsigned int*)(l), 16, 0, 0);
}

// ---------------------------------------------------------------------------
// Prep 1: split K_mem -> khi/klo (bf16 hi + residual lo)
// ---------------------------------------------------------------------------
__global__ __launch_bounds__(256) void split_k(const float* __restrict__ K,
                                               u16* __restrict__ khi,
                                               u16* __restrict__ klo) {
  const int i8 = (blockIdx.x * 256 + threadIdx.x) * 8;
  union { u16 u[8]; float4 f; } H, L;
#pragma unroll
  for (int j = 0; j < 8; j++) {
    const float v = K[i8 + j];
    const u16 h = f2bf(v);
    H.u[j] = h;
    L.u[j] = f2bf(v - bf2f(h));
  }
  *(float4*)(khi + i8) = H.f;
  *(float4*)(klo + i8) = L.f;
}

// ---------------------------------------------------------------------------
// Prep 2: V_mem[4096][256] -> vthi/vtlo transposed [256][4096] bf16 hi/lo
// ---------------------------------------------------------------------------
__global__ __launch_bounds__(256) void vt_split(const float* __restrict__ V,
                                                u16* __restrict__ vthi,
                                                u16* __restrict__ vtlo) {
  __shared__ float Vs[32][260];
  const int t = threadIdx.x;
  const int s0 = (blockIdx.x & 15) * 256;
  const int d0 = (blockIdx.x >> 4) * 32;
#pragma unroll
  for (int m = 0; m < 8; m++) {
    const int r = (t >> 3) + 32 * m;
    const float4 v =
        *(const float4*)(V + (size_t)(s0 + r) * 256 + d0 + (t & 7) * 4);
    Vs[(t & 7) * 4 + 0][r] = v.x;
    Vs[(t & 7) * 4 + 1][r] = v.y;
    Vs[(t & 7) * 4 + 2][r] = v.z;
    Vs[(t & 7) * 4 + 3][r] = v.w;
  }
  __syncthreads();
  const int dl = t >> 3;
  const int sl0 = (t & 7) * 32;
  union { u16 u[8]; float4 f; } H[4], L[4];
#pragma unroll
  for (int i = 0; i < 8; i++) {
    const float4 v = *(const float4*)&Vs[dl][sl0 + i * 4];
    const float vv[4] = {v.x, v.y, v.z, v.w};
#pragma unroll
    for (int j = 0; j < 4; j++) {
      const u16 h = f2bf(vv[j]);
      H[i >> 1].u[(i & 1) * 4 + j] = h;
      L[i >> 1].u[(i & 1) * 4 + j] = f2bf(vv[j] - bf2f(h));
    }
  }
  const size_t ob = (size_t)(d0 + dl) * 4096 + s0 + sl0;
#pragma unroll
  for (int i = 0; i < 4; i++) {
    *(float4*)(vthi + ob + i * 8) = H[i].f;
    *(float4*)(vtlo + ob + i * 8) = L[i].f;
  }
}

// ---------------------------------------------------------------------------
// GEMM BN=256, BM=32, KSTEP=32, 256 threads.
// ---------------------------------------------------------------------------
template <int KDIM, int EPI>
__global__ __launch_bounds__(256) void gemm256(
    const float* __restrict__ A1, const float* __restrict__ A2,
    const float* __restrict__ W, const float* __restrict__ bias,
    const float* __restrict__ g0, const float* __restrict__ be0,
    const float* __restrict__ g1, const float* __restrict__ be1,
    const float* __restrict__ ident, float* __restrict__ out,
    u16* __restrict__ bh, u16* __restrict__ bl) {
  __shared__ float As[32][36];
  __shared__ float Bs[32][256];
  const int t = threadIdx.x;
  const int tx = t & 63;
  const int ty = t >> 6;
  const int row0 = blockIdx.x * 32;
  const int c0 = tx * 4;

  float acc[8][4];
#pragma unroll
  for (int r = 0; r < 8; r++)
#pragma unroll
    for (int j = 0; j < 4; j++) acc[r][j] = 0.f;

  const int ar = t >> 3;
  const int akc = (t & 7) * 4;

  for (int k0 = 0; k0 < KDIM; k0 += 32) {
    float4 av;
    if (KDIM == 512) {
      const int kg = k0 + akc;
      const float* src = (kg < 256) ? A1 : A2;
      av = *(const float4*)(src + (size_t)(row0 + ar) * 256 + (kg & 255));
    } else {
      av = *(const float4*)(A1 + (size_t)(row0 + ar) * 256 + k0 + akc);
    }
    As[akc + 0][ar] = av.x;
    As[akc + 1][ar] = av.y;
    As[akc + 2][ar] = av.z;
    As[akc + 3][ar] = av.w;
#pragma unroll
    for (int j = 0; j < 8; j++) {
      *(float4*)&Bs[ar][akc + j * 32] =
          *(const float4*)(W + (size_t)(k0 + ar) * 256 + akc + j * 32);
    }
    __syncthreads();
#pragma unroll
    for (int kk = 0; kk < 32; kk++) {
      const float4 bv = *(const float4*)&Bs[kk][c0];
      const float4 a0 = *(const float4*)&As[kk][ty * 8];
      const float4 a1 = *(const float4*)&As[kk][ty * 8 + 4];
      const float a8[8] = {a0.x, a0.y, a0.z, a0.w, a1.x, a1.y, a1.z, a1.w};
      const float b4[4] = {bv.x, bv.y, bv.z, bv.w};
#pragma unroll
      for (int r = 0; r < 8; r++)
#pragma unroll
        for (int j = 0; j < 4; j++) acc[r][j] = fmaf(a8[r], b4[j], acc[r][j]);
    }
    __syncthreads();
  }

  float bb[4];
#pragma unroll
  for (int j = 0; j < 4; j++) bb[j] = bias[c0 + j];
#pragma unroll
  for (int r = 0; r < 8; r++)
#pragma unroll
    for (int j = 0; j < 4; j++) acc[r][j] += bb[j];

  if (EPI == 0) {
#pragma unroll
    for (int r = 0; r < 8; r++) {
      float4 v = make_float4(acc[r][0], acc[r][1], acc[r][2], acc[r][3]);
      *(float4*)(out + (size_t)(row0 + ty * 8 + r) * 256 + c0) = v;
    }
    return;
  }

  float gg[4], ee[4];
#pragma unroll
  for (int j = 0; j < 4; j++) {
    gg[j] = g0[c0 + j];
    ee[j] = be0[c0 + j];
  }

#pragma unroll
  for (int r = 0; r < 8; r++) {
    float s1 = acc[r][0] + acc[r][1] + acc[r][2] + acc[r][3];
    float s2 = acc[r][0] * acc[r][0] + acc[r][1] * acc[r][1] +
               acc[r][2] * acc[r][2] + acc[r][3] * acc[r][3];
#pragma unroll
    for (int mk = 1; mk < 64; mk <<= 1) {
      s1 += __shfl_xor(s1, mk, 64);
      s2 += __shfl_xor(s2, mk, 64);
    }
    const float mu = s1 * (1.0f / 256.0f);
    const float rstd = rsqrtf(s2 * (1.0f / 256.0f) - mu * mu + 1e-5f);
    if (EPI == 1) {
      float q[4];
#pragma unroll
      for (int j = 0; j < 4; j++)
        q[j] = gelu_f((acc[r][j] - mu) * rstd * gg[j] + ee[j]) * 0.0625f;
      ushort4 hv, lv;
      u16 h;
      h = f2bf(q[0]); hv.x = h; lv.x = f2bf(q[0] - bf2f(h));
      h = f2bf(q[1]); hv.y = h; lv.y = f2bf(q[1] - bf2f(h));
      h = f2bf(q[2]); hv.z = h; lv.z = f2bf(q[2] - bf2f(h));
      h = f2bf(q[3]); hv.w = h; lv.w = f2bf(q[3] - bf2f(h));
      const size_t o = (size_t)(row0 + ty * 8 + r) * 256 + c0;
      *(ushort4*)(bh + o) = hv;
      *(ushort4*)(bl + o) = lv;
    } else {
      const float4 idv =
          *(const float4*)(ident + (size_t)(row0 + ty * 8 + r) * 256 + c0);
      acc[r][0] = (acc[r][0] - mu) * rstd * gg[0] + ee[0] + idv.x;
      acc[r][1] = (acc[r][1] - mu) * rstd * gg[1] + ee[1] + idv.y;
      acc[r][2] = (acc[r][2] - mu) * rstd * gg[2] + ee[2] + idv.z;
      acc[r][3] = (acc[r][3] - mu) * rstd * gg[3] + ee[3] + idv.w;
    }
  }

  if (EPI == 2) {
    float g1v[4], e1v[4];
#pragma unroll
    for (int j = 0; j < 4; j++) {
      g1v[j] = g1[c0 + j];
      e1v[j] = be1[c0 + j];
    }
#pragma unroll
    for (int r = 0; r < 8; r++) {
      float s1 = acc[r][0] + acc[r][1] + acc[r][2] + acc[r][3];
      float s2 = acc[r][0] * acc[r][0] + acc[r][1] * acc[r][1] +
                 acc[r][2] * acc[r][2] + acc[r][3] * acc[r][3];
#pragma unroll
      for (int mk = 1; mk < 64; mk <<= 1) {
        s1 += __shfl_xor(s1, mk, 64);
        s2 += __shfl_xor(s2, mk, 64);
      }
      const float mu = s1 * (1.0f / 256.0f);
      const float rstd = rsqrtf(s2 * (1.0f / 256.0f) - mu * mu + 1e-5f);
      float4 v;
      v.x = (acc[r][0] - mu) * rstd * g1v[0] + e1v[0];
      v.y = (acc[r][1] - mu) * rstd * g1v[1] + e1v[1];
      v.z = (acc[r][2] - mu) * rstd * g1v[2] + e1v[2];
      v.w = (acc[r][3] - mu) * rstd * g1v[3] + e1v[3];
      *(float4*)(out + (size_t)(row0 + ty * 8 + r) * 256 + c0) = v;
    }
  }
}

// ---------------------------------------------------------------------------
// kv GEMM.
// ---------------------------------------------------------------------------
__global__ __launch_bounds__(256) void gemm_kv(
    const float* __restrict__ A1, const float* __restrict__ A2,
    const float* __restrict__ W, const float* __restrict__ bias,
    const float* __restrict__ gln, const float* __restrict__ bln,
    float* __restrict__ key_new, u16* __restrict__ knhi, u16* __restrict__ knlo,
    float* __restrict__ value_new, float* __restrict__ lr_out) {
  __shared__ float As[16][20];
  __shared__ float Bs[16][768];
  const int t = threadIdx.x;
  const int tx = t & 63;
  const int ty = t >> 6;
  const int row0 = blockIdx.x * 16;
  const int c0 = tx * 4;

  float acc[4][3][4];
#pragma unroll
  for (int r = 0; r < 4; r++)
#pragma unroll
    for (int g = 0; g < 3; g++)
#pragma unroll
      for (int j = 0; j < 4; j++) acc[r][g][j] = 0.f;

  for (int k0 = 0; k0 < 512; k0 += 16) {
    if (t < 64) {
      const int r = t & 15;
      const int kc = (t >> 4) * 4;
      const int kg = k0 + kc;
      const float* src = (kg < 256) ? A1 : A2;
      const float4 av =
          *(const float4*)(src + (size_t)(row0 + r) * 256 + (kg & 255));
      As[kc + 0][r] = av.x;
      As[kc + 1][r] = av.y;
      As[kc + 2][r] = av.z;
      As[kc + 3][r] = av.w;
    }
    {
      const int kk = t >> 4;
      const int bc = (t & 15) * 4;
#pragma unroll
      for (int j = 0; j < 12; j++)
        *(float4*)&Bs[kk][bc + j * 64] =
            *(const float4*)(W + (size_t)(k0 + kk) * 768 + bc + j * 64);
    }
    __syncthreads();
#pragma unroll
    for (int kk = 0; kk < 16; kk++) {
      const float4 a = *(const float4*)&As[kk][ty * 4];
      const float a4[4] = {a.x, a.y, a.z, a.w};
#pragma unroll
      for (int g = 0; g < 3; g++) {
        const float4 b = *(const float4*)&Bs[kk][g * 256 + c0];
#pragma unroll
        for (int r = 0; r < 4; r++) {
          acc[r][g][0] = fmaf(a4[r], b.x, acc[r][g][0]);
          acc[r][g][1] = fmaf(a4[r], b.y, acc[r][g][1]);
          acc[r][g][2] = fmaf(a4[r], b.z, acc[r][g][2]);
          acc[r][g][3] = fmaf(a4[r], b.w, acc[r][g][3]);
        }
      }
    }
    __syncthreads();
  }

  float bv[3][4], gw[3][4], ew[3][4];
#pragma unroll
  for (int g = 0; g < 3; g++)
#pragma unroll
    for (int j = 0; j < 4; j++) {
      bv[g][j] = bias[g * 256 + c0 + j];
      gw[g][j] = gln[g * 256 + c0 + j];
      ew[g][j] = bln[g * 256 + c0 + j];
    }

#pragma unroll
  for (int r = 0; r < 4; r++) {
    float s1 = 0.f, s2 = 0.f;
#pragma unroll
    for (int g = 0; g < 3; g++)
#pragma unroll
      for (int j = 0; j < 4; j++) {
        acc[r][g][j] += bv[g][j];
        s1 += acc[r][g][j];
        s2 += acc[r][g][j] * acc[r][g][j];
      }
#pragma unroll
    for (int mk = 1; mk < 64; mk <<= 1) {
      s1 += __shfl_xor(s1, mk, 64);
      s2 += __shfl_xor(s2, mk, 64);
    }
    const float mu = s1 * (1.0f / 768.0f);
    const float rstd = rsqrtf(s2 * (1.0f / 768.0f) - mu * mu + 1e-5f);
    const size_t orow = (size_t)(row0 + ty * 4 + r) * 256 + c0;
    float kq[4];
    float4 vv;
#pragma unroll
    for (int j = 0; j < 4; j++)
      kq[j] = gelu_f((acc[r][0][j] - mu) * rstd * gw[0][j] + ew[0][j]);
    vv.x = gelu_f((acc[r][1][0] - mu) * rstd * gw[1][0] + ew[1][0]);
    vv.y = gelu_f((acc[r][1][1] - mu) * rstd * gw[1][1] + ew[1][1]);
    vv.z = gelu_f((acc[r][1][2] - mu) * rstd * gw[1][2] + ew[1][2]);
    vv.w = gelu_f((acc[r][1][3] - mu) * rstd * gw[1][3] + ew[1][3]);
    *(float4*)(key_new + orow) = make_float4(kq[0], kq[1], kq[2], kq[3]);
    *(float4*)(value_new + orow) = vv;
    ushort4 hv, lv;
    u16 h;
    h = f2bf(kq[0]); hv.x = h; lv.x = f2bf(kq[0] - bf2f(h));
    h = f2bf(kq[1]); hv.y = h; lv.y = f2bf(kq[1] - bf2f(h));
    h = f2bf(kq[2]); hv.z = h; lv.z = f2bf(kq[2] - bf2f(h));
    h = f2bf(kq[3]); hv.w = h; lv.w = f2bf(kq[3] - bf2f(h));
    *(ushort4*)(knhi + orow) = hv;
    *(ushort4*)(knlo + orow) = lv;
    float ls = 0.f;
#pragma unroll
    for (int j = 0; j < 4; j++) {
      const float lvv = gelu_f((acc[r][2][j] - mu) * rstd * gw[2][j] + ew[2][j]);
      ls += 1.0f / (1.0f + __expf(-lvv));
    }
#pragma unroll
    for (int mk = 1; mk < 64; mk <<= 1) ls += __shfl_xor(ls, mk, 64);
    if (tx == 0) lr_out[row0 + ty * 4 + r] = ls * (1.0f / 256.0f);
  }
}

// ---------------------------------------------------------------------------
// Flash read: conflict-free LDS slot layouts, async global_load_lds staging,
// 2 barriers/chunk. MFMA sequence identical to the R4-passing kernel.
// K slot id = ks*128 + nt*64 + g*16 + s ; V slot id = nt*64 + g*16 + s
// P slot id = mt*64 + cg*16 + (tok&15)
// ---------------------------------------------------------------------------
__global__ __launch_bounds__(128, 1) void flash_mfma(
    const u16* __restrict__ qhi, const u16* __restrict__ qlo,
    const u16* __restrict__ khi, const u16* __restrict__ klo,
    const u16* __restrict__ vthi, const u16* __restrict__ vtlo,
    float* __restrict__ memout, float* __restrict__ surprise_out) {
  __shared__ u16 Kb[2][8192];        // [prec][1024 slots * 8]
  __shared__ u16 Vb[2][8192];        // [prec][1024 slots * 8]
  __shared__ u16 pbuf[2][2][1024];   // [wave][prec][128 slots * 8]
  __shared__ float scf[2][32];
  const int t = threadIdx.x;
  const int w = t >> 6;
  const int l = t & 63;
  const int s = l & 15;
  const int g = l >> 4;
  const int row0 = blockIdx.x * 64 + w * 32;
  const int p0 = (g * 16 + s) * 8;  // lane's read slot base (u16 units)

  // staging source inner offsets (u16 units); instruction i covers slots
  // i*128 + w*64 + lane
  int kin[8], vin[8];
#pragma unroll
  for (int i = 0; i < 8; i++) {
    const int sid = i * 128 + w * 64 + l;
    kin[i] = (((sid >> 6) & 1) * 16 + (sid & 15)) * 256 + (sid >> 7) * 32 +
             ((sid >> 4) & 3) * 8;
    vin[i] = ((sid >> 6) * 16 + (sid & 15)) * 4096 + ((sid >> 4) & 3) * 8;
  }

  f32x4_t o_acc[2][16];
  f32x4_t l_acc[2];
  float m_st[2][4];
#pragma unroll
  for (int mt = 0; mt < 2; mt++) {
#pragma unroll
    for (int nt = 0; nt < 16; nt++)
#pragma unroll
      for (int j = 0; j < 4; j++) o_acc[mt][nt][j] = 0.f;
#pragma unroll
    for (int j = 0; j < 4; j++) l_acc[mt][j] = 0.f;
#pragma unroll
    for (int q = 0; q < 4; q++) m_st[mt][q] = -INFINITY;
  }
  bf16x8_t ones;
#pragma unroll
  for (int j = 0; j < 8; j++) ones[j] = (short)0x3F80;

  // prologue: stage K[0]
#pragma unroll
  for (int i = 0; i < 8; i++) {
    glds16(khi + kin[i], &Kb[0][(i * 128 + w * 64) * 8]);
    glds16(klo + kin[i], &Kb[1][(i * 128 + w * 64) * 8]);
  }

  for (int c = 0; c < NC; c++) {
    const int c0 = c * 32;
    __syncthreads();  // (A) K[c] resident; Vbuf free (prev PV done)
    // issue V[c] (flies under QK)
#pragma unroll
    for (int i = 0; i < 8; i++) {
      glds16(vthi + c0 + vin[i], &Vb[0][(i * 128 + w * 64) * 8]);
      glds16(vtlo + c0 + vin[i], &Vb[1][(i * 128 + w * 64) * 8]);
    }
    // ---- scores: S = Q @ K^T (3-product) ----
    f32x4_t sacc[2][2];
#pragma unroll
    for (int mt = 0; mt < 2; mt++)
#pragma unroll
      for (int nt = 0; nt < 2; nt++)
#pragma unroll
        for (int j = 0; j < 4; j++) sacc[mt][nt][j] = 0.f;
#pragma unroll
    for (int ks = 0; ks < 8; ks++) {
      bf16x8_t qh[2], ql[2];
#pragma unroll
      for (int mt = 0; mt < 2; mt++) {
        const size_t qo = (size_t)(row0 + mt * 16 + s) * 256 + ks * 32 + g * 8;
        qh[mt] = *(const bf16x8_t*)(qhi + qo);
        ql[mt] = *(const bf16x8_t*)(qlo + qo);
      }
#pragma unroll
      for (int nt = 0; nt < 2; nt++) {
        const int ko = ks * 1024 + nt * 512 + p0;
        const bf16x8_t kh = *(const bf16x8_t*)&Kb[0][ko];
        const bf16x8_t kl = *(const bf16x8_t*)&Kb[1][ko];
#pragma unroll
        for (int mt = 0; mt < 2; mt++) {
          sacc[mt][nt] = MFMA16(qh[mt], kh, sacc[mt][nt]);
          sacc[mt][nt] = MFMA16(ql[mt], kh, sacc[mt][nt]);
          sacc[mt][nt] = MFMA16(qh[mt], kl, sacc[mt][nt]);
        }
      }
    }
    // ---- online softmax (rows: tok = mt*16 + g*4 + q) ----
    float cmax[2][4];
    bool needb = false;
#pragma unroll
    for (int mt = 0; mt < 2; mt++)
#pragma unroll
      for (int q = 0; q < 4; q++) {
        float v = fmaxf(sacc[mt][0][q], sacc[mt][1][q]);
#pragma unroll
        for (int mk = 1; mk < 16; mk <<= 1) v = fmaxf(v, __shfl_xor(v, mk, 64));
        cmax[mt][q] = v;
        needb |= (v > m_st[mt][q]);
      }
    const bool need = (__ballot(needb) != 0ull);
#pragma unroll
    for (int mt = 0; mt < 2; mt++)
#pragma unroll
      for (int q = 0; q < 4; q++) {
        const float mold = m_st[mt][q];
        const float mnew = need ? fmaxf(mold, cmax[mt][q]) : mold;
        const float e0 = __expf(sacc[mt][0][q] - mnew);
        const float e1 = __expf(sacc[mt][1][q] - mnew);
        const int cg0 = s >> 3, w0 = s & 7;
        const int i0 = (mt * 64 + cg0 * 16 + g * 4 + q) * 8 + w0;        // col s
        const int i1 = (mt * 64 + (2 + cg0) * 16 + g * 4 + q) * 8 + w0;  // col 16+s
        u16 h;
        h = f2bf(e0);
        pbuf[w][0][i0] = h;
        pbuf[w][1][i0] = f2bf(e0 - bf2f(h));
        h = f2bf(e1);
        pbuf[w][0][i1] = h;
        pbuf[w][1][i1] = f2bf(e1 - bf2f(h));
        if (need) {
          if (s == 0) scf[w][mt * 16 + g * 4 + q] = __expf(mold - mnew);
          m_st[mt][q] = mnew;
        }
      }
    __syncthreads();  // (B) V[c] resident; pbuf/scf visible; Kbuf free
    // issue K[c+1] (flies under PV)
    if (c + 1 < NC) {
      const int cofs = (c0 + 32) * 256;
#pragma unroll
      for (int i = 0; i < 8; i++) {
        glds16(khi + cofs + kin[i], &Kb[0][(i * 128 + w * 64) * 8]);
        glds16(klo + cofs + kin[i], &Kb[1][(i * 128 + w * 64) * 8]);
      }
    }
    // ---- rescale (exact defer: only when max moved) ----
    if (need) {
      float scv[2];
      scv[0] = scf[w][s];
      scv[1] = scf[w][16 + s];
#pragma unroll
      for (int mt = 0; mt < 2; mt++) {
#pragma unroll
        for (int j = 0; j < 4; j++) l_acc[mt][j] *= scv[mt];
#pragma unroll
        for (int nt = 0; nt < 16; nt++)
#pragma unroll
          for (int j = 0; j < 4; j++) o_acc[mt][nt][j] *= scv[mt];
      }
    }
    // ---- P fragments + l update via ones-MFMA ----
    bf16x8_t ph[2], pl[2];
#pragma unroll
    for (int mt = 0; mt < 2; mt++) {
      ph[mt] = *(const bf16x8_t*)&pbuf[w][0][mt * 512 + p0];
      pl[mt] = *(const bf16x8_t*)&pbuf[w][1][mt * 512 + p0];
      l_acc[mt] = MFMA16(ones, ph[mt], l_acc[mt]);
      l_acc[mt] = MFMA16(ones, pl[mt], l_acc[mt]);
    }
    // ---- PV: O^T = V^T @ P^T (3-product) ----
#pragma unroll
    for (int nt = 0; nt < 16; nt++) {
      const int vo = nt * 512 + p0;
      const bf16x8_t vh = *(const bf16x8_t*)&Vb[0][vo];
      const bf16x8_t vl = *(const bf16x8_t*)&Vb[1][vo];
#pragma unroll
      for (int mt = 0; mt < 2; mt++) {
        o_acc[mt][nt] = MFMA16(vh, ph[mt], o_acc[mt][nt]);
        o_acc[mt][nt] = MFMA16(vl, ph[mt], o_acc[mt][nt]);
        o_acc[mt][nt] = MFMA16(vh, pl[mt], o_acc[mt][nt]);
      }
    }
  }
  // ---- epilogue: normalize + store ----
#pragma unroll
  for (int mt = 0; mt < 2; mt++) {
    const float li = 1.0f / l_acc[mt][0];
    if (g == 0) surprise_out[row0 + mt * 16 + s] = 1.0f - li;
    const size_t rb = (size_t)(row0 + mt * 16 + s) * 256;
#pragma unroll
    for (int nt = 0; nt < 16; nt++) {
      float4 v = make_float4(o_acc[mt][nt][0] * li, o_acc[mt][nt][1] * li,
                             o_acc[mt][nt][2] * li, o_acc[mt][nt][3] * li);
      *(float4*)(memout + rb + nt * 16 + g * 4) = v;
    }
  }
}

// ---------------------------------------------------------------------------
// wsim: same conflict-free K layout, double-buffered async K, 1 barrier/chunk.
// ---------------------------------------------------------------------------
__device__ __forceinline__ void top2_upd(float a, int ia, float& v1, int& i1,
                                         float& v2, int& i2) {
  if (a > v1 || (a == v1 && ia < i1)) {
    v2 = v1; i2 = i1; v1 = a; i1 = ia;
  } else if (a > v2 || (a == v2 && ia < i2)) {
    v2 = a; i2 = ia;
  }
}

__global__ __launch_bounds__(128, 1) void wsim_mfma(
    const u16* __restrict__ knhi, const u16* __restrict__ knlo,
    const u16* __restrict__ khi, const u16* __restrict__ klo,
    int* __restrict__ cand1, int* __restrict__ cand2) {
  __shared__ u16 Kb[2][2][8192];  // [dbuf][prec][1024 slots * 8]
  const int t = threadIdx.x;
  const int w = t >> 6;
  const int l = t & 63;
  const int s = l & 15;
  const int g = l >> 4;
  const int row0 = blockIdx.x * 64 + w * 32;
  const int p0 = (g * 16 + s) * 8;

  int kin[8];
#pragma unroll
  for (int i = 0; i < 8; i++) {
    const int sid = i * 128 + w * 64 + l;
    kin[i] = (((sid >> 6) & 1) * 16 + (sid & 15)) * 256 + (sid >> 7) * 32 +
             ((sid >> 4) & 3) * 8;
  }

  bf16x8_t ah[2][8], al[2][8];
#pragma unroll
  for (int mt = 0; mt < 2; mt++)
#pragma unroll
    for (int ks = 0; ks < 8; ks++) {
      const size_t qo = (size_t)(row0 + mt * 16 + s) * 256 + ks * 32 + g * 8;
      ah[mt][ks] = *(const bf16x8_t*)(knhi + qo);
      al[mt][ks] = *(const bf16x8_t*)(knlo + qo);
    }
  float v1[2][4], v2[2][4];
  int i1[2][4], i2[2][4];
#pragma unroll
  for (int mt = 0; mt < 2; mt++)
#pragma unroll
    for (int q = 0; q < 4; q++) {
      v1[mt][q] = -INFINITY; v2[mt][q] = -INFINITY;
      i1[mt][q] = 0; i2[mt][q] = 0;
    }

  // prologue: stage K[0] into buf 0
#pragma unroll
  for (int i = 0; i < 8; i++) {
    glds16(khi + kin[i], &Kb[0][0][(i * 128 + w * 64) * 8]);
    glds16(klo + kin[i], &Kb[0][1][(i * 128 + w * 64) * 8]);
  }

  for (int c = 0; c < NC; c++) {
    const int cb = c & 1;
    __syncthreads();  // K[c] resident
    if (c + 1 < NC) {
      const int cofs = (c + 1) * 32 * 256;
#pragma unroll
      for (int i = 0; i < 8; i++) {
        glds16(khi + cofs + kin[i], &Kb[cb ^ 1][0][(i * 128 + w * 64) * 8]);
        glds16(klo + cofs + kin[i], &Kb[cb ^ 1][1][(i * 128 + w * 64) * 8]);
      }
    }
    f32x4_t sacc[2][2];
#pragma unroll
    for (int mt = 0; mt < 2; mt++)
#pragma unroll
      for (int nt = 0; nt < 2; nt++)
#pragma unroll
        for (int j = 0; j < 4; j++) sacc[mt][nt][j] = 0.f;
#pragma unroll
    for (int ks = 0; ks < 8; ks++) {
#pragma unroll
      for (int nt = 0; nt < 2; nt++) {
        const int ko = ks * 1024 + nt * 512 + p0;
        const bf16x8_t kh = *(const bf16x8_t*)&Kb[cb][0][ko];
        const bf16x8_t kl = *(const bf16x8_t*)&Kb[cb][1][ko];
#pragma unroll
        for (int mt = 0; mt < 2; mt++) {
          sacc[mt][nt] = MFMA16(ah[mt][ks], kh, sacc[mt][nt]);
          sacc[mt][nt] = MFMA16(al[mt][ks], kh, sacc[mt][nt]);
          sacc[mt][nt] = MFMA16(ah[mt][ks], kl, sacc[mt][nt]);
        }
      }
    }
    const int c0 = c * 32;
#pragma unroll
    for (int mt = 0; mt < 2; mt++)
#pragma unroll
      for (int q = 0; q < 4; q++) {
        top2_upd(sacc[mt][0][q], c0 + s, v1[mt][q], i1[mt][q], v2[mt][q],
                 i2[mt][q]);
        top2_upd(sacc[mt][1][q], c0 + 16 + s, v1[mt][q], i1[mt][q], v2[mt][q],
                 i2[mt][q]);
      }
  }
  // cross-lane merge over the 16 slot-lanes
#pragma unroll
  for (int mt = 0; mt < 2; mt++)
#pragma unroll
    for (int q = 0; q < 4; q++) {
#pragma unroll
      for (int mk = 1; mk < 16; mk <<= 1) {
        const float w1 = __shfl_xor(v1[mt][q], mk, 64);
        const int j1 = __shfl_xor(i1[mt][q], mk, 64);
        const float w2 = __shfl_xor(v2[mt][q], mk, 64);
        const int j2 = __shfl_xor(i2[mt][q], mk, 64);
        const bool take = (w1 > v1[mt][q]) || (w1 == v1[mt][q] && j1 < i1[mt][q]);
        const float ca = take ? v1[mt][q] : w1;
        const int ja = take ? i1[mt][q] : j1;
        const float cb2 = take ? w2 : v2[mt][q];
        const int jb = take ? j2 : i2[mt][q];
        v1[mt][q] = take ? w1 : v1[mt][q];
        i1[mt][q] = take ? j1 : i1[mt][q];
        const bool t2 = (cb2 > ca) || (cb2 == ca && jb < ja);
        v2[mt][q] = t2 ? cb2 : ca;
        i2[mt][q] = t2 ? jb : ja;
      }
      if (s == 0) {
        cand1[row0 + mt * 16 + g * 4 + q] = i1[mt][q];
        cand2[row0 + mt * 16 + g * 4 + q] = i2[mt][q];
      }
    }
}

// exact fp32 re-check of the two candidates -> final argmax index
__global__ __launch_bounds__(256) void refine_argmax(
    const float* __restrict__ kn, const float* __restrict__ Km,
    const int* __restrict__ cand1, const int* __restrict__ cand2,
    int* __restrict__ idx) {
  const int t = threadIdx.x;
  const int w = t >> 6;
  const int l = t & 63;
  const int tok = blockIdx.x * 4 + w;
  const int c1 = cand1[tok], c2 = cand2[tok];
  const float4 a = *(const float4*)(kn + (size_t)tok * 256 + l * 4);
  const float4 b1 = *(const float4*)(Km + (size_t)c1 * 256 + l * 4);
  const float4 b2 = *(const float4*)(Km + (size_t)c2 * 256 + l * 4);
  float d1 = a.x * b1.x + a.y * b1.y + a.z * b1.z + a.w * b1.w;
  float d2 = a.x * b2.x + a.y * b2.y + a.z * b2.z + a.w * b2.w;
#pragma unroll
  for (int mk = 1; mk < 64; mk <<= 1) {
    d1 += __shfl_xor(d1, mk, 64);
    d2 += __shfl_xor(d2, mk, 64);
  }
  if (l == 0) idx[tok] = (d2 > d1 || (d2 == d1 && c2 < c1)) ? c2 : c1;
}

// ---------------------------------------------------------------------------
// Binned write path.
// ---------------------------------------------------------------------------
__global__ void zero_kernel(float* __restrict__ p, int n) {
  int i = blockIdx.x * blockDim.x + threadIdx.x;
  const int stride = gridDim.x * blockDim.x;
  for (; i < n; i += stride) p[i] = 0.f;
}

__global__ __launch_bounds__(256) void hist_kernel(const int* __restrict__ idx,
                                                   int* __restrict__ cnt) {
  const int i = blockIdx.x * 256 + threadIdx.x;
  atomicAdd(&cnt[idx[i]], 1);
}

__global__ __launch_bounds__(1024) void scan4096(const int* __restrict__ cnt,
                                                 int* __restrict__ start,
                                                 int* __restrict__ cursor) {
  __shared__ int sums[1024];
  const int t = threadIdx.x;
  const int4 c = *(const int4*)(cnt + t * 4);
  const int local = c.x + c.y + c.z + c.w;
  sums[t] = local;
  __syncthreads();
  int acc = local;
  for (int off = 1; off < 1024; off <<= 1) {
    const int v = (t >= off) ? sums[t - off] : 0;
    __syncthreads();
    acc += v;
    sums[t] = acc;
    __syncthreads();
  }
  const int base = acc - local;
  int4 st;
  st.x = base;
  st.y = base + c.x;
  st.z = st.y + c.y;
  st.w = st.z + c.z;
  *(int4*)(start + t * 4) = st;
  *(int4*)(cursor + t * 4) = st;
  if (t == 1023) start[4096] = acc;
}

__global__ __launch_bounds__(256) void fill_kernel(const int* __restrict__ idx,
                                                   int* __restrict__ cursor,
                                                   int* __restrict__ tok_list) {
  const int i = blockIdx.x * 256 + threadIdx.x;
  const int pos = atomicAdd(&cursor[idx[i]], 1);
  tok_list[pos] = i;
}

__global__ __launch_bounds__(256) void gather_update(
    const float* __restrict__ keyn, const float* __restrict__ valn,
    const float* __restrict__ surprise, const int* __restrict__ start,
    const int* __restrict__ tok_list, const float* __restrict__ Km,
    const float* __restrict__ Vm, float* __restrict__ Ko,
    float* __restrict__ Vo) {
  __shared__ float4 gkp[4][64];
  __shared__ float4 gvp[4][64];
  __shared__ float gcp[4];
  const int t = threadIdx.x;
  const int w = t >> 6;
  const int l = t & 63;
  const int s = blockIdx.x;
  const int d0 = l * 4;
  const int b = start[s];
  const int e = start[s + 1];
  float4 gk = make_float4(0.f, 0.f, 0.f, 0.f);
  float4 gv = make_float4(0.f, 0.f, 0.f, 0.f);
  float gc = 0.f;
  for (int i = b + w; i < e; i += 4) {
    const int tok = tok_list[i];
    const float gate = surprise[tok];
    const float4 kq = *(const float4*)(keyn + (size_t)tok * 256 + d0);
    const float4 vq = *(const float4*)(valn + (size_t)tok * 256 + d0);
    gk.x = fmaf(gate, kq.x, gk.x);
    gk.y = fmaf(gate, kq.y, gk.y);
    gk.z = fmaf(gate, kq.z, gk.z);
    gk.w = fmaf(gate, kq.w, gk.w);
    gv.x = fmaf(gate, vq.x, gv.x);
    gv.y = fmaf(gate, vq.y, gv.y);
    gv.z = fmaf(gate, vq.z, gv.z);
    gv.w = fmaf(gate, vq.w, gv.w);
    gc += gate;
  }
  gkp[w][l] = gk;
  gvp[w][l] = gv;
  if (l == 0) gcp[w] = gc;
  __syncthreads();
  if (w == 0) {
#pragma unroll
    for (int ww = 1; ww < 4; ww++) {
      const float4 a = gkp[ww][l];
      gk.x += a.x; gk.y += a.y; gk.z += a.z; gk.w += a.w;
      const float4 bq = gvp[ww][l];
      gv.x += bq.x; gv.y += bq.y; gv.z += bq.z; gv.w += bq.w;
    }
    const float gct = gcp[0] + gcp[1] + gcp[2] + gcp[3];
    const float4 km = *(const float4*)(Km + (size_t)s * 256 + d0);
    const float4 vm = *(const float4*)(Vm + (size_t)s * 256 + d0);
    float4 ko, vo;
    ko.x = km.x + 0.1f * (gk.x - gct * km.x);
    ko.y = km.y + 0.1f * (gk.y - gct * km.y);
    ko.z = km.z + 0.1f * (gk.z - gct * km.z);
    ko.w = km.w + 0.1f * (gk.w - gct * km.w);
    vo.x = vm.x + 0.1f * (gv.x - gct * vm.x);
    vo.y = vm.y + 0.1f * (gv.y - gct * vm.y);
    vo.z = vm.z + 0.1f * (gv.z - gct * vm.z);
    vo.w = vm.w + 0.1f * (gv.w - gct * vm.w);
    *(float4*)(Ko + (size_t)s * 256 + d0) = ko;
    *(float4*)(Vo + (size_t)s * 256 + d0) = vo;
  }
}

// ---------------------------------------------------------------------------
extern "C" void kernel_launch(void* const* d_in, const int* in_sizes, int n_in,
                              void* d_out, int out_size, void* d_ws,
                              size_t ws_size, hipStream_t stream) {
  const float* x = (const float*)d_in[0];
  const float* W_in = (const float*)d_in[1];
  const float* b_in = (const float*)d_in[2];
  const float* W_q = (const float*)d_in[3];
  const float* b_q = (const float*)d_in[4];
  const float* g_q = (const float*)d_in[5];
  const float* be_q = (const float*)d_in[6];
  const float* K_mem = (const float*)d_in[7];
  const float* V_mem = (const float*)d_in[8];
  const float* W_kv = (const float*)d_in[9];
  const float* b_kv = (const float*)d_in[10];
  const float* g_kv = (const float*)d_in[11];
  const float* be_kv = (const float*)d_in[12];
  const float* W_o = (const float*)d_in[13];
  const float* b_o = (const float*)d_in[14];
  const float* g_o = (const float*)d_in[15];
  const float* be_o = (const float*)d_in[16];
  const float* g_1 = (const float*)d_in[17];
  const float* be_1 = (const float*)d_in[18];

  // d_out: [out(N*256) | K_new(S*256) | V_new(S*256) | surprise(N) | lr(N)]
  float* out_main = (float*)d_out;
  float* out_K = out_main + (size_t)NTOK * 256;
  float* out_V = out_K + (size_t)SMEM * 256;
  float* out_sur = out_V + (size_t)SMEM * 256;
  float* out_lr = out_sur + NTOK;

  // workspace layout (float offsets)
  float* ws = (float*)d_ws;
  float* x_proj = ws + (size_t)0;
  float* memout = ws + (size_t)8388608;
  float* keynew = ws + (size_t)16777216;
  float* valnew = ws + (size_t)25165824;
  u16* qhi = (u16*)(ws + (size_t)33554432);
  u16* qlo = (u16*)(ws + (size_t)37748736);
  u16* knhi = (u16*)(ws + (size_t)41943040);
  u16* knlo = (u16*)(ws + (size_t)46137344);
  u16* khi = (u16*)(ws + (size_t)50331648);
  u16* klo = (u16*)(ws + (size_t)50855936);
  u16* vthi = (u16*)(ws + (size_t)51380224);
  u16* vtlo = (u16*)(ws + (size_t)51904512);
  int* cnt = (int*)(ws + (size_t)52428800);
  int* cursor = (int*)(ws + (size_t)52432896);
  int* slot_start = (int*)(ws + (size_t)52436992);
  int* tok_list = (int*)(ws + (size_t)52445184);
  int* cand1 = (int*)(ws + (size_t)54530048);
  int* cand2 = (int*)(ws + (size_t)54562816);
  int* idx = (int*)(ws + (size_t)54595584);

  const dim3 b256(256), b128(128);
  split_k<<<512, b256, 0, stream>>>(K_mem, khi, klo);
  vt_split<<<128, b256, 0, stream>>>(V_mem, vthi, vtlo);
  gemm256<256, 0><<<NTOK / 32, b256, 0, stream>>>(
      x, nullptr, W_in, b_in, nullptr, nullptr, nullptr, nullptr, nullptr,
      x_proj, nullptr, nullptr);
  gemm256<256, 1><<<NTOK / 32, b256, 0, stream>>>(
      x_proj, nullptr, W_q, b_q, g_q, be_q, nullptr, nullptr, nullptr, nullptr,
      qhi, qlo);
  flash_mfma<<<NTOK / 64, b128, 0, stream>>>(qhi, qlo, khi, klo, vthi, vtlo,
                                             memout, out_sur);
  gemm_kv<<<NTOK / 16, b256, 0, stream>>>(x_proj, memout, W_kv, b_kv, g_kv,
                                          be_kv, keynew, knhi, knlo, valnew,
                                          out_lr);
  wsim_mfma<<<NTOK / 64, b128, 0, stream>>>(knhi, knlo, khi, klo, cand1, cand2);
  refine_argmax<<<NTOK / 4, b256, 0, stream>>>(keynew, K_mem, cand1, cand2,
                                               idx);
  zero_kernel<<<16, b256, 0, stream>>>((float*)cnt, SMEM);
  hist_kernel<<<NTOK / 256, b256, 0, stream>>>(idx, cnt);
  scan4096<<<1, 1024, 0, stream>>>(cnt, slot_start, cursor);
  fill_kernel<<<NTOK / 256, b256, 0, stream>>>(idx, cursor, tok_list);
  gather_update<<<SMEM, b256, 0, stream>>>(keynew, valnew, out_sur,
                                           slot_start, tok_list, K_mem,
                                           V_mem, out_K, out_V);
  gemm256<512, 2><<<NTOK / 32, b256, 0, stream>>>(
      x_proj, memout, W_o, b_o, g_o, be_o, g_1, be_1, x_proj, out_main,
      nullptr, nullptr);
}

// Round 7
// 3289.647 us; speedup vs baseline: 1.6423x; 1.0242x over previous
//
#include <hip/hip_runtime.h>
#include <math.h>

// Shapes fixed by setup_inputs: B=4, T=8192 -> N=32768 tokens, D=256, H=256, S=4096.
#define NTOK 32768
#define SMEM 4096
#define NC 128  // 32-slot chunks

typedef unsigned short u16;
typedef __attribute__((ext_vector_type(8))) short bf16x8_t;
typedef __attribute__((ext_vector_type(4))) float f32x4_t;

#define MFMA16(A, B, C) __builtin_amdgcn_mfma_f32_16x16x32_bf16(A, B, C, 0, 0, 0)

__device__ __forceinline__ float gelu_f(float x) {
  return 0.5f * x * (1.0f + erff(x * 0.7071067811865475f));
}
__device__ __forceinline__ u16 f2bf(float x) {
  unsigned u = __float_as_uint(x);
  return (u16)((u + 0x7FFFu + ((u >> 16) & 1u)) >> 16);
}
__device__ __forceinline__ float bf2f(u16 h) {
  return __uint_as_float(((unsigned)h) << 16);
}

// ---------------------------------------------------------------------------
// Prep 1: split K_mem -> khi/klo (bf16 hi + residual lo)
// ---------------------------------------------------------------------------
__global__ __launch_bounds__(256) void split_k(const float* __restrict__ K,
                                               u16* __restrict__ khi,
                                               u16* __restrict__ klo) {
  const int i8 = (blockIdx.x * 256 + threadIdx.x) * 8;
  union { u16 u[8]; float4 f; } H, L;
#pragma unroll
  for (int j = 0; j < 8; j++) {
    const float v = K[i8 + j];
    const u16 h = f2bf(v);
    H.u[j] = h;
    L.u[j] = f2bf(v - bf2f(h));
  }
  *(float4*)(khi + i8) = H.f;
  *(float4*)(klo + i8) = L.f;
}

// ---------------------------------------------------------------------------
// Prep 2: V_mem[4096][256] -> vthi/vtlo transposed [256][4096] bf16 hi/lo
// ---------------------------------------------------------------------------
__global__ __launch_bounds__(256) void vt_split(const float* __restrict__ V,
                                                u16* __restrict__ vthi,
                                                u16* __restrict__ vtlo) {
  __shared__ float Vs[32][260];
  const int t = threadIdx.x;
  const int s0 = (blockIdx.x & 15) * 256;
  const int d0 = (blockIdx.x >> 4) * 32;
#pragma unroll
  for (int m = 0; m < 8; m++) {
    const int r = (t >> 3) + 32 * m;
    const float4 v =
        *(const float4*)(V + (size_t)(s0 + r) * 256 + d0 + (t & 7) * 4);
    Vs[(t & 7) * 4 + 0][r] = v.x;
    Vs[(t & 7) * 4 + 1][r] = v.y;
    Vs[(t & 7) * 4 + 2][r] = v.z;
    Vs[(t & 7) * 4 + 3][r] = v.w;
  }
  __syncthreads();
  const int dl = t >> 3;
  const int sl0 = (t & 7) * 32;
  union { u16 u[8]; float4 f; } H[4], L[4];
#pragma unroll
  for (int i = 0; i < 8; i++) {
    const float4 v = *(const float4*)&Vs[dl][sl0 + i * 4];
    const float vv[4] = {v.x, v.y, v.z, v.w};
#pragma unroll
    for (int j = 0; j < 4; j++) {
      const u16 h = f2bf(vv[j]);
      H[i >> 1].u[(i & 1) * 4 + j] = h;
      L[i >> 1].u[(i & 1) * 4 + j] = f2bf(vv[j] - bf2f(h));
    }
  }
  const size_t ob = (size_t)(d0 + dl) * 4096 + s0 + sl0;
#pragma unroll
  for (int i = 0; i < 4; i++) {
    *(float4*)(vthi + ob + i * 8) = H[i].f;
    *(float4*)(vtlo + ob + i * 8) = L[i].f;
  }
}

// ---------------------------------------------------------------------------
// GEMM BN=256, BM=32, KSTEP=32, 256 threads (unchanged).
// ---------------------------------------------------------------------------
template <int KDIM, int EPI>
__global__ __launch_bounds__(256) void gemm256(
    const float* __restrict__ A1, const float* __restrict__ A2,
    const float* __restrict__ W, const float* __restrict__ bias,
    const float* __restrict__ g0, const float* __restrict__ be0,
    const float* __restrict__ g1, const float* __restrict__ be1,
    const float* __restrict__ ident, float* __restrict__ out,
    u16* __restrict__ bh, u16* __restrict__ bl) {
  __shared__ float As[32][36];
  __shared__ float Bs[32][256];
  const int t = threadIdx.x;
  const int tx = t & 63;
  const int ty = t >> 6;
  const int row0 = blockIdx.x * 32;
  const int c0 = tx * 4;

  float acc[8][4];
#pragma unroll
  for (int r = 0; r < 8; r++)
#pragma unroll
    for (int j = 0; j < 4; j++) acc[r][j] = 0.f;

  const int ar = t >> 3;
  const int akc = (t & 7) * 4;

  for (int k0 = 0; k0 < KDIM; k0 += 32) {
    float4 av;
    if (KDIM == 512) {
      const int kg = k0 + akc;
      const float* src = (kg < 256) ? A1 : A2;
      av = *(const float4*)(src + (size_t)(row0 + ar) * 256 + (kg & 255));
    } else {
      av = *(const float4*)(A1 + (size_t)(row0 + ar) * 256 + k0 + akc);
    }
    As[akc + 0][ar] = av.x;
    As[akc + 1][ar] = av.y;
    As[akc + 2][ar] = av.z;
    As[akc + 3][ar] = av.w;
#pragma unroll
    for (int j = 0; j < 8; j++) {
      *(float4*)&Bs[ar][akc + j * 32] =
          *(const float4*)(W + (size_t)(k0 + ar) * 256 + akc + j * 32);
    }
    __syncthreads();
#pragma unroll
    for (int kk = 0; kk < 32; kk++) {
      const float4 bv = *(const float4*)&Bs[kk][c0];
      const float4 a0 = *(const float4*)&As[kk][ty * 8];
      const float4 a1 = *(const float4*)&As[kk][ty * 8 + 4];
      const float a8[8] = {a0.x, a0.y, a0.z, a0.w, a1.x, a1.y, a1.z, a1.w};
      const float b4[4] = {bv.x, bv.y, bv.z, bv.w};
#pragma unroll
      for (int r = 0; r < 8; r++)
#pragma unroll
        for (int j = 0; j < 4; j++) acc[r][j] = fmaf(a8[r], b4[j], acc[r][j]);
    }
    __syncthreads();
  }

  float bb[4];
#pragma unroll
  for (int j = 0; j < 4; j++) bb[j] = bias[c0 + j];
#pragma unroll
  for (int r = 0; r < 8; r++)
#pragma unroll
    for (int j = 0; j < 4; j++) acc[r][j] += bb[j];

  if (EPI == 0) {
#pragma unroll
    for (int r = 0; r < 8; r++) {
      float4 v = make_float4(acc[r][0], acc[r][1], acc[r][2], acc[r][3]);
      *(float4*)(out + (size_t)(row0 + ty * 8 + r) * 256 + c0) = v;
    }
    return;
  }

  float gg[4], ee[4];
#pragma unroll
  for (int j = 0; j < 4; j++) {
    gg[j] = g0[c0 + j];
    ee[j] = be0[c0 + j];
  }

#pragma unroll
  for (int r = 0; r < 8; r++) {
    float s1 = acc[r][0] + acc[r][1] + acc[r][2] + acc[r][3];
    float s2 = acc[r][0] * acc[r][0] + acc[r][1] * acc[r][1] +
               acc[r][2] * acc[r][2] + acc[r][3] * acc[r][3];
#pragma unroll
    for (int mk = 1; mk < 64; mk <<= 1) {
      s1 += __shfl_xor(s1, mk, 64);
      s2 += __shfl_xor(s2, mk, 64);
    }
    const float mu = s1 * (1.0f / 256.0f);
    const float rstd = rsqrtf(s2 * (1.0f / 256.0f) - mu * mu + 1e-5f);
    if (EPI == 1) {
      float q[4];
#pragma unroll
      for (int j = 0; j < 4; j++)
        q[j] = gelu_f((acc[r][j] - mu) * rstd * gg[j] + ee[j]) * 0.0625f;
      ushort4 hv, lv;
      u16 h;
      h = f2bf(q[0]); hv.x = h; lv.x = f2bf(q[0] - bf2f(h));
      h = f2bf(q[1]); hv.y = h; lv.y = f2bf(q[1] - bf2f(h));
      h = f2bf(q[2]); hv.z = h; lv.z = f2bf(q[2] - bf2f(h));
      h = f2bf(q[3]); hv.w = h; lv.w = f2bf(q[3] - bf2f(h));
      const size_t o = (size_t)(row0 + ty * 8 + r) * 256 + c0;
      *(ushort4*)(bh + o) = hv;
      *(ushort4*)(bl + o) = lv;
    } else {
      const float4 idv =
          *(const float4*)(ident + (size_t)(row0 + ty * 8 + r) * 256 + c0);
      acc[r][0] = (acc[r][0] - mu) * rstd * gg[0] + ee[0] + idv.x;
      acc[r][1] = (acc[r][1] - mu) * rstd * gg[1] + ee[1] + idv.y;
      acc[r][2] = (acc[r][2] - mu) * rstd * gg[2] + ee[2] + idv.z;
      acc[r][3] = (acc[r][3] - mu) * rstd * gg[3] + ee[3] + idv.w;
    }
  }

  if (EPI == 2) {
    float g1v[4], e1v[4];
#pragma unroll
    for (int j = 0; j < 4; j++) {
      g1v[j] = g1[c0 + j];
      e1v[j] = be1[c0 + j];
    }
#pragma unroll
    for (int r = 0; r < 8; r++) {
      float s1 = acc[r][0] + acc[r][1] + acc[r][2] + acc[r][3];
      float s2 = acc[r][0] * acc[r][0] + acc[r][1] * acc[r][1] +
                 acc[r][2] * acc[r][2] + acc[r][3] * acc[r][3];
#pragma unroll
      for (int mk = 1; mk < 64; mk <<= 1) {
        s1 += __shfl_xor(s1, mk, 64);
        s2 += __shfl_xor(s2, mk, 64);
      }
      const float mu = s1 * (1.0f / 256.0f);
      const float rstd = rsqrtf(s2 * (1.0f / 256.0f) - mu * mu + 1e-5f);
      float4 v;
      v.x = (acc[r][0] - mu) * rstd * g1v[0] + e1v[0];
      v.y = (acc[r][1] - mu) * rstd * g1v[1] + e1v[1];
      v.z = (acc[r][2] - mu) * rstd * g1v[2] + e1v[2];
      v.w = (acc[r][3] - mu) * rstd * g1v[3] + e1v[3];
      *(float4*)(out + (size_t)(row0 + ty * 8 + r) * 256 + c0) = v;
    }
  }
}

// ---------------------------------------------------------------------------
// kv GEMM (unchanged).
// ---------------------------------------------------------------------------
__global__ __launch_bounds__(256) void gemm_kv(
    const float* __restrict__ A1, const float* __restrict__ A2,
    const float* __restrict__ W, const float* __restrict__ bias,
    const float* __restrict__ gln, const float* __restrict__ bln,
    float* __restrict__ key_new, u16* __restrict__ knhi, u16* __restrict__ knlo,
    float* __restrict__ value_new, float* __restrict__ lr_out) {
  __shared__ float As[16][20];
  __shared__ float Bs[16][768];
  const int t = threadIdx.x;
  const int tx = t & 63;
  const int ty = t >> 6;
  const int row0 = blockIdx.x * 16;
  const int c0 = tx * 4;

  float acc[4][3][4];
#pragma unroll
  for (int r = 0; r < 4; r++)
#pragma unroll
    for (int g = 0; g < 3; g++)
#pragma unroll
      for (int j = 0; j < 4; j++) acc[r][g][j] = 0.f;

  for (int k0 = 0; k0 < 512; k0 += 16) {
    if (t < 64) {
      const int r = t & 15;
      const int kc = (t >> 4) * 4;
      const int kg = k0 + kc;
      const float* src = (kg < 256) ? A1 : A2;
      const float4 av =
          *(const float4*)(src + (size_t)(row0 + r) * 256 + (kg & 255));
      As[kc + 0][r] = av.x;
      As[kc + 1][r] = av.y;
      As[kc + 2][r] = av.z;
      As[kc + 3][r] = av.w;
    }
    {
      const int kk = t >> 4;
      const int bc = (t & 15) * 4;
#pragma unroll
      for (int j = 0; j < 12; j++)
        *(float4*)&Bs[kk][bc + j * 64] =
            *(const float4*)(W + (size_t)(k0 + kk) * 768 + bc + j * 64);
    }
    __syncthreads();
#pragma unroll
    for (int kk = 0; kk < 16; kk++) {
      const float4 a = *(const float4*)&As[kk][ty * 4];
      const float a4[4] = {a.x, a.y, a.z, a.w};
#pragma unroll
      for (int g = 0; g < 3; g++) {
        const float4 b = *(const float4*)&Bs[kk][g * 256 + c0];
#pragma unroll
        for (int r = 0; r < 4; r++) {
          acc[r][g][0] = fmaf(a4[r], b.x, acc[r][g][0]);
          acc[r][g][1] = fmaf(a4[r], b.y, acc[r][g][1]);
          acc[r][g][2] = fmaf(a4[r], b.z, acc[r][g][2]);
          acc[r][g][3] = fmaf(a4[r], b.w, acc[r][g][3]);
        }
      }
    }
    __syncthreads();
  }

  float bv[3][4], gw[3][4], ew[3][4];
#pragma unroll
  for (int g = 0; g < 3; g++)
#pragma unroll
    for (int j = 0; j < 4; j++) {
      bv[g][j] = bias[g * 256 + c0 + j];
      gw[g][j] = gln[g * 256 + c0 + j];
      ew[g][j] = bln[g * 256 + c0 + j];
    }

#pragma unroll
  for (int r = 0; r < 4; r++) {
    float s1 = 0.f, s2 = 0.f;
#pragma unroll
    for (int g = 0; g < 3; g++)
#pragma unroll
      for (int j = 0; j < 4; j++) {
        acc[r][g][j] += bv[g][j];
        s1 += acc[r][g][j];
        s2 += acc[r][g][j] * acc[r][g][j];
      }
#pragma unroll
    for (int mk = 1; mk < 64; mk <<= 1) {
      s1 += __shfl_xor(s1, mk, 64);
      s2 += __shfl_xor(s2, mk, 64);
    }
    const float mu = s1 * (1.0f / 768.0f);
    const float rstd = rsqrtf(s2 * (1.0f / 768.0f) - mu * mu + 1e-5f);
    const size_t orow = (size_t)(row0 + ty * 4 + r) * 256 + c0;
    float kq[4];
    float4 vv;
#pragma unroll
    for (int j = 0; j < 4; j++)
      kq[j] = gelu_f((acc[r][0][j] - mu) * rstd * gw[0][j] + ew[0][j]);
    vv.x = gelu_f((acc[r][1][0] - mu) * rstd * gw[1][0] + ew[1][0]);
    vv.y = gelu_f((acc[r][1][1] - mu) * rstd * gw[1][1] + ew[1][1]);
    vv.z = gelu_f((acc[r][1][2] - mu) * rstd * gw[1][2] + ew[1][2]);
    vv.w = gelu_f((acc[r][1][3] - mu) * rstd * gw[1][3] + ew[1][3]);
    *(float4*)(key_new + orow) = make_float4(kq[0], kq[1], kq[2], kq[3]);
    *(float4*)(value_new + orow) = vv;
    ushort4 hv, lv;
    u16 h;
    h = f2bf(kq[0]); hv.x = h; lv.x = f2bf(kq[0] - bf2f(h));
    h = f2bf(kq[1]); hv.y = h; lv.y = f2bf(kq[1] - bf2f(h));
    h = f2bf(kq[2]); hv.z = h; lv.z = f2bf(kq[2] - bf2f(h));
    h = f2bf(kq[3]); hv.w = h; lv.w = f2bf(kq[3] - bf2f(h));
    *(ushort4*)(knhi + orow) = hv;
    *(ushort4*)(knlo + orow) = lv;
    float ls = 0.f;
#pragma unroll
    for (int j = 0; j < 4; j++) {
      const float lvv = gelu_f((acc[r][2][j] - mu) * rstd * gw[2][j] + ew[2][j]);
      ls += 1.0f / (1.0f + __expf(-lvv));
    }
#pragma unroll
    for (int mk = 1; mk < 64; mk <<= 1) ls += __shfl_xor(ls, mk, 64);
    if (tx == 0) lr_out[row0 + ty * 4 + r] = ls * (1.0f / 256.0f);
  }
}

// ---------------------------------------------------------------------------
// Flash read v3: 256 threads = 4 waves, 16 tokens/wave (64/block), grid 512
// -> 8 waves/CU. Reg-staging (global gather -> VGPR -> linear ds_write_b128)
// replaces global_load_lds (which serialized). 2 barriers/chunk; per-token
// MFMA sequence identical to R6 (3-product throughout).
// ---------------------------------------------------------------------------
__global__ __launch_bounds__(256) void flash_mfma(
    const u16* __restrict__ qhi, const u16* __restrict__ qlo,
    const u16* __restrict__ khi, const u16* __restrict__ klo,
    const u16* __restrict__ vthi, const u16* __restrict__ vtlo,
    float* __restrict__ memout, float* __restrict__ surprise_out) {
  __shared__ u16 Kb[2][8192];      // [prec][1024 slots * 8]
  __shared__ u16 Vb[2][8192];
  __shared__ u16 pbuf[4][2][512];  // [wave][prec][64 slots * 8]
  __shared__ float scf[4][16];
  const int t = threadIdx.x;
  const int w = t >> 6;
  const int l = t & 63;
  const int s = l & 15;
  const int g = l >> 4;
  const int row0 = blockIdx.x * 64 + w * 16;
  const int p0 = (g * 16 + s) * 8;

  // staging: this wave covers slots sid = i*256 + w*64 + l, i<4.
  // kin/vin = global u16 offset of slot sid's content; lsl = LDS u16 offset.
  int kin[4], vin[4], lsl[4];
#pragma unroll
  for (int i = 0; i < 4; i++) {
    const int sid = i * 256 + w * 64 + l;
    kin[i] = (((sid >> 6) & 1) * 16 + (sid & 15)) * 256 + (sid >> 7) * 32 +
             ((sid >> 4) & 3) * 8;
    vin[i] = ((sid >> 6) * 16 + (sid & 15)) * 4096 + ((sid >> 4) & 3) * 8;
    lsl[i] = sid * 8;
  }

  // Q fragments in registers (16 tokens)
  bf16x8_t qh[8], ql[8];
#pragma unroll
  for (int ks = 0; ks < 8; ks++) {
    const size_t qo = (size_t)(row0 + s) * 256 + ks * 32 + g * 8;
    qh[ks] = *(const bf16x8_t*)(qhi + qo);
    ql[ks] = *(const bf16x8_t*)(qlo + qo);
  }

  f32x4_t o_acc[16];
  f32x4_t l_acc;
  float m_st[4];
#pragma unroll
  for (int nt = 0; nt < 16; nt++)
#pragma unroll
    for (int j = 0; j < 4; j++) o_acc[nt][j] = 0.f;
#pragma unroll
  for (int j = 0; j < 4; j++) l_acc[j] = 0.f;
#pragma unroll
  for (int q = 0; q < 4; q++) m_st[q] = -INFINITY;
  bf16x8_t ones;
#pragma unroll
  for (int j = 0; j < 8; j++) ones[j] = (short)0x3F80;

  // prologue: stage K(0)
  bf16x8_t kst[2][4];
#pragma unroll
  for (int i = 0; i < 4; i++) {
    kst[0][i] = *(const bf16x8_t*)(khi + kin[i]);
    kst[1][i] = *(const bf16x8_t*)(klo + kin[i]);
  }
#pragma unroll
  for (int i = 0; i < 4; i++) {
    *(bf16x8_t*)&Kb[0][lsl[i]] = kst[0][i];
    *(bf16x8_t*)&Kb[1][lsl[i]] = kst[1][i];
  }

  for (int c = 0; c < NC; c++) {
    const int c0 = c * 32;
    __syncthreads();  // (A) Kb[c] visible; Vb free
    // issue V(c) gather (flies under QK)
    bf16x8_t vst[2][4];
#pragma unroll
    for (int i = 0; i < 4; i++) {
      vst[0][i] = *(const bf16x8_t*)(vthi + c0 + vin[i]);
      vst[1][i] = *(const bf16x8_t*)(vtlo + c0 + vin[i]);
    }
    // ---- scores: 3-product ----
    f32x4_t sacc[2];
#pragma unroll
    for (int nt = 0; nt < 2; nt++)
#pragma unroll
      for (int j = 0; j < 4; j++) sacc[nt][j] = 0.f;
#pragma unroll
    for (int ks = 0; ks < 8; ks++) {
#pragma unroll
      for (int nt = 0; nt < 2; nt++) {
        const int ko = ks * 1024 + nt * 512 + p0;
        const bf16x8_t kh = *(const bf16x8_t*)&Kb[0][ko];
        const bf16x8_t kl = *(const bf16x8_t*)&Kb[1][ko];
        sacc[nt] = MFMA16(qh[ks], kh, sacc[nt]);
        sacc[nt] = MFMA16(ql[ks], kh, sacc[nt]);
        sacc[nt] = MFMA16(qh[ks], kl, sacc[nt]);
      }
    }
    // ---- online softmax (tokens: g*4+q) ----
    float cmax[4];
    bool needb = false;
#pragma unroll
    for (int q = 0; q < 4; q++) {
      float v = fmaxf(sacc[0][q], sacc[1][q]);
#pragma unroll
      for (int mk = 1; mk < 16; mk <<= 1) v = fmaxf(v, __shfl_xor(v, mk, 64));
      cmax[q] = v;
      needb |= (v > m_st[q]);
    }
    const bool need = (__ballot(needb) != 0ull);
#pragma unroll
    for (int q = 0; q < 4; q++) {
      const float mold = m_st[q];
      const float mnew = need ? fmaxf(mold, cmax[q]) : mold;
      const float e0 = __expf(sacc[0][q] - mnew);
      const float e1 = __expf(sacc[1][q] - mnew);
      const int cg0 = s >> 3, w0 = s & 7;
      const int i0 = (cg0 * 16 + g * 4 + q) * 8 + w0;        // col s
      const int i1 = ((2 + cg0) * 16 + g * 4 + q) * 8 + w0;  // col 16+s
      u16 h;
      h = f2bf(e0);
      pbuf[w][0][i0] = h;
      pbuf[w][1][i0] = f2bf(e0 - bf2f(h));
      h = f2bf(e1);
      pbuf[w][0][i1] = h;
      pbuf[w][1][i1] = f2bf(e1 - bf2f(h));
      if (need) {
        if (s == 0) scf[w][g * 4 + q] = __expf(mold - mnew);
        m_st[q] = mnew;
      }
    }
    // write V(c) to LDS (linear, conflict-free)
#pragma unroll
    for (int i = 0; i < 4; i++) {
      *(bf16x8_t*)&Vb[0][lsl[i]] = vst[0][i];
      *(bf16x8_t*)&Vb[1][lsl[i]] = vst[1][i];
    }
    __syncthreads();  // (B) Vb[c] + pbuf visible; Kb free
    // issue K(c+1) gather (flies under PV)
    if (c + 1 < NC) {
      const size_t cofs = (size_t)(c0 + 32) * 256;
#pragma unroll
      for (int i = 0; i < 4; i++) {
        kst[0][i] = *(const bf16x8_t*)(khi + cofs + kin[i]);
        kst[1][i] = *(const bf16x8_t*)(klo + cofs + kin[i]);
      }
    }
    // ---- rescale (exact defer) ----
    if (need) {
      const float scv = scf[w][s];
#pragma unroll
      for (int j = 0; j < 4; j++) l_acc[j] *= scv;
#pragma unroll
      for (int nt = 0; nt < 16; nt++)
#pragma unroll
        for (int j = 0; j < 4; j++) o_acc[nt][j] *= scv;
    }
    // ---- P fragments + l ----
    const bf16x8_t ph = *(const bf16x8_t*)&pbuf[w][0][p0];
    const bf16x8_t pl = *(const bf16x8_t*)&pbuf[w][1][p0];
    l_acc = MFMA16(ones, ph, l_acc);
    l_acc = MFMA16(ones, pl, l_acc);
    // ---- PV: O^T = V^T @ P^T (3-product) ----
#pragma unroll
    for (int nt = 0; nt < 16; nt++) {
      const int vo = nt * 512 + p0;
      const bf16x8_t vh = *(const bf16x8_t*)&Vb[0][vo];
      const bf16x8_t vl = *(const bf16x8_t*)&Vb[1][vo];
      o_acc[nt] = MFMA16(vh, ph, o_acc[nt]);
      o_acc[nt] = MFMA16(vl, ph, o_acc[nt]);
      o_acc[nt] = MFMA16(vh, pl, o_acc[nt]);
    }
    // write K(c+1) to LDS (Kb free since barrier B)
    if (c + 1 < NC) {
#pragma unroll
      for (int i = 0; i < 4; i++) {
        *(bf16x8_t*)&Kb[0][lsl[i]] = kst[0][i];
        *(bf16x8_t*)&Kb[1][lsl[i]] = kst[1][i];
      }
    }
  }
  // ---- epilogue ----
  const float li = 1.0f / l_acc[0];
  if (g == 0) surprise_out[row0 + s] = 1.0f - li;
  const size_t rb = (size_t)(row0 + s) * 256;
#pragma unroll
  for (int nt = 0; nt < 16; nt++) {
    float4 v = make_float4(o_acc[nt][0] * li, o_acc[nt][1] * li,
                           o_acc[nt][2] * li, o_acc[nt][3] * li);
    *(float4*)(memout + rb + nt * 16 + g * 4) = v;
  }
}

// ---------------------------------------------------------------------------
// wsim v3: LDS-free, barrier-free. 256 threads = 4 waves, 16 tokens/wave,
// grid 512 -> 2048 waves = 8/CU. K fragments loaded directly global->VGPR
// (64B-line-coalesced gather, L2-resident). MFMA order identical to R6.
// ---------------------------------------------------------------------------
__device__ __forceinline__ void top2_upd(float a, int ia, float& v1, int& i1,
                                         float& v2, int& i2) {
  if (a > v1 || (a == v1 && ia < i1)) {
    v2 = v1; i2 = i1; v1 = a; i1 = ia;
  } else if (a > v2 || (a == v2 && ia < i2)) {
    v2 = a; i2 = ia;
  }
}

__global__ __launch_bounds__(256) void wsim_mfma(
    const u16* __restrict__ knhi, const u16* __restrict__ knlo,
    const u16* __restrict__ khi, const u16* __restrict__ klo,
    int* __restrict__ cand1, int* __restrict__ cand2) {
  const int t = threadIdx.x;
  const int w = t >> 6;
  const int l = t & 63;
  const int s = l & 15;
  const int g = l >> 4;
  const int row0 = blockIdx.x * 64 + w * 16;

  bf16x8_t ah[8], al[8];
#pragma unroll
  for (int ks = 0; ks < 8; ks++) {
    const size_t qo = (size_t)(row0 + s) * 256 + ks * 32 + g * 8;
    ah[ks] = *(const bf16x8_t*)(knhi + qo);
    al[ks] = *(const bf16x8_t*)(knlo + qo);
  }
  float v1[4], v2[4];
  int i1[4], i2[4];
#pragma unroll
  for (int q = 0; q < 4; q++) {
    v1[q] = -INFINITY; v2[q] = -INFINITY;
    i1[q] = 0; i2[q] = 0;
  }

  for (int c = 0; c < NC; c++) {
    const size_t cb = (size_t)c * 8192;
    f32x4_t sacc[2];
#pragma unroll
    for (int nt = 0; nt < 2; nt++)
#pragma unroll
      for (int j = 0; j < 4; j++) sacc[nt][j] = 0.f;
    // two half-chunks of ks: 16 loads in flight per group
#pragma unroll
    for (int half = 0; half < 2; half++) {
      bf16x8_t kf[4][2][2];  // [ks4][nt][prec]
#pragma unroll
      for (int ks4 = 0; ks4 < 4; ks4++) {
        const int ks = half * 4 + ks4;
#pragma unroll
        for (int nt = 0; nt < 2; nt++) {
          const size_t o = cb + (size_t)(nt * 16 + s) * 256 + ks * 32 + g * 8;
          kf[ks4][nt][0] = *(const bf16x8_t*)(khi + o);
          kf[ks4][nt][1] = *(const bf16x8_t*)(klo + o);
        }
      }
#pragma unroll
      for (int ks4 = 0; ks4 < 4; ks4++) {
        const int ks = half * 4 + ks4;
#pragma unroll
        for (int nt = 0; nt < 2; nt++) {
          sacc[nt] = MFMA16(ah[ks], kf[ks4][nt][0], sacc[nt]);
          sacc[nt] = MFMA16(al[ks], kf[ks4][nt][0], sacc[nt]);
          sacc[nt] = MFMA16(ah[ks], kf[ks4][nt][1], sacc[nt]);
        }
      }
    }
    const int c0 = c * 32;
#pragma unroll
    for (int q = 0; q < 4; q++) {
      top2_upd(sacc[0][q], c0 + s, v1[q], i1[q], v2[q], i2[q]);
      top2_upd(sacc[1][q], c0 + 16 + s, v1[q], i1[q], v2[q], i2[q]);
    }
  }
  // cross-lane merge over the 16 slot-lanes
#pragma unroll
  for (int q = 0; q < 4; q++) {
#pragma unroll
    for (int mk = 1; mk < 16; mk <<= 1) {
      const float w1 = __shfl_xor(v1[q], mk, 64);
      const int j1 = __shfl_xor(i1[q], mk, 64);
      const float w2 = __shfl_xor(v2[q], mk, 64);
      const int j2 = __shfl_xor(i2[q], mk, 64);
      const bool take = (w1 > v1[q]) || (w1 == v1[q] && j1 < i1[q]);
      const float ca = take ? v1[q] : w1;
      const int ja = take ? i1[q] : j1;
      const float cb2 = take ? w2 : v2[q];
      const int jb = take ? j2 : i2[q];
      v1[q] = take ? w1 : v1[q];
      i1[q] = take ? j1 : i1[q];
      const bool t2 = (cb2 > ca) || (cb2 == ca && jb < ja);
      v2[q] = t2 ? cb2 : ca;
      i2[q] = t2 ? jb : ja;
    }
    if (s == 0) {
      cand1[row0 + g * 4 + q] = i1[q];
      cand2[row0 + g * 4 + q] = i2[q];
    }
  }
}

// exact fp32 re-check of the two candidates -> final argmax index
__global__ __launch_bounds__(256) void refine_argmax(
    const float* __restrict__ kn, const float* __restrict__ Km,
    const int* __restrict__ cand1, const int* __restrict__ cand2,
    int* __restrict__ idx) {
  const int t = threadIdx.x;
  const int w = t >> 6;
  const int l = t & 63;
  const int tok = blockIdx.x * 4 + w;
  const int c1 = cand1[tok], c2 = cand2[tok];
  const float4 a = *(const float4*)(kn + (size_t)tok * 256 + l * 4);
  const float4 b1 = *(const float4*)(Km + (size_t)c1 * 256 + l * 4);
  const float4 b2 = *(const float4*)(Km + (size_t)c2 * 256 + l * 4);
  float d1 = a.x * b1.x + a.y * b1.y + a.z * b1.z + a.w * b1.w;
  float d2 = a.x * b2.x + a.y * b2.y + a.z * b2.z + a.w * b2.w;
#pragma unroll
  for (int mk = 1; mk < 64; mk <<= 1) {
    d1 += __shfl_xor(d1, mk, 64);
    d2 += __shfl_xor(d2, mk, 64);
  }
  if (l == 0) idx[tok] = (d2 > d1 || (d2 == d1 && c2 < c1)) ? c2 : c1;
}

// ---------------------------------------------------------------------------
// Binned write path (unchanged).
// ---------------------------------------------------------------------------
__global__ void zero_kernel(float* __restrict__ p, int n) {
  int i = blockIdx.x * blockDim.x + threadIdx.x;
  const int stride = gridDim.x * blockDim.x;
  for (; i < n; i += stride) p[i] = 0.f;
}

__global__ __launch_bounds__(256) void hist_kernel(const int* __restrict__ idx,
                                                   int* __restrict__ cnt) {
  const int i = blockIdx.x * 256 + threadIdx.x;
  atomicAdd(&cnt[idx[i]], 1);
}

__global__ __launch_bounds__(1024) void scan4096(const int* __restrict__ cnt,
                                                 int* __restrict__ start,
                                                 int* __restrict__ cursor) {
  __shared__ int sums[1024];
  const int t = threadIdx.x;
  const int4 c = *(const int4*)(cnt + t * 4);
  const int local = c.x + c.y + c.z + c.w;
  sums[t] = local;
  __syncthreads();
  int acc = local;
  for (int off = 1; off < 1024; off <<= 1) {
    const int v = (t >= off) ? sums[t - off] : 0;
    __syncthreads();
    acc += v;
    sums[t] = acc;
    __syncthreads();
  }
  const int base = acc - local;
  int4 st;
  st.x = base;
  st.y = base + c.x;
  st.z = st.y + c.y;
  st.w = st.z + c.z;
  *(int4*)(start + t * 4) = st;
  *(int4*)(cursor + t * 4) = st;
  if (t == 1023) start[4096] = acc;
}

__global__ __launch_bounds__(256) void fill_kernel(const int* __restrict__ idx,
                                                   int* __restrict__ cursor,
                                                   int* __restrict__ tok_list) {
  const int i = blockIdx.x * 256 + threadIdx.x;
  const int pos = atomicAdd(&cursor[idx[i]], 1);
  tok_list[pos] = i;
}

__global__ __launch_bounds__(256) void gather_update(
    const float* __restrict__ keyn, const float* __restrict__ valn,
    const float* __restrict__ surprise, const int* __restrict__ start,
    const int* __restrict__ tok_list, const float* __restrict__ Km,
    const float* __restrict__ Vm, float* __restrict__ Ko,
    float* __restrict__ Vo) {
  __shared__ float4 gkp[4][64];
  __shared__ float4 gvp[4][64];
  __shared__ float gcp[4];
  const int t = threadIdx.x;
  const int w = t >> 6;
  const int l = t & 63;
  const int s = blockIdx.x;
  const int d0 = l * 4;
  const int b = start[s];
  const int e = start[s + 1];
  float4 gk = make_float4(0.f, 0.f, 0.f, 0.f);
  float4 gv = make_float4(0.f, 0.f, 0.f, 0.f);
  float gc = 0.f;
  for (int i = b + w; i < e; i += 4) {
    const int tok = tok_list[i];
    const float gate = surprise[tok];
    const float4 kq = *(const float4*)(keyn + (size_t)tok * 256 + d0);
    const float4 vq = *(const float4*)(valn + (size_t)tok * 256 + d0);
    gk.x = fmaf(gate, kq.x, gk.x);
    gk.y = fmaf(gate, kq.y, gk.y);
    gk.z = fmaf(gate, kq.z, gk.z);
    gk.w = fmaf(gate, kq.w, gk.w);
    gv.x = fmaf(gate, vq.x, gv.x);
    gv.y = fmaf(gate, vq.y, gv.y);
    gv.z = fmaf(gate, vq.z, gv.z);
    gv.w = fmaf(gate, vq.w, gv.w);
    gc += gate;
  }
  gkp[w][l] = gk;
  gvp[w][l] = gv;
  if (l == 0) gcp[w] = gc;
  __syncthreads();
  if (w == 0) {
#pragma unroll
    for (int ww = 1; ww < 4; ww++) {
      const float4 a = gkp[ww][l];
      gk.x += a.x; gk.y += a.y; gk.z += a.z; gk.w += a.w;
      const float4 bq = gvp[ww][l];
      gv.x += bq.x; gv.y += bq.y; gv.z += bq.z; gv.w += bq.w;
    }
    const float gct = gcp[0] + gcp[1] + gcp[2] + gcp[3];
    const float4 km = *(const float4*)(Km + (size_t)s * 256 + d0);
    const float4 vm = *(const float4*)(Vm + (size_t)s * 256 + d0);
    float4 ko, vo;
    ko.x = km.x + 0.1f * (gk.x - gct * km.x);
    ko.y = km.y + 0.1f * (gk.y - gct * km.y);
    ko.z = km.z + 0.1f * (gk.z - gct * km.z);
    ko.w = km.w + 0.1f * (gk.w - gct * km.w);
    vo.x = vm.x + 0.1f * (gv.x - gct * vm.x);
    vo.y = vm.y + 0.1f * (gv.y - gct * vm.y);
    vo.z = vm.z + 0.1f * (gv.z - gct * vm.z);
    vo.w = vm.w + 0.1f * (gv.w - gct * vm.w);
    *(float4*)(Ko + (size_t)s * 256 + d0) = ko;
    *(float4*)(Vo + (size_t)s * 256 + d0) = vo;
  }
}

// ---------------------------------------------------------------------------
extern "C" void kernel_launch(void* const* d_in, const int* in_sizes, int n_in,
                              void* d_out, int out_size, void* d_ws,
                              size_t ws_size, hipStream_t stream) {
  const float* x = (const float*)d_in[0];
  const float* W_in = (const float*)d_in[1];
  const float* b_in = (const float*)d_in[2];
  const float* W_q = (const float*)d_in[3];
  const float* b_q = (const float*)d_in[4];
  const float* g_q = (const float*)d_in[5];
  const float* be_q = (const float*)d_in[6];
  const float* K_mem = (const float*)d_in[7];
  const float* V_mem = (const float*)d_in[8];
  const float* W_kv = (const float*)d_in[9];
  const float* b_kv = (const float*)d_in[10];
  const float* g_kv = (const float*)d_in[11];
  const float* be_kv = (const float*)d_in[12];
  const float* W_o = (const float*)d_in[13];
  const float* b_o = (const float*)d_in[14];
  const float* g_o = (const float*)d_in[15];
  const float* be_o = (const float*)d_in[16];
  const float* g_1 = (const float*)d_in[17];
  const float* be_1 = (const float*)d_in[18];

  // d_out: [out(N*256) | K_new(S*256) | V_new(S*256) | surprise(N) | lr(N)]
  float* out_main = (float*)d_out;
  float* out_K = out_main + (size_t)NTOK * 256;
  float* out_V = out_K + (size_t)SMEM * 256;
  float* out_sur = out_V + (size_t)SMEM * 256;
  float* out_lr = out_sur + NTOK;

  // workspace layout (float offsets)
  float* ws = (float*)d_ws;
  float* x_proj = ws + (size_t)0;
  float* memout = ws + (size_t)8388608;
  float* keynew = ws + (size_t)16777216;
  float* valnew = ws + (size_t)25165824;
  u16* qhi = (u16*)(ws + (size_t)33554432);
  u16* qlo = (u16*)(ws + (size_t)37748736);
  u16* knhi = (u16*)(ws + (size_t)41943040);
  u16* knlo = (u16*)(ws + (size_t)46137344);
  u16* khi = (u16*)(ws + (size_t)50331648);
  u16* klo = (u16*)(ws + (size_t)50855936);
  u16* vthi = (u16*)(ws + (size_t)51380224);
  u16* vtlo = (u16*)(ws + (size_t)51904512);
  int* cnt = (int*)(ws + (size_t)52428800);
  int* cursor = (int*)(ws + (size_t)52432896);
  int* slot_start = (int*)(ws + (size_t)52436992);
  int* tok_list = (int*)(ws + (size_t)52445184);
  int* cand1 = (int*)(ws + (size_t)54530048);
  int* cand2 = (int*)(ws + (size_t)54562816);
  int* idx = (int*)(ws + (size_t)54595584);

  const dim3 b256(256);
  split_k<<<512, b256, 0, stream>>>(K_mem, khi, klo);
  vt_split<<<128, b256, 0, stream>>>(V_mem, vthi, vtlo);
  gemm256<256, 0><<<NTOK / 32, b256, 0, stream>>>(
      x, nullptr, W_in, b_in, nullptr, nullptr, nullptr, nullptr, nullptr,
      x_proj, nullptr, nullptr);
  gemm256<256, 1><<<NTOK / 32, b256, 0, stream>>>(
      x_proj, nullptr, W_q, b_q, g_q, be_q, nullptr, nullptr, nullptr, nullptr,
      qhi, qlo);
  flash_mfma<<<NTOK / 64, b256, 0, stream>>>(qhi, qlo, khi, klo, vthi, vtlo,
                                             memout, out_sur);
  gemm_kv<<<NTOK / 16, b256, 0, stream>>>(x_proj, memout, W_kv, b_kv, g_kv,
                                          be_kv, keynew, knhi, knlo, valnew,
                                          out_lr);
  wsim_mfma<<<NTOK / 64, b256, 0, stream>>>(knhi, knlo, khi, klo, cand1,
                                            cand2);
  refine_argmax<<<NTOK / 4, b256, 0, stream>>>(keynew, K_mem, cand1, cand2,
                                               idx);
  zero_kernel<<<16, b256, 0, stream>>>((float*)cnt, SMEM);
  hist_kernel<<<NTOK / 256, b256, 0, stream>>>(idx, cnt);
  scan4096<<<1, 1024, 0, stream>>>(cnt, slot_start, cursor);
  fill_kernel<<<NTOK / 256, b256, 0, stream>>>(idx, cursor, tok_list);
  gather_update<<<SMEM, b256, 0, stream>>>(keynew, valnew, out_sur,
                                           slot_start, tok_list, K_mem,
                                           V_mem, out_K, out_V);
  gemm256<512, 2><<<NTOK / 32, b256, 0, stream>>>(
      x_proj, memout, W_o, b_o, g_o, be_o, g_1, be_1, x_proj, out_main,
      nullptr, nullptr);
}

// Round 8
// 2523.993 us; speedup vs baseline: 2.1406x; 1.3034x over previous
//
#include <hip/hip_runtime.h>
#include <math.h>

// Shapes fixed by setup_inputs: B=4, T=8192 -> N=32768 tokens, D=256, H=256, S=4096.
#define NTOK 32768
#define SMEM 4096
#define NC 128  // 32-slot chunks

typedef unsigned short u16;
typedef __attribute__((ext_vector_type(8))) short bf16x8_t;
typedef __attribute__((ext_vector_type(4))) float f32x4_t;

#define MFMA16(A, B, C) __builtin_amdgcn_mfma_f32_16x16x32_bf16(A, B, C, 0, 0, 0)

__device__ __forceinline__ float gelu_f(float x) {
  return 0.5f * x * (1.0f + erff(x * 0.7071067811865475f));
}
__device__ __forceinline__ u16 f2bf(float x) {
  unsigned u = __float_as_uint(x);
  return (u16)((u + 0x7FFFu + ((u >> 16) & 1u)) >> 16);
}
__device__ __forceinline__ float bf2f(u16 h) {
  return __uint_as_float(((unsigned)h) << 16);
}

// ---------------------------------------------------------------------------
// Prep 1: split K_mem -> khi/klo (bf16 hi + residual lo)
// ---------------------------------------------------------------------------
__global__ __launch_bounds__(256) void split_k(const float* __restrict__ K,
                                               u16* __restrict__ khi,
                                               u16* __restrict__ klo) {
  const int i8 = (blockIdx.x * 256 + threadIdx.x) * 8;
  union { u16 u[8]; float4 f; } H, L;
#pragma unroll
  for (int j = 0; j < 8; j++) {
    const float v = K[i8 + j];
    const u16 h = f2bf(v);
    H.u[j] = h;
    L.u[j] = f2bf(v - bf2f(h));
  }
  *(float4*)(khi + i8) = H.f;
  *(float4*)(klo + i8) = L.f;
}

// ---------------------------------------------------------------------------
// Prep 2: V_mem[4096][256] -> vthi/vtlo transposed [256][4096] bf16 hi/lo
// ---------------------------------------------------------------------------
__global__ __launch_bounds__(256) void vt_split(const float* __restrict__ V,
                                                u16* __restrict__ vthi,
                                                u16* __restrict__ vtlo) {
  __shared__ float Vs[32][260];
  const int t = threadIdx.x;
  const int s0 = (blockIdx.x & 15) * 256;
  const int d0 = (blockIdx.x >> 4) * 32;
#pragma unroll
  for (int m = 0; m < 8; m++) {
    const int r = (t >> 3) + 32 * m;
    const float4 v =
        *(const float4*)(V + (size_t)(s0 + r) * 256 + d0 + (t & 7) * 4);
    Vs[(t & 7) * 4 + 0][r] = v.x;
    Vs[(t & 7) * 4 + 1][r] = v.y;
    Vs[(t & 7) * 4 + 2][r] = v.z;
    Vs[(t & 7) * 4 + 3][r] = v.w;
  }
  __syncthreads();
  const int dl = t >> 3;
  const int sl0 = (t & 7) * 32;
  union { u16 u[8]; float4 f; } H[4], L[4];
#pragma unroll
  for (int i = 0; i < 8; i++) {
    const float4 v = *(const float4*)&Vs[dl][sl0 + i * 4];
    const float vv[4] = {v.x, v.y, v.z, v.w};
#pragma unroll
    for (int j = 0; j < 4; j++) {
      const u16 h = f2bf(vv[j]);
      H[i >> 1].u[(i & 1) * 4 + j] = h;
      L[i >> 1].u[(i & 1) * 4 + j] = f2bf(vv[j] - bf2f(h));
    }
  }
  const size_t ob = (size_t)(d0 + dl) * 4096 + s0 + sl0;
#pragma unroll
  for (int i = 0; i < 4; i++) {
    *(float4*)(vthi + ob + i * 8) = H[i].f;
    *(float4*)(vtlo + ob + i * 8) = L[i].f;
  }
}

// ---------------------------------------------------------------------------
// GEMM BN=256, BM=32, KSTEP=32, 256 threads (unchanged).
// ---------------------------------------------------------------------------
template <int KDIM, int EPI>
__global__ __launch_bounds__(256) void gemm256(
    const float* __restrict__ A1, const float* __restrict__ A2,
    const float* __restrict__ W, const float* __restrict__ bias,
    const float* __restrict__ g0, const float* __restrict__ be0,
    const float* __restrict__ g1, const float* __restrict__ be1,
    const float* __restrict__ ident, float* __restrict__ out,
    u16* __restrict__ bh, u16* __restrict__ bl) {
  __shared__ float As[32][36];
  __shared__ float Bs[32][256];
  const int t = threadIdx.x;
  const int tx = t & 63;
  const int ty = t >> 6;
  const int row0 = blockIdx.x * 32;
  const int c0 = tx * 4;

  float acc[8][4];
#pragma unroll
  for (int r = 0; r < 8; r++)
#pragma unroll
    for (int j = 0; j < 4; j++) acc[r][j] = 0.f;

  const int ar = t >> 3;
  const int akc = (t & 7) * 4;

  for (int k0 = 0; k0 < KDIM; k0 += 32) {
    float4 av;
    if (KDIM == 512) {
      const int kg = k0 + akc;
      const float* src = (kg < 256) ? A1 : A2;
      av = *(const float4*)(src + (size_t)(row0 + ar) * 256 + (kg & 255));
    } else {
      av = *(const float4*)(A1 + (size_t)(row0 + ar) * 256 + k0 + akc);
    }
    As[akc + 0][ar] = av.x;
    As[akc + 1][ar] = av.y;
    As[akc + 2][ar] = av.z;
    As[akc + 3][ar] = av.w;
#pragma unroll
    for (int j = 0; j < 8; j++) {
      *(float4*)&Bs[ar][akc + j * 32] =
          *(const float4*)(W + (size_t)(k0 + ar) * 256 + akc + j * 32);
    }
    __syncthreads();
#pragma unroll
    for (int kk = 0; kk < 32; kk++) {
      const float4 bv = *(const float4*)&Bs[kk][c0];
      const float4 a0 = *(const float4*)&As[kk][ty * 8];
      const float4 a1 = *(const float4*)&As[kk][ty * 8 + 4];
      const float a8[8] = {a0.x, a0.y, a0.z, a0.w, a1.x, a1.y, a1.z, a1.w};
      const float b4[4] = {bv.x, bv.y, bv.z, bv.w};
#pragma unroll
      for (int r = 0; r < 8; r++)
#pragma unroll
        for (int j = 0; j < 4; j++) acc[r][j] = fmaf(a8[r], b4[j], acc[r][j]);
    }
    __syncthreads();
  }

  float bb[4];
#pragma unroll
  for (int j = 0; j < 4; j++) bb[j] = bias[c0 + j];
#pragma unroll
  for (int r = 0; r < 8; r++)
#pragma unroll
    for (int j = 0; j < 4; j++) acc[r][j] += bb[j];

  if (EPI == 0) {
#pragma unroll
    for (int r = 0; r < 8; r++) {
      float4 v = make_float4(acc[r][0], acc[r][1], acc[r][2], acc[r][3]);
      *(float4*)(out + (size_t)(row0 + ty * 8 + r) * 256 + c0) = v;
    }
    return;
  }

  float gg[4], ee[4];
#pragma unroll
  for (int j = 0; j < 4; j++) {
    gg[j] = g0[c0 + j];
    ee[j] = be0[c0 + j];
  }

#pragma unroll
  for (int r = 0; r < 8; r++) {
    float s1 = acc[r][0] + acc[r][1] + acc[r][2] + acc[r][3];
    float s2 = acc[r][0] * acc[r][0] + acc[r][1] * acc[r][1] +
               acc[r][2] * acc[r][2] + acc[r][3] * acc[r][3];
#pragma unroll
    for (int mk = 1; mk < 64; mk <<= 1) {
      s1 += __shfl_xor(s1, mk, 64);
      s2 += __shfl_xor(s2, mk, 64);
    }
    const float mu = s1 * (1.0f / 256.0f);
    const float rstd = rsqrtf(s2 * (1.0f / 256.0f) - mu * mu + 1e-5f);
    if (EPI == 1) {
      float q[4];
#pragma unroll
      for (int j = 0; j < 4; j++)
        q[j] = gelu_f((acc[r][j] - mu) * rstd * gg[j] + ee[j]) * 0.0625f;
      ushort4 hv, lv;
      u16 h;
      h = f2bf(q[0]); hv.x = h; lv.x = f2bf(q[0] - bf2f(h));
      h = f2bf(q[1]); hv.y = h; lv.y = f2bf(q[1] - bf2f(h));
      h = f2bf(q[2]); hv.z = h; lv.z = f2bf(q[2] - bf2f(h));
      h = f2bf(q[3]); hv.w = h; lv.w = f2bf(q[3] - bf2f(h));
      const size_t o = (size_t)(row0 + ty * 8 + r) * 256 + c0;
      *(ushort4*)(bh + o) = hv;
      *(ushort4*)(bl + o) = lv;
    } else {
      const float4 idv =
          *(const float4*)(ident + (size_t)(row0 + ty * 8 + r) * 256 + c0);
      acc[r][0] = (acc[r][0] - mu) * rstd * gg[0] + ee[0] + idv.x;
      acc[r][1] = (acc[r][1] - mu) * rstd * gg[1] + ee[1] + idv.y;
      acc[r][2] = (acc[r][2] - mu) * rstd * gg[2] + ee[2] + idv.z;
      acc[r][3] = (acc[r][3] - mu) * rstd * gg[3] + ee[3] + idv.w;
    }
  }

  if (EPI == 2) {
    float g1v[4], e1v[4];
#pragma unroll
    for (int j = 0; j < 4; j++) {
      g1v[j] = g1[c0 + j];
      e1v[j] = be1[c0 + j];
    }
#pragma unroll
    for (int r = 0; r < 8; r++) {
      float s1 = acc[r][0] + acc[r][1] + acc[r][2] + acc[r][3];
      float s2 = acc[r][0] * acc[r][0] + acc[r][1] * acc[r][1] +
                 acc[r][2] * acc[r][2] + acc[r][3] * acc[r][3];
#pragma unroll
      for (int mk = 1; mk < 64; mk <<= 1) {
        s1 += __shfl_xor(s1, mk, 64);
        s2 += __shfl_xor(s2, mk, 64);
      }
      const float mu = s1 * (1.0f / 256.0f);
      const float rstd = rsqrtf(s2 * (1.0f / 256.0f) - mu * mu + 1e-5f);
      float4 v;
      v.x = (acc[r][0] - mu) * rstd * g1v[0] + e1v[0];
      v.y = (acc[r][1] - mu) * rstd * g1v[1] + e1v[1];
      v.z = (acc[r][2] - mu) * rstd * g1v[2] + e1v[2];
      v.w = (acc[r][3] - mu) * rstd * g1v[3] + e1v[3];
      *(float4*)(out + (size_t)(row0 + ty * 8 + r) * 256 + c0) = v;
    }
  }
}

// ---------------------------------------------------------------------------
// kv GEMM v2: BM=32 (was 16), halves blocks/barriers/W-traffic per output.
// ---------------------------------------------------------------------------
__global__ __launch_bounds__(256) void gemm_kv(
    const float* __restrict__ A1, const float* __restrict__ A2,
    const float* __restrict__ W, const float* __restrict__ bias,
    const float* __restrict__ gln, const float* __restrict__ bln,
    float* __restrict__ key_new, u16* __restrict__ knhi, u16* __restrict__ knlo,
    float* __restrict__ value_new, float* __restrict__ lr_out) {
  __shared__ float As[16][40];   // [k][row], 40 -> 160B rows keep 16B align
  __shared__ float Bs[16][768];
  const int t = threadIdx.x;
  const int tx = t & 63;
  const int ty = t >> 6;
  const int row0 = blockIdx.x * 32;
  const int c0 = tx * 4;

  float acc[8][3][4];
#pragma unroll
  for (int r = 0; r < 8; r++)
#pragma unroll
    for (int g = 0; g < 3; g++)
#pragma unroll
      for (int j = 0; j < 4; j++) acc[r][g][j] = 0.f;

  for (int k0 = 0; k0 < 512; k0 += 16) {
    if (t < 128) {
      const int r = t & 31;
      const int kc = (t >> 5) * 4;
      const int kg = k0 + kc;
      const float* src = (kg < 256) ? A1 : A2;
      const float4 av =
          *(const float4*)(src + (size_t)(row0 + r) * 256 + (kg & 255));
      As[kc + 0][r] = av.x;
      As[kc + 1][r] = av.y;
      As[kc + 2][r] = av.z;
      As[kc + 3][r] = av.w;
    }
    {
      const int kk = t >> 4;
      const int bc = (t & 15) * 4;
#pragma unroll
      for (int j = 0; j < 12; j++)
        *(float4*)&Bs[kk][bc + j * 64] =
            *(const float4*)(W + (size_t)(k0 + kk) * 768 + bc + j * 64);
    }
    __syncthreads();
#pragma unroll
    for (int kk = 0; kk < 16; kk++) {
      const float4 a0 = *(const float4*)&As[kk][ty * 8];
      const float4 a1 = *(const float4*)&As[kk][ty * 8 + 4];
      const float a8[8] = {a0.x, a0.y, a0.z, a0.w, a1.x, a1.y, a1.z, a1.w};
#pragma unroll
      for (int g = 0; g < 3; g++) {
        const float4 b = *(const float4*)&Bs[kk][g * 256 + c0];
#pragma unroll
        for (int r = 0; r < 8; r++) {
          acc[r][g][0] = fmaf(a8[r], b.x, acc[r][g][0]);
          acc[r][g][1] = fmaf(a8[r], b.y, acc[r][g][1]);
          acc[r][g][2] = fmaf(a8[r], b.z, acc[r][g][2]);
          acc[r][g][3] = fmaf(a8[r], b.w, acc[r][g][3]);
        }
      }
    }
    __syncthreads();
  }

  float bv[3][4], gw[3][4], ew[3][4];
#pragma unroll
  for (int g = 0; g < 3; g++)
#pragma unroll
    for (int j = 0; j < 4; j++) {
      bv[g][j] = bias[g * 256 + c0 + j];
      gw[g][j] = gln[g * 256 + c0 + j];
      ew[g][j] = bln[g * 256 + c0 + j];
    }

#pragma unroll
  for (int r = 0; r < 8; r++) {
    float s1 = 0.f, s2 = 0.f;
#pragma unroll
    for (int g = 0; g < 3; g++)
#pragma unroll
      for (int j = 0; j < 4; j++) {
        acc[r][g][j] += bv[g][j];
        s1 += acc[r][g][j];
        s2 += acc[r][g][j] * acc[r][g][j];
      }
#pragma unroll
    for (int mk = 1; mk < 64; mk <<= 1) {
      s1 += __shfl_xor(s1, mk, 64);
      s2 += __shfl_xor(s2, mk, 64);
    }
    const float mu = s1 * (1.0f / 768.0f);
    const float rstd = rsqrtf(s2 * (1.0f / 768.0f) - mu * mu + 1e-5f);
    const size_t orow = (size_t)(row0 + ty * 8 + r) * 256 + c0;
    float kq[4];
    float4 vv;
#pragma unroll
    for (int j = 0; j < 4; j++)
      kq[j] = gelu_f((acc[r][0][j] - mu) * rstd * gw[0][j] + ew[0][j]);
    vv.x = gelu_f((acc[r][1][0] - mu) * rstd * gw[1][0] + ew[1][0]);
    vv.y = gelu_f((acc[r][1][1] - mu) * rstd * gw[1][1] + ew[1][1]);
    vv.z = gelu_f((acc[r][1][2] - mu) * rstd * gw[1][2] + ew[1][2]);
    vv.w = gelu_f((acc[r][1][3] - mu) * rstd * gw[1][3] + ew[1][3]);
    *(float4*)(key_new + orow) = make_float4(kq[0], kq[1], kq[2], kq[3]);
    *(float4*)(value_new + orow) = vv;
    ushort4 hv, lv;
    u16 h;
    h = f2bf(kq[0]); hv.x = h; lv.x = f2bf(kq[0] - bf2f(h));
    h = f2bf(kq[1]); hv.y = h; lv.y = f2bf(kq[1] - bf2f(h));
    h = f2bf(kq[2]); hv.z = h; lv.z = f2bf(kq[2] - bf2f(h));
    h = f2bf(kq[3]); hv.w = h; lv.w = f2bf(kq[3] - bf2f(h));
    *(ushort4*)(knhi + orow) = hv;
    *(ushort4*)(knlo + orow) = lv;
    float ls = 0.f;
#pragma unroll
    for (int j = 0; j < 4; j++) {
      const float lvv = gelu_f((acc[r][2][j] - mu) * rstd * gw[2][j] + ew[2][j]);
      ls += 1.0f / (1.0f + __expf(-lvv));
    }
#pragma unroll
    for (int mk = 1; mk < 64; mk <<= 1) ls += __shfl_xor(ls, mk, 64);
    if (tx == 0) lr_out[row0 + ty * 8 + r] = ls * (1.0f / 256.0f);
  }
}

// ---------------------------------------------------------------------------
// Flash read v3 (unchanged from R7): 4 waves, reg-staged LDS, 2 barriers.
// ---------------------------------------------------------------------------
__global__ __launch_bounds__(256) void flash_mfma(
    const u16* __restrict__ qhi, const u16* __restrict__ qlo,
    const u16* __restrict__ khi, const u16* __restrict__ klo,
    const u16* __restrict__ vthi, const u16* __restrict__ vtlo,
    float* __restrict__ memout, float* __restrict__ surprise_out) {
  __shared__ u16 Kb[2][8192];      // [prec][1024 slots * 8]
  __shared__ u16 Vb[2][8192];
  __shared__ u16 pbuf[4][2][512];  // [wave][prec][64 slots * 8]
  __shared__ float scf[4][16];
  const int t = threadIdx.x;
  const int w = t >> 6;
  const int l = t & 63;
  const int s = l & 15;
  const int g = l >> 4;
  const int row0 = blockIdx.x * 64 + w * 16;
  const int p0 = (g * 16 + s) * 8;

  int kin[4], vin[4], lsl[4];
#pragma unroll
  for (int i = 0; i < 4; i++) {
    const int sid = i * 256 + w * 64 + l;
    kin[i] = (((sid >> 6) & 1) * 16 + (sid & 15)) * 256 + (sid >> 7) * 32 +
             ((sid >> 4) & 3) * 8;
    vin[i] = ((sid >> 6) * 16 + (sid & 15)) * 4096 + ((sid >> 4) & 3) * 8;
    lsl[i] = sid * 8;
  }

  bf16x8_t qh[8], ql[8];
#pragma unroll
  for (int ks = 0; ks < 8; ks++) {
    const size_t qo = (size_t)(row0 + s) * 256 + ks * 32 + g * 8;
    qh[ks] = *(const bf16x8_t*)(qhi + qo);
    ql[ks] = *(const bf16x8_t*)(qlo + qo);
  }

  f32x4_t o_acc[16];
  f32x4_t l_acc;
  float m_st[4];
#pragma unroll
  for (int nt = 0; nt < 16; nt++)
#pragma unroll
    for (int j = 0; j < 4; j++) o_acc[nt][j] = 0.f;
#pragma unroll
  for (int j = 0; j < 4; j++) l_acc[j] = 0.f;
#pragma unroll
  for (int q = 0; q < 4; q++) m_st[q] = -INFINITY;
  bf16x8_t ones;
#pragma unroll
  for (int j = 0; j < 8; j++) ones[j] = (short)0x3F80;

  bf16x8_t kst[2][4];
#pragma unroll
  for (int i = 0; i < 4; i++) {
    kst[0][i] = *(const bf16x8_t*)(khi + kin[i]);
    kst[1][i] = *(const bf16x8_t*)(klo + kin[i]);
  }
#pragma unroll
  for (int i = 0; i < 4; i++) {
    *(bf16x8_t*)&Kb[0][lsl[i]] = kst[0][i];
    *(bf16x8_t*)&Kb[1][lsl[i]] = kst[1][i];
  }

  for (int c = 0; c < NC; c++) {
    const int c0 = c * 32;
    __syncthreads();  // (A) Kb[c] visible; Vb free
    bf16x8_t vst[2][4];
#pragma unroll
    for (int i = 0; i < 4; i++) {
      vst[0][i] = *(const bf16x8_t*)(vthi + c0 + vin[i]);
      vst[1][i] = *(const bf16x8_t*)(vtlo + c0 + vin[i]);
    }
    f32x4_t sacc[2];
#pragma unroll
    for (int nt = 0; nt < 2; nt++)
#pragma unroll
      for (int j = 0; j < 4; j++) sacc[nt][j] = 0.f;
#pragma unroll
    for (int ks = 0; ks < 8; ks++) {
#pragma unroll
      for (int nt = 0; nt < 2; nt++) {
        const int ko = ks * 1024 + nt * 512 + p0;
        const bf16x8_t kh = *(const bf16x8_t*)&Kb[0][ko];
        const bf16x8_t kl = *(const bf16x8_t*)&Kb[1][ko];
        sacc[nt] = MFMA16(qh[ks], kh, sacc[nt]);
        sacc[nt] = MFMA16(ql[ks], kh, sacc[nt]);
        sacc[nt] = MFMA16(qh[ks], kl, sacc[nt]);
      }
    }
    float cmax[4];
    bool needb = false;
#pragma unroll
    for (int q = 0; q < 4; q++) {
      float v = fmaxf(sacc[0][q], sacc[1][q]);
#pragma unroll
      for (int mk = 1; mk < 16; mk <<= 1) v = fmaxf(v, __shfl_xor(v, mk, 64));
      cmax[q] = v;
      needb |= (v > m_st[q]);
    }
    const bool need = (__ballot(needb) != 0ull);
#pragma unroll
    for (int q = 0; q < 4; q++) {
      const float mold = m_st[q];
      const float mnew = need ? fmaxf(mold, cmax[q]) : mold;
      const float e0 = __expf(sacc[0][q] - mnew);
      const float e1 = __expf(sacc[1][q] - mnew);
      const int cg0 = s >> 3, w0 = s & 7;
      const int i0 = (cg0 * 16 + g * 4 + q) * 8 + w0;
      const int i1 = ((2 + cg0) * 16 + g * 4 + q) * 8 + w0;
      u16 h;
      h = f2bf(e0);
      pbuf[w][0][i0] = h;
      pbuf[w][1][i0] = f2bf(e0 - bf2f(h));
      h = f2bf(e1);
      pbuf[w][0][i1] = h;
      pbuf[w][1][i1] = f2bf(e1 - bf2f(h));
      if (need) {
        if (s == 0) scf[w][g * 4 + q] = __expf(mold - mnew);
        m_st[q] = mnew;
      }
    }
#pragma unroll
    for (int i = 0; i < 4; i++) {
      *(bf16x8_t*)&Vb[0][lsl[i]] = vst[0][i];
      *(bf16x8_t*)&Vb[1][lsl[i]] = vst[1][i];
    }
    __syncthreads();  // (B) Vb[c] + pbuf visible; Kb free
    if (c + 1 < NC) {
      const size_t cofs = (size_t)(c0 + 32) * 256;
#pragma unroll
      for (int i = 0; i < 4; i++) {
        kst[0][i] = *(const bf16x8_t*)(khi + cofs + kin[i]);
        kst[1][i] = *(const bf16x8_t*)(klo + cofs + kin[i]);
      }
    }
    if (need) {
      const float scv = scf[w][s];
#pragma unroll
      for (int j = 0; j < 4; j++) l_acc[j] *= scv;
#pragma unroll
      for (int nt = 0; nt < 16; nt++)
#pragma unroll
        for (int j = 0; j < 4; j++) o_acc[nt][j] *= scv;
    }
    const bf16x8_t ph = *(const bf16x8_t*)&pbuf[w][0][p0];
    const bf16x8_t pl = *(const bf16x8_t*)&pbuf[w][1][p0];
    l_acc = MFMA16(ones, ph, l_acc);
    l_acc = MFMA16(ones, pl, l_acc);
#pragma unroll
    for (int nt = 0; nt < 16; nt++) {
      const int vo = nt * 512 + p0;
      const bf16x8_t vh = *(const bf16x8_t*)&Vb[0][vo];
      const bf16x8_t vl = *(const bf16x8_t*)&Vb[1][vo];
      o_acc[nt] = MFMA16(vh, ph, o_acc[nt]);
      o_acc[nt] = MFMA16(vl, ph, o_acc[nt]);
      o_acc[nt] = MFMA16(vh, pl, o_acc[nt]);
    }
    if (c + 1 < NC) {
#pragma unroll
      for (int i = 0; i < 4; i++) {
        *(bf16x8_t*)&Kb[0][lsl[i]] = kst[0][i];
        *(bf16x8_t*)&Kb[1][lsl[i]] = kst[1][i];
      }
    }
  }
  const float li = 1.0f / l_acc[0];
  if (g == 0) surprise_out[row0 + s] = 1.0f - li;
  const size_t rb = (size_t)(row0 + s) * 256;
#pragma unroll
  for (int nt = 0; nt < 16; nt++) {
    float4 v = make_float4(o_acc[nt][0] * li, o_acc[nt][1] * li,
                           o_acc[nt][2] * li, o_acc[nt][3] * li);
    *(float4*)(memout + rb + nt * 16 + g * 4) = v;
  }
}

// ---------------------------------------------------------------------------
// wsim v4: block-shared K via double-buffered LDS with reg-staged prefetch
// (fixes R7's 4x per-wave L2/TA redundancy; no glds serialization).
// 256 thr = 4 waves, 16 tok/wave; LDS 64 KB -> 2 blocks/CU = 8 waves/CU.
// 1 barrier/chunk. MFMA order identical to R6/R7.
// ---------------------------------------------------------------------------
__device__ __forceinline__ void top2_upd(float a, int ia, float& v1, int& i1,
                                         float& v2, int& i2) {
  if (a > v1 || (a == v1 && ia < i1)) {
    v2 = v1; i2 = i1; v1 = a; i1 = ia;
  } else if (a > v2 || (a == v2 && ia < i2)) {
    v2 = a; i2 = ia;
  }
}

__global__ __launch_bounds__(256) void wsim_mfma(
    const u16* __restrict__ knhi, const u16* __restrict__ knlo,
    const u16* __restrict__ khi, const u16* __restrict__ klo,
    int* __restrict__ cand1, int* __restrict__ cand2) {
  __shared__ u16 Kb[2][2][8192];  // [dbuf][prec][1024 slots * 8]
  const int t = threadIdx.x;
  const int w = t >> 6;
  const int l = t & 63;
  const int s = l & 15;
  const int g = l >> 4;
  const int row0 = blockIdx.x * 64 + w * 16;
  const int p0 = (g * 16 + s) * 8;

  int kin[4], lsl[4];
#pragma unroll
  for (int i = 0; i < 4; i++) {
    const int sid = i * 256 + w * 64 + l;
    kin[i] = (((sid >> 6) & 1) * 16 + (sid & 15)) * 256 + (sid >> 7) * 32 +
             ((sid >> 4) & 3) * 8;
    lsl[i] = sid * 8;
  }

  bf16x8_t ah[8], al[8];
#pragma unroll
  for (int ks = 0; ks < 8; ks++) {
    const size_t qo = (size_t)(row0 + s) * 256 + ks * 32 + g * 8;
    ah[ks] = *(const bf16x8_t*)(knhi + qo);
    al[ks] = *(const bf16x8_t*)(knlo + qo);
  }
  float v1[4], v2[4];
  int i1[4], i2[4];
#pragma unroll
  for (int q = 0; q < 4; q++) {
    v1[q] = -INFINITY; v2[q] = -INFINITY;
    i1[q] = 0; i2[q] = 0;
  }

  // prologue: stage chunk 0 into buf 0
  bf16x8_t kst[2][4];
#pragma unroll
  for (int i = 0; i < 4; i++) {
    kst[0][i] = *(const bf16x8_t*)(khi + kin[i]);
    kst[1][i] = *(const bf16x8_t*)(klo + kin[i]);
  }
#pragma unroll
  for (int i = 0; i < 4; i++) {
    *(bf16x8_t*)&Kb[0][0][lsl[i]] = kst[0][i];
    *(bf16x8_t*)&Kb[0][1][lsl[i]] = kst[1][i];
  }

  for (int c = 0; c < NC; c++) {
    const int cb = c & 1;
    __syncthreads();  // buf[cb] ready; buf[cb^1] free
    // prefetch chunk c+1 into regs (flies under the MFMAs)
    if (c + 1 < NC) {
      const size_t cofs = (size_t)(c + 1) * 32 * 256;
#pragma unroll
      for (int i = 0; i < 4; i++) {
        kst[0][i] = *(const bf16x8_t*)(khi + cofs + kin[i]);
        kst[1][i] = *(const bf16x8_t*)(klo + cofs + kin[i]);
      }
    }
    f32x4_t sacc[2];
#pragma unroll
    for (int nt = 0; nt < 2; nt++)
#pragma unroll
      for (int j = 0; j < 4; j++) sacc[nt][j] = 0.f;
#pragma unroll
    for (int ks = 0; ks < 8; ks++) {
#pragma unroll
      for (int nt = 0; nt < 2; nt++) {
        const int ko = ks * 1024 + nt * 512 + p0;
        const bf16x8_t kh = *(const bf16x8_t*)&Kb[cb][0][ko];
        const bf16x8_t kl = *(const bf16x8_t*)&Kb[cb][1][ko];
        sacc[nt] = MFMA16(ah[ks], kh, sacc[nt]);
        sacc[nt] = MFMA16(al[ks], kh, sacc[nt]);
        sacc[nt] = MFMA16(ah[ks], kl, sacc[nt]);
      }
    }
    const int c0 = c * 32;
#pragma unroll
    for (int q = 0; q < 4; q++) {
      top2_upd(sacc[0][q], c0 + s, v1[q], i1[q], v2[q], i2[q]);
      top2_upd(sacc[1][q], c0 + 16 + s, v1[q], i1[q], v2[q], i2[q]);
    }
    // write prefetched chunk to the spare buffer (safe: all waves are past
    // this iteration's barrier, so prior reads of buf[cb^1] are done)
    if (c + 1 < NC) {
#pragma unroll
      for (int i = 0; i < 4; i++) {
        *(bf16x8_t*)&Kb[cb ^ 1][0][lsl[i]] = kst[0][i];
        *(bf16x8_t*)&Kb[cb ^ 1][1][lsl[i]] = kst[1][i];
      }
    }
  }
  // cross-lane merge over the 16 slot-lanes
#pragma unroll
  for (int q = 0; q < 4; q++) {
#pragma unroll
    for (int mk = 1; mk < 16; mk <<= 1) {
      const float w1 = __shfl_xor(v1[q], mk, 64);
      const int j1 = __shfl_xor(i1[q], mk, 64);
      const float w2 = __shfl_xor(v2[q], mk, 64);
      const int j2 = __shfl_xor(i2[q], mk, 64);
      const bool take = (w1 > v1[q]) || (w1 == v1[q] && j1 < i1[q]);
      const float ca = take ? v1[q] : w1;
      const int ja = take ? i1[q] : j1;
      const float cb2 = take ? w2 : v2[q];
      const int jb = take ? j2 : i2[q];
      v1[q] = take ? w1 : v1[q];
      i1[q] = take ? j1 : i1[q];
      const bool t2 = (cb2 > ca) || (cb2 == ca && jb < ja);
      v2[q] = t2 ? cb2 : ca;
      i2[q] = t2 ? jb : ja;
    }
    if (s == 0) {
      cand1[row0 + g * 4 + q] = i1[q];
      cand2[row0 + g * 4 + q] = i2[q];
    }
  }
}

// exact fp32 re-check of the two candidates -> final argmax index
__global__ __launch_bounds__(256) void refine_argmax(
    const float* __restrict__ kn, const float* __restrict__ Km,
    const int* __restrict__ cand1, const int* __restrict__ cand2,
    int* __restrict__ idx) {
  const int t = threadIdx.x;
  const int w = t >> 6;
  const int l = t & 63;
  const int tok = blockIdx.x * 4 + w;
  const int c1 = cand1[tok], c2 = cand2[tok];
  const float4 a = *(const float4*)(kn + (size_t)tok * 256 + l * 4);
  const float4 b1 = *(const float4*)(Km + (size_t)c1 * 256 + l * 4);
  const float4 b2 = *(const float4*)(Km + (size_t)c2 * 256 + l * 4);
  float d1 = a.x * b1.x + a.y * b1.y + a.z * b1.z + a.w * b1.w;
  float d2 = a.x * b2.x + a.y * b2.y + a.z * b2.z + a.w * b2.w;
#pragma unroll
  for (int mk = 1; mk < 64; mk <<= 1) {
    d1 += __shfl_xor(d1, mk, 64);
    d2 += __shfl_xor(d2, mk, 64);
  }
  if (l == 0) idx[tok] = (d2 > d1 || (d2 == d1 && c2 < c1)) ? c2 : c1;
}

// ---------------------------------------------------------------------------
// Binned write path (unchanged).
// ---------------------------------------------------------------------------
__global__ void zero_kernel(float* __restrict__ p, int n) {
  int i = blockIdx.x * blockDim.x + threadIdx.x;
  const int stride = gridDim.x * blockDim.x;
  for (; i < n; i += stride) p[i] = 0.f;
}

__global__ __launch_bounds__(256) void hist_kernel(const int* __restrict__ idx,
                                                   int* __restrict__ cnt) {
  const int i = blockIdx.x * 256 + threadIdx.x;
  atomicAdd(&cnt[idx[i]], 1);
}

__global__ __launch_bounds__(1024) void scan4096(const int* __restrict__ cnt,
                                                 int* __restrict__ start,
                                                 int* __restrict__ cursor) {
  __shared__ int sums[1024];
  const int t = threadIdx.x;
  const int4 c = *(const int4*)(cnt + t * 4);
  const int local = c.x + c.y + c.z + c.w;
  sums[t] = local;
  __syncthreads();
  int acc = local;
  for (int off = 1; off < 1024; off <<= 1) {
    const int v = (t >= off) ? sums[t - off] : 0;
    __syncthreads();
    acc += v;
    sums[t] = acc;
    __syncthreads();
  }
  const int base = acc - local;
  int4 st;
  st.x = base;
  st.y = base + c.x;
  st.z = st.y + c.y;
  st.w = st.z + c.z;
  *(int4*)(start + t * 4) = st;
  *(int4*)(cursor + t * 4) = st;
  if (t == 1023) start[4096] = acc;
}

__global__ __launch_bounds__(256) void fill_kernel(const int* __restrict__ idx,
                                                   int* __restrict__ cursor,
                                                   int* __restrict__ tok_list) {
  const int i = blockIdx.x * 256 + threadIdx.x;
  const int pos = atomicAdd(&cursor[idx[i]], 1);
  tok_list[pos] = i;
}

__global__ __launch_bounds__(256) void gather_update(
    const float* __restrict__ keyn, const float* __restrict__ valn,
    const float* __restrict__ surprise, const int* __restrict__ start,
    const int* __restrict__ tok_list, const float* __restrict__ Km,
    const float* __restrict__ Vm, float* __restrict__ Ko,
    float* __restrict__ Vo) {
  __shared__ float4 gkp[4][64];
  __shared__ float4 gvp[4][64];
  __shared__ float gcp[4];
  const int t = threadIdx.x;
  const int w = t >> 6;
  const int l = t & 63;
  const int s = blockIdx.x;
  const int d0 = l * 4;
  const int b = start[s];
  const int e = start[s + 1];
  float4 gk = make_float4(0.f, 0.f, 0.f, 0.f);
  float4 gv = make_float4(0.f, 0.f, 0.f, 0.f);
  float gc = 0.f;
  for (int i = b + w; i < e; i += 4) {
    const int tok = tok_list[i];
    const float gate = surprise[tok];
    const float4 kq = *(const float4*)(keyn + (size_t)tok * 256 + d0);
    const float4 vq = *(const float4*)(valn + (size_t)tok * 256 + d0);
    gk.x = fmaf(gate, kq.x, gk.x);
    gk.y = fmaf(gate, kq.y, gk.y);
    gk.z = fmaf(gate, kq.z, gk.z);
    gk.w = fmaf(gate, kq.w, gk.w);
    gv.x = fmaf(gate, vq.x, gv.x);
    gv.y = fmaf(gate, vq.y, gv.y);
    gv.z = fmaf(gate, vq.z, gv.z);
    gv.w = fmaf(gate, vq.w, gv.w);
    gc += gate;
  }
  gkp[w][l] = gk;
  gvp[w][l] = gv;
  if (l == 0) gcp[w] = gc;
  __syncthreads();
  if (w == 0) {
#pragma unroll
    for (int ww = 1; ww < 4; ww++) {
      const float4 a = gkp[ww][l];
      gk.x += a.x; gk.y += a.y; gk.z += a.z; gk.w += a.w;
      const float4 bq = gvp[ww][l];
      gv.x += bq.x; gv.y += bq.y; gv.z += bq.z; gv.w += bq.w;
    }
    const float gct = gcp[0] + gcp[1] + gcp[2] + gcp[3];
    const float4 km = *(const float4*)(Km + (size_t)s * 256 + d0);
    const float4 vm = *(const float4*)(Vm + (size_t)s * 256 + d0);
    float4 ko, vo;
    ko.x = km.x + 0.1f * (gk.x - gct * km.x);
    ko.y = km.y + 0.1f * (gk.y - gct * km.y);
    ko.z = km.z + 0.1f * (gk.z - gct * km.z);
    ko.w = km.w + 0.1f * (gk.w - gct * km.w);
    vo.x = vm.x + 0.1f * (gv.x - gct * vm.x);
    vo.y = vm.y + 0.1f * (gv.y - gct * vm.y);
    vo.z = vm.z + 0.1f * (gv.z - gct * vm.z);
    vo.w = vm.w + 0.1f * (gv.w - gct * vm.w);
    *(float4*)(Ko + (size_t)s * 256 + d0) = ko;
    *(float4*)(Vo + (size_t)s * 256 + d0) = vo;
  }
}

// ---------------------------------------------------------------------------
extern "C" void kernel_launch(void* const* d_in, const int* in_sizes, int n_in,
                              void* d_out, int out_size, void* d_ws,
                              size_t ws_size, hipStream_t stream) {
  const float* x = (const float*)d_in[0];
  const float* W_in = (const float*)d_in[1];
  const float* b_in = (const float*)d_in[2];
  const float* W_q = (const float*)d_in[3];
  const float* b_q = (const float*)d_in[4];
  const float* g_q = (const float*)d_in[5];
  const float* be_q = (const float*)d_in[6];
  const float* K_mem = (const float*)d_in[7];
  const float* V_mem = (const float*)d_in[8];
  const float* W_kv = (const float*)d_in[9];
  const float* b_kv = (const float*)d_in[10];
  const float* g_kv = (const float*)d_in[11];
  const float* be_kv = (const float*)d_in[12];
  const float* W_o = (const float*)d_in[13];
  const float* b_o = (const float*)d_in[14];
  const float* g_o = (const float*)d_in[15];
  const float* be_o = (const float*)d_in[16];
  const float* g_1 = (const float*)d_in[17];
  const float* be_1 = (const float*)d_in[18];

  // d_out: [out(N*256) | K_new(S*256) | V_new(S*256) | surprise(N) | lr(N)]
  float* out_main = (float*)d_out;
  float* out_K = out_main + (size_t)NTOK * 256;
  float* out_V = out_K + (size_t)SMEM * 256;
  float* out_sur = out_V + (size_t)SMEM * 256;
  float* out_lr = out_sur + NTOK;

  // workspace layout (float offsets)
  float* ws = (float*)d_ws;
  float* x_proj = ws + (size_t)0;
  float* memout = ws + (size_t)8388608;
  float* keynew = ws + (size_t)16777216;
  float* valnew = ws + (size_t)25165824;
  u16* qhi = (u16*)(ws + (size_t)33554432);
  u16* qlo = (u16*)(ws + (size_t)37748736);
  u16* knhi = (u16*)(ws + (size_t)41943040);
  u16* knlo = (u16*)(ws + (size_t)46137344);
  u16* khi = (u16*)(ws + (size_t)50331648);
  u16* klo = (u16*)(ws + (size_t)50855936);
  u16* vthi = (u16*)(ws + (size_t)51380224);
  u16* vtlo = (u16*)(ws + (size_t)51904512);
  int* cnt = (int*)(ws + (size_t)52428800);
  int* cursor = (int*)(ws + (size_t)52432896);
  int* slot_start = (int*)(ws + (size_t)52436992);
  int* tok_list = (int*)(ws + (size_t)52445184);
  int* cand1 = (int*)(ws + (size_t)54530048);
  int* cand2 = (int*)(ws + (size_t)54562816);
  int* idx = (int*)(ws + (size_t)54595584);

  const dim3 b256(256);
  split_k<<<512, b256, 0, stream>>>(K_mem, khi, klo);
  vt_split<<<128, b256, 0, stream>>>(V_mem, vthi, vtlo);
  gemm256<256, 0><<<NTOK / 32, b256, 0, stream>>>(
      x, nullptr, W_in, b_in, nullptr, nullptr, nullptr, nullptr, nullptr,
      x_proj, nullptr, nullptr);
  gemm256<256, 1><<<NTOK / 32, b256, 0, stream>>>(
      x_proj, nullptr, W_q, b_q, g_q, be_q, nullptr, nullptr, nullptr, nullptr,
      qhi, qlo);
  flash_mfma<<<NTOK / 64, b256, 0, stream>>>(qhi, qlo, khi, klo, vthi, vtlo,
                                             memout, out_sur);
  gemm_kv<<<NTOK / 32, b256, 0, stream>>>(x_proj, memout, W_kv, b_kv, g_kv,
                                          be_kv, keynew, knhi, knlo, valnew,
                                          out_lr);
  wsim_mfma<<<NTOK / 64, b256, 0, stream>>>(knhi, knlo, khi, klo, cand1,
                                            cand2);
  refine_argmax<<<NTOK / 4, b256, 0, stream>>>(keynew, K_mem, cand1, cand2,
                                               idx);
  zero_kernel<<<16, b256, 0, stream>>>((float*)cnt, SMEM);
  hist_kernel<<<NTOK / 256, b256, 0, stream>>>(idx, cnt);
  scan4096<<<1, 1024, 0, stream>>>(cnt, slot_start, cursor);
  fill_kernel<<<NTOK / 256, b256, 0, stream>>>(idx, cursor, tok_list);
  gather_update<<<SMEM, b256, 0, stream>>>(keynew, valnew, out_sur,
                                           slot_start, tok_list, K_mem,
                                           V_mem, out_K, out_V);
  gemm256<512, 2><<<NTOK / 32, b256, 0, stream>>>(
      x_proj, memout, W_o, b_o, g_o, be_o, g_1, be_1, x_proj, out_main,
      nullptr, nullptr);
}